// Round 3
// baseline (746.621 us; speedup 1.0000x reference)
//
#include <hip/hip_runtime.h>
#include <math.h>

// PruningAgent r2:
//  - mm_mfma: A-only LDS staging (one 128-k shot, single barrier pair),
//    W fragments read directly from global (L1/L2-resident, shared by all
//    blocks), split-bf16 x3-MFMA precision as r1. enc1 layer+head merged.
//  - agg_split: XCD-aware block swizzle for head graphs (each head graph's
//    4 MiB table == one XCD's L2), 8-deep gather unroll.

typedef unsigned short ushort_t;
using short8 = __attribute__((ext_vector_type(8))) short;
using f32x4  = __attribute__((ext_vector_type(4))) float;

constexpr int N_L  = 40000;
constexpr int E_L  = 640000;
constexpr int H_   = 128;
constexpr int L_H  = 8;
constexpr int N_H1 = 8192;
constexpr int E_H1 = 131072;
constexpr int N_HT = 65536;    // 8*8192
constexpr int E_HT = 1048576;  // 8*131072
constexpr int NLP  = 40064;    // layer rows padded to 128
constexpr int R_T  = 105600;   // NLP + N_HT (combined row space)
constexpr int HBASE = 40064;   // head rows start here

// ---------------- numeric helpers ----------------

__device__ __forceinline__ unsigned short bf16_rne(float f) {
  unsigned u = __float_as_uint(f);
  unsigned r = u + 0x7FFFu + ((u >> 16) & 1u);
  return (unsigned short)(r >> 16);
}
__device__ __forceinline__ float bfhi_f(unsigned short h) {
  return __uint_as_float((unsigned)h << 16);
}
__device__ __forceinline__ void split2(float f, unsigned short& h, unsigned short& l) {
  h = bf16_rne(f);
  l = bf16_rne(f - bfhi_f(h));
}

__device__ __forceinline__ void gload16(const void* g, void* l) {
  __builtin_amdgcn_global_load_lds((__attribute__((address_space(1))) void*)(g),
                                   (__attribute__((address_space(3))) void*)(l),
                                   16, 0, 0);
}

// ---------------- degree / CSR build ----------------

__global__ __launch_bounds__(256) void count_deg_l(const int* __restrict__ ei,
                                                   int* __restrict__ indeg) {
  int i = blockIdx.x * 256 + threadIdx.x;
  if (i < E_L) atomicAdd(&indeg[ei[E_L + i]], 1);
}

__global__ __launch_bounds__(256) void count_deg_h(const int* __restrict__ hei,
                                                   int* __restrict__ indeg) {
  int i = blockIdx.x * 256 + threadIdx.x;
  if (i < E_HT) {
    int l = i >> 17, e = i & (E_H1 - 1);
    atomicAdd(&indeg[l * N_H1 + hei[l * 2 * E_H1 + E_H1 + e]], 1);
  }
}

__global__ __launch_bounds__(256) void dinv_kernel(const int* __restrict__ indeg,
                                                   float* __restrict__ dinv, int n) {
  int i = blockIdx.x * 256 + threadIdx.x;
  if (i < n) dinv[i] = 1.0f / sqrtf((float)(indeg[i] + 1));
}

__global__ __launch_bounds__(1024) void scan_block(const int* __restrict__ in, int n,
                                                   int* __restrict__ out,
                                                   int* __restrict__ bsum) {
  __shared__ int s[1024];
  int t = threadIdx.x;
  int i = blockIdx.x * 1024 + t;
  int v = (i < n) ? in[i] : 0;
  s[t] = v;
  __syncthreads();
  for (int off = 1; off < 1024; off <<= 1) {
    int x = (t >= off) ? s[t - off] : 0;
    __syncthreads();
    s[t] += x;
    __syncthreads();
  }
  if (i < n) out[i] = s[t] - v;
  if (t == 1023) bsum[blockIdx.x] = s[t];
}

__global__ __launch_bounds__(64) void scan_top(int* __restrict__ bsum, int nb) {
  int lane = threadIdx.x;
  int v = (lane < nb) ? bsum[lane] : 0;
  int incl = v;
  for (int off = 1; off < 64; off <<= 1) {
    int x = __shfl_up(incl, off);
    if (lane >= off) incl += x;
  }
  int total = __shfl(incl, 63);
  if (lane < nb) bsum[lane] = incl - v;
  if (lane == 0) bsum[nb] = total;
}

__global__ __launch_bounds__(256) void scan_fix(int* __restrict__ rowptr,
                                                const int* __restrict__ bsum,
                                                int n, int nb,
                                                int* __restrict__ rowpos) {
  int i = blockIdx.x * 256 + threadIdx.x;
  if (i < n) {
    int v = rowptr[i] + bsum[i >> 10];
    rowptr[i] = v;
    rowpos[i] = v;
  } else if (i == n) {
    rowptr[n] = bsum[nb];
  }
}

__global__ __launch_bounds__(256) void fill_csr_l(const int* __restrict__ ei,
                                                  int* __restrict__ rowpos,
                                                  int* __restrict__ col) {
  int i = blockIdx.x * 256 + threadIdx.x;
  if (i < E_L) {
    int dst = ei[E_L + i];
    int p = atomicAdd(&rowpos[dst], 1);
    col[p] = ei[i];
  }
}

__global__ __launch_bounds__(256) void fill_csr_h(const int* __restrict__ hei,
                                                  int* __restrict__ rowpos,
                                                  int* __restrict__ col) {
  int i = blockIdx.x * 256 + threadIdx.x;
  if (i < E_HT) {
    int l = i >> 17, e = i & (E_H1 - 1);
    int base = l * 2 * E_H1;
    int dst = l * N_H1 + hei[base + E_H1 + e];
    int src = l * N_H1 + hei[base + e];
    int p = atomicAdd(&rowpos[dst], 1);
    col[p] = HBASE + src;  // global row id
  }
}

// ---------------- weight pre-split (transposed) ----------------
// dst layout Wt[c][k] (hi/lo). element offsets:
// enc_w1:0 (K=256), enc_w2:32768, gnn_w1:49152, gnn_w2:65536, lp_w1:81920, hp_w1:98304

__global__ __launch_bounds__(256) void conv_weights(
    const float* __restrict__ w0, const float* __restrict__ w1,
    const float* __restrict__ w2, const float* __restrict__ w3,
    const float* __restrict__ w4, const float* __restrict__ w5,
    unsigned short* __restrict__ th, unsigned short* __restrict__ tl) {
  int t = blockIdx.x * 256 + threadIdx.x;
  const float* src; int K, dstoff, idx;
  if (t < 32768) { src = w0; K = 256; dstoff = 0; idx = t; }
  else {
    int s = (t - 32768) >> 14;
    idx = (t - 32768) & 16383;
    K = 128;
    dstoff = 32768 + s * 16384;
    src = s == 0 ? w1 : s == 1 ? w2 : s == 2 ? w3 : s == 3 ? w4 : w5;
  }
  int k = idx >> 7, c = idx & 127;
  unsigned short h_, l_;
  split2(src[idx], h_, l_);
  th[dstoff + c * K + k] = h_;
  tl[dstoff + c * K + k] = l_;
}

// ---------------- MFMA matmul ----------------
// C[M,128] = act(A[M,K] @ W[K,128] + b). A: split-bf16 (or fp32 with CONV,
// two source regions: Af rows [0,NLP) clamped to N_L, Af2 rows [NLP,..)).
// W pre-transposed split-bf16 Wt[128][K], read directly from global (shared,
// L1/L2-resident). A staged in LDS per 128-k chunk, XOR-swizzled 16B units:
// unit x of row r lives at slot r*16 + (x ^ (r&7)).

template <int K, bool CONV, bool RELU, bool BIAS, bool SPLITOUT>
__global__ __launch_bounds__(256) void mm_mfma(
    const float* __restrict__ Af, const float* __restrict__ Af2,
    const unsigned short* __restrict__ Ah, const unsigned short* __restrict__ Al,
    const unsigned short* __restrict__ Wth, const unsigned short* __restrict__ Wtl,
    const float* __restrict__ bias,
    float* __restrict__ Cf, unsigned short* __restrict__ Ch,
    unsigned short* __restrict__ Cl, int Mreal) {
  __shared__ __align__(16) char lds[65536];
  char* As_h = lds;
  char* As_l = lds + 32768;

  const int tid = threadIdx.x;
  const int lane = tid & 63;
  const int wv = tid >> 6;
  const int g = lane >> 4;
  const int li = lane & 15;
  const int row0 = blockIdx.x * 128;

  f32x4 acc[2][8];
#pragma unroll
  for (int m = 0; m < 2; ++m)
#pragma unroll
    for (int j = 0; j < 8; ++j) acc[m][j] = f32x4{0.f, 0.f, 0.f, 0.f};

  for (int kc = 0; kc < K; kc += 128) {
    if (kc) __syncthreads();  // protect LDS reuse across chunks
    if constexpr (!CONV) {
      const int rsub = lane >> 4;
      const int xl = lane & 15;
#pragma unroll
      for (int j = 0; j < 8; ++j) {
        int q = wv * 8 + j;           // KB index 0..31
        int r = q * 4 + rsub;         // row 0..127
        size_t gb = ((size_t)(row0 + r) * K + kc) * 2 + (size_t)((xl ^ (r & 7)) * 16);
        gload16((const char*)Ah + gb, As_h + q * 1024);
        gload16((const char*)Al + gb, As_l + q * 1024);
      }
    } else {
      // fp32 A -> split bf16, swizzled ds_write. 64 floats/thread.
      int r = tid >> 1, hf = tid & 1;
      int grow = row0 + r;
      const float* srcb;
      int lrow;
      if (grow < NLP) { srcb = Af; lrow = min(grow, Mreal - 1); }
      else            { srcb = Af2; lrow = grow - NLP; }
      const float* src = srcb + (size_t)lrow * K + kc + hf * 64;
#pragma unroll
      for (int i = 0; i < 8; ++i) {
        float4 a = ((const float4*)src)[2 * i];
        float4 b = ((const float4*)src)[2 * i + 1];
        float f[8] = {a.x, a.y, a.z, a.w, b.x, b.y, b.z, b.w};
        short8 vh, vl;
#pragma unroll
        for (int e = 0; e < 8; ++e) {
          unsigned short h_, l_;
          split2(f[e], h_, l_);
          vh[e] = (short)h_;
          vl[e] = (short)l_;
        }
        int x = hf * 8 + i;
        int u = r * 16 + (x ^ (r & 7));
        *(short8*)(As_h + u * 16) = vh;
        *(short8*)(As_l + u * 16) = vl;
      }
    }
    __syncthreads();

    // A fragments: row = wv*32 + m*16 + li, k = ks*32 + g*8 + e
    short8 fa_h[2][4], fa_l[2][4];
#pragma unroll
    for (int m = 0; m < 2; ++m)
#pragma unroll
      for (int ks = 0; ks < 4; ++ks) {
        int row = wv * 32 + m * 16 + li;
        int x = ks * 4 + g;
        int off = (row * 16 + (x ^ (row & 7))) * 16;
        fa_h[m][ks] = *(const short8*)(As_h + off);
        fa_l[m][ks] = *(const short8*)(As_l + off);
      }

    // B fragments straight from global (L1/L2-hot): col c, same k map
#pragma unroll
    for (int nh = 0; nh < 2; ++nh)
#pragma unroll
      for (int n = 0; n < 4; ++n) {
        int c = nh * 64 + n * 16 + li;
        const unsigned short* wbh = Wth + (size_t)c * K + kc + g * 8;
        const unsigned short* wbl = Wtl + (size_t)c * K + kc + g * 8;
        short8 fb_h[4], fb_l[4];
#pragma unroll
        for (int ks = 0; ks < 4; ++ks) {
          fb_h[ks] = *(const short8*)(wbh + ks * 32);
          fb_l[ks] = *(const short8*)(wbl + ks * 32);
        }
#pragma unroll
        for (int m = 0; m < 2; ++m) {
          f32x4 a_ = acc[m][nh * 4 + n];
#pragma unroll
          for (int ks = 0; ks < 4; ++ks) {
            a_ = __builtin_amdgcn_mfma_f32_16x16x32_bf16(fa_h[m][ks], fb_h[ks], a_, 0, 0, 0);
            a_ = __builtin_amdgcn_mfma_f32_16x16x32_bf16(fa_h[m][ks], fb_l[ks], a_, 0, 0, 0);
            a_ = __builtin_amdgcn_mfma_f32_16x16x32_bf16(fa_l[m][ks], fb_h[ks], a_, 0, 0, 0);
          }
          acc[m][nh * 4 + n] = a_;
        }
      }
  }

  // epilogue: D row = (lane>>4)*4 + reg, col = lane&15
#pragma unroll
  for (int m = 0; m < 2; ++m)
#pragma unroll
    for (int j = 0; j < 8; ++j) {
      int c = j * 16 + li;
      float bj = BIAS ? bias[c] : 0.f;
#pragma unroll
      for (int r = 0; r < 4; ++r) {
        int rowg = row0 + wv * 32 + m * 16 + g * 4 + r;
        float o = acc[m][j][r] + bj;
        if (RELU) o = fmaxf(o, 0.f);
        size_t idx = (size_t)rowg * 128 + c;
        if constexpr (SPLITOUT) {
          unsigned short h_, l_;
          split2(o, h_, l_);
          Ch[idx] = h_;
          Cl[idx] = l_;
        } else {
          Cf[idx] = o;
        }
      }
    }
}

// ---------------- GCN aggregation (gather), split-bf16 out ----------------
// swz=1: remap blocks so head graph g (4 MiB table) stays on XCD g.

__global__ __launch_bounds__(256) void agg_split(const float* __restrict__ Hin,
                                                 const float* __restrict__ dinvg,
                                                 const int* __restrict__ rowptr,
                                                 const int* __restrict__ col,
                                                 const float* __restrict__ bias,
                                                 unsigned short* __restrict__ Oh,
                                                 unsigned short* __restrict__ Ol,
                                                 int n, int base, int swz) {
  int b = blockIdx.x;
  if (swz) b = (b & 7) * (gridDim.x >> 3) + (b >> 3);
  int v = b * 4 + (threadIdx.x >> 6);
  int lane = threadIdx.x & 63;
  int gnode = base + v;
  float2 acc;
  acc.x = 0.f;
  acc.y = 0.f;
  if (v < n) {
    const float2* H2 = (const float2*)Hin;
    float dv = dinvg[gnode];
    float2 h = H2[(size_t)gnode * 64 + lane];
    acc.x = h.x * dv * dv;
    acc.y = h.y * dv * dv;
    int e = rowptr[v], e1 = rowptr[v + 1];
    for (; e + 8 <= e1; e += 8) {
      int u0 = col[e],     u1 = col[e + 1], u2 = col[e + 2], u3 = col[e + 3];
      int u4 = col[e + 4], u5 = col[e + 5], u6 = col[e + 6], u7 = col[e + 7];
      float c0 = dinvg[u0] * dv, c1 = dinvg[u1] * dv;
      float c2 = dinvg[u2] * dv, c3 = dinvg[u3] * dv;
      float c4 = dinvg[u4] * dv, c5 = dinvg[u5] * dv;
      float c6 = dinvg[u6] * dv, c7 = dinvg[u7] * dv;
      float2 x0 = H2[(size_t)u0 * 64 + lane];
      float2 x1 = H2[(size_t)u1 * 64 + lane];
      float2 x2 = H2[(size_t)u2 * 64 + lane];
      float2 x3 = H2[(size_t)u3 * 64 + lane];
      float2 x4 = H2[(size_t)u4 * 64 + lane];
      float2 x5 = H2[(size_t)u5 * 64 + lane];
      float2 x6 = H2[(size_t)u6 * 64 + lane];
      float2 x7 = H2[(size_t)u7 * 64 + lane];
      acc.x += x0.x * c0 + x1.x * c1 + x2.x * c2 + x3.x * c3;
      acc.y += x0.y * c0 + x1.y * c1 + x2.y * c2 + x3.y * c3;
      acc.x += x4.x * c4 + x5.x * c5 + x6.x * c6 + x7.x * c7;
      acc.y += x4.y * c4 + x5.y * c5 + x6.y * c6 + x7.y * c7;
    }
    for (; e < e1; ++e) {
      int u = col[e];
      float c = dinvg[u] * dv;
      float2 x = H2[(size_t)u * 64 + lane];
      acc.x += x.x * c;
      acc.y += x.y * c;
    }
    float2 b2 = ((const float2*)bias)[lane];
    acc.x = fmaxf(acc.x + b2.x, 0.f);
    acc.y = fmaxf(acc.y + b2.y, 0.f);
  }
  unsigned short hx, lx, hy, ly;
  split2(acc.x, hx, lx);
  split2(acc.y, hy, ly);
  ushort2 th, tl;
  th.x = hx; th.y = hy;
  tl.x = lx; tl.y = ly;
  ((ushort2*)Oh)[(size_t)gnode * 64 + lane] = th;
  ((ushort2*)Ol)[(size_t)gnode * 64 + lane] = tl;
}

// ---------------- heads ----------------

__global__ __launch_bounds__(256) void prob_kernel(const float* __restrict__ Hrelu,
                                                   const float* __restrict__ w2,
                                                   const float* __restrict__ b2,
                                                   float* __restrict__ out, int n) {
  int r = blockIdx.x * 4 + (threadIdx.x >> 6);
  if (r >= n) return;
  int lane = threadIdx.x & 63;
  float2 h = ((const float2*)Hrelu)[(size_t)r * 64 + lane];
  float2 w = ((const float2*)w2)[lane];
  float p = h.x * w.x + h.y * w.y;
  for (int off = 32; off; off >>= 1) p += __shfl_down(p, off);
  if (lane == 0) out[r] = 1.0f / (1.0f + expf(-(p + b2[0])));
}

__global__ __launch_bounds__(128) void colsum_split(const unsigned short* __restrict__ Hh,
                                                    const unsigned short* __restrict__ Hl,
                                                    float* __restrict__ hsum, int n) {
  int f = threadIdx.x;
  int r0 = blockIdx.x * 128;
  int r1 = min(r0 + 128, n);
  float acc = 0.f;
  for (int r = r0; r < r1; ++r) {
    size_t idx = (size_t)r * 128 + f;
    acc += bfhi_f(Hh[idx]) + bfhi_f(Hl[idx]);
  }
  atomicAdd(&hsum[f], acc);
}

__global__ __launch_bounds__(128) void value_kernel(const float* __restrict__ hsum,
                                                    const float* __restrict__ w1,
                                                    const float* __restrict__ b1,
                                                    const float* __restrict__ w2,
                                                    const float* __restrict__ b2,
                                                    float* __restrict__ out) {
  __shared__ float hm[128];
  __shared__ float red[128];
  int t = threadIdx.x;
  hm[t] = hsum[t] * (1.0f / (float)N_L);
  __syncthreads();
  float acc = b1[t];
  for (int k = 0; k < 128; ++k) acc = fmaf(hm[k], w1[k * 128 + t], acc);
  red[t] = fmaxf(acc, 0.f) * w2[t];
  for (int off = 64; off > 0; off >>= 1) {
    __syncthreads();
    if (t < off) red[t] += red[t + off];
  }
  __syncthreads();
  if (t == 0) out[0] = red[0] + b2[0];
}

__global__ __launch_bounds__(64) void mask_kernel(const float* __restrict__ lp,
                                                  float* __restrict__ out) {
  int i = threadIdx.x;
  if (i < L_H) out[i] = (lp[i] > 0.5f) ? 1.0f : 0.0f;
}

// ---------------- driver ----------------

extern "C" void kernel_launch(void* const* d_in, const int* in_sizes, int n_in,
                              void* d_out, int out_size, void* d_ws, size_t ws_size,
                              hipStream_t stream) {
  const float* x      = (const float*)d_in[0];
  const int*   ei     = (const int*)d_in[1];
  const float* head_x = (const float*)d_in[2];
  const int*   hei    = (const int*)d_in[3];
  const float* enc_w1 = (const float*)d_in[4];
  const float* enc_b1 = (const float*)d_in[5];
  const float* enc_w2 = (const float*)d_in[6];
  const float* enc_b2 = (const float*)d_in[7];
  const float* gnn_w1 = (const float*)d_in[8];
  const float* gnn_b1 = (const float*)d_in[9];
  const float* gnn_w2 = (const float*)d_in[10];
  const float* gnn_b2 = (const float*)d_in[11];
  const float* lp_w1  = (const float*)d_in[12];
  const float* lp_b1  = (const float*)d_in[13];
  const float* lp_w2  = (const float*)d_in[14];
  const float* lp_b2  = (const float*)d_in[15];
  const float* hp_w1  = (const float*)d_in[16];
  const float* hp_b1  = (const float*)d_in[17];
  const float* hp_w2  = (const float*)d_in[18];
  const float* hp_b2  = (const float*)d_in[19];
  const float* v_w1   = (const float*)d_in[20];
  const float* v_b1   = (const float*)d_in[21];
  const float* v_w2   = (const float*)d_in[22];
  const float* v_b2   = (const float*)d_in[23];
  float* out = (float*)d_out;

  // ---- workspace layout ----
  const size_t ELE = (size_t)R_T * 128;
  char* base = (char*)d_ws;
  float* SAf = (float*)base;
  unsigned short* SAh = (unsigned short*)base;
  unsigned short* SAl = SAh + ELE;
  char* baseB = base + ELE * 4;
  unsigned short* SBh = (unsigned short*)baseB;
  unsigned short* SBl = SBh + ELE;
  unsigned short* WTh = (unsigned short*)(baseB + ELE * 4);
  unsigned short* WTl = WTh + 114688;
  float* dinv_g = (float*)(WTl + 114688);
  float* hsum   = dinv_g + R_T;
  int* ip       = (int*)(hsum + 128);
  int* indeg_l  = ip;  ip += 40000;   // doubles as rowpos_l
  int* rowptr_l = ip;  ip += 40065;
  int* col_l    = ip;  ip += 640000;
  int* indeg_h  = ip;  ip += 65536;   // doubles as rowpos_h
  int* rowptr_h = ip;  ip += 65537;
  int* col_h    = ip;  ip += 1048576;
  int* bsum_l   = ip;  ip += 48;
  int* bsum_h   = ip;  ip += 72;

  const int WT_ENC1 = 0, WT_ENC2 = 32768, WT_G1 = 49152, WT_G2 = 65536,
            WT_LP = 81920, WT_HP = 98304;

  const int OUT_LP = 0, OUT_HP = N_L, OUT_MASK = N_L + N_HT, OUT_SV = N_L + N_HT + L_H;

  // ---- CSR + dinv + weight split ----
  hipMemsetAsync(indeg_l, 0, 40000 * sizeof(int), stream);
  hipMemsetAsync(indeg_h, 0, (size_t)N_HT * sizeof(int), stream);
  hipMemsetAsync(hsum, 0, 128 * sizeof(float), stream);

  conv_weights<<<448, 256, 0, stream>>>(enc_w1, enc_w2, gnn_w1, gnn_w2, lp_w1, hp_w1,
                                        WTh, WTl);

  count_deg_l<<<E_L / 256, 256, 0, stream>>>(ei, indeg_l);
  count_deg_h<<<E_HT / 256, 256, 0, stream>>>(hei, indeg_h);
  dinv_kernel<<<(N_L + 255) / 256, 256, 0, stream>>>(indeg_l, dinv_g, N_L);
  dinv_kernel<<<N_HT / 256, 256, 0, stream>>>(indeg_h, dinv_g + HBASE, N_HT);

  scan_block<<<40, 1024, 0, stream>>>(indeg_l, N_L, rowptr_l, bsum_l);
  scan_top<<<1, 64, 0, stream>>>(bsum_l, 40);
  scan_fix<<<(N_L + 256) / 256, 256, 0, stream>>>(rowptr_l, bsum_l, N_L, 40, indeg_l);
  fill_csr_l<<<E_L / 256, 256, 0, stream>>>(ei, indeg_l, col_l);

  scan_block<<<64, 1024, 0, stream>>>(indeg_h, N_HT, rowptr_h, bsum_h);
  scan_top<<<1, 64, 0, stream>>>(bsum_h, 64);
  scan_fix<<<(N_HT + 256) / 256, 256, 0, stream>>>(rowptr_h, bsum_h, N_HT, 64, indeg_h);
  fill_csr_h<<<E_HT / 256, 256, 0, stream>>>(hei, indeg_h, col_h);

  // ---- encoder: enc1 (merged layer+head, fp32 CONV), enc2 ----
  mm_mfma<256, true, true, true, true><<<R_T / 128, 256, 0, stream>>>(
      x, head_x, nullptr, nullptr, WTh + WT_ENC1, WTl + WT_ENC1, enc_b1,
      nullptr, SAh, SAl, N_L);

  mm_mfma<128, false, true, true, true><<<R_T / 128, 256, 0, stream>>>(
      nullptr, nullptr, SAh, SAl, WTh + WT_ENC2, WTl + WT_ENC2, enc_b2,
      nullptr, SBh, SBl, R_T);

  // ---- GCN layer 1 ----
  mm_mfma<128, false, false, false, false><<<R_T / 128, 256, 0, stream>>>(
      nullptr, nullptr, SBh, SBl, WTh + WT_G1, WTl + WT_G1, nullptr,
      SAf, nullptr, nullptr, R_T);
  agg_split<<<NLP / 4, 256, 0, stream>>>(SAf, dinv_g, rowptr_l, col_l, gnn_b1,
                                         SBh, SBl, N_L, 0, 0);
  agg_split<<<N_HT / 4, 256, 0, stream>>>(SAf, dinv_g, rowptr_h, col_h, gnn_b1,
                                          SBh, SBl, N_HT, HBASE, 1);

  // ---- GCN layer 2 ----
  mm_mfma<128, false, false, false, false><<<R_T / 128, 256, 0, stream>>>(
      nullptr, nullptr, SBh, SBl, WTh + WT_G2, WTl + WT_G2, nullptr,
      SAf, nullptr, nullptr, R_T);
  agg_split<<<NLP / 4, 256, 0, stream>>>(SAf, dinv_g, rowptr_l, col_l, gnn_b2,
                                         SBh, SBl, N_L, 0, 0);
  agg_split<<<N_HT / 4, 256, 0, stream>>>(SAf, dinv_g, rowptr_h, col_h, gnn_b2,
                                          SBh, SBl, N_HT, HBASE, 1);

  // ---- layer policy + value ----
  mm_mfma<128, false, true, true, false><<<NLP / 128, 256, 0, stream>>>(
      nullptr, nullptr, SBh, SBl, WTh + WT_LP, WTl + WT_LP, lp_b1,
      SAf, nullptr, nullptr, NLP);
  prob_kernel<<<N_L / 4, 256, 0, stream>>>(SAf, lp_w2, lp_b2, out + OUT_LP, N_L);

  colsum_split<<<(N_L + 127) / 128, 128, 0, stream>>>(SBh, SBl, hsum, N_L);
  value_kernel<<<1, 128, 0, stream>>>(hsum, v_w1, v_b1, v_w2, v_b2, out + OUT_SV);

  // ---- head policy ----
  mm_mfma<128, false, true, true, false><<<N_HT / 128, 256, 0, stream>>>(
      nullptr, nullptr, SBh + (size_t)HBASE * 128, SBl + (size_t)HBASE * 128,
      WTh + WT_HP, WTl + WT_HP, hp_b1,
      SAf, nullptr, nullptr, N_HT);
  prob_kernel<<<N_HT / 4, 256, 0, stream>>>(SAf, hp_w2, hp_b2, out + OUT_HP, N_HT);

  // ---- mask ----
  mask_kernel<<<1, 64, 0, stream>>>(out + OUT_LP, out + OUT_MASK);
}

// Round 4
// 567.316 us; speedup vs baseline: 1.3161x; 1.3161x over previous
//
#include <hip/hip_runtime.h>
#include <math.h>

// PruningAgent r3: r1's proven mm_mfma (A+W LDS-staged via global_load_lds,
// KC=64 chunks) + r2's XCD-swizzled head aggregation + fused policy heads
// (sigmoid(dot(relu(H),w2)+b2) computed in mm epilogue via shfl reduce).

typedef unsigned short ushort_t;
using short8 = __attribute__((ext_vector_type(8))) short;
using f32x4  = __attribute__((ext_vector_type(4))) float;

constexpr int N_L  = 40000;
constexpr int E_L  = 640000;
constexpr int H_   = 128;
constexpr int L_H  = 8;
constexpr int N_H1 = 8192;
constexpr int E_H1 = 131072;
constexpr int N_HT = 65536;    // 8*8192
constexpr int E_HT = 1048576;  // 8*131072
constexpr int NLP  = 40064;    // layer rows padded to 128
constexpr int R_T  = 105600;   // NLP + N_HT (combined row space)
constexpr int HBASE = 40064;   // head rows start here

// ---------------- numeric helpers ----------------

__device__ __forceinline__ unsigned short bf16_rne(float f) {
  unsigned u = __float_as_uint(f);
  unsigned r = u + 0x7FFFu + ((u >> 16) & 1u);
  return (unsigned short)(r >> 16);
}
__device__ __forceinline__ float bfhi_f(unsigned short h) {
  return __uint_as_float((unsigned)h << 16);
}
__device__ __forceinline__ void split2(float f, unsigned short& h, unsigned short& l) {
  h = bf16_rne(f);
  l = bf16_rne(f - bfhi_f(h));
}

__device__ __forceinline__ void gload16(const void* g, void* l) {
  __builtin_amdgcn_global_load_lds((__attribute__((address_space(1))) void*)(g),
                                   (__attribute__((address_space(3))) void*)(l),
                                   16, 0, 0);
}

// ---------------- degree / CSR build ----------------

__global__ __launch_bounds__(256) void count_deg_l(const int* __restrict__ ei,
                                                   int* __restrict__ indeg) {
  int i = blockIdx.x * 256 + threadIdx.x;
  if (i < E_L) atomicAdd(&indeg[ei[E_L + i]], 1);
}

__global__ __launch_bounds__(256) void count_deg_h(const int* __restrict__ hei,
                                                   int* __restrict__ indeg) {
  int i = blockIdx.x * 256 + threadIdx.x;
  if (i < E_HT) {
    int l = i >> 17, e = i & (E_H1 - 1);
    atomicAdd(&indeg[l * N_H1 + hei[l * 2 * E_H1 + E_H1 + e]], 1);
  }
}

__global__ __launch_bounds__(256) void dinv_kernel(const int* __restrict__ indeg,
                                                   float* __restrict__ dinv, int n) {
  int i = blockIdx.x * 256 + threadIdx.x;
  if (i < n) dinv[i] = 1.0f / sqrtf((float)(indeg[i] + 1));
}

__global__ __launch_bounds__(1024) void scan_block(const int* __restrict__ in, int n,
                                                   int* __restrict__ out,
                                                   int* __restrict__ bsum) {
  __shared__ int s[1024];
  int t = threadIdx.x;
  int i = blockIdx.x * 1024 + t;
  int v = (i < n) ? in[i] : 0;
  s[t] = v;
  __syncthreads();
  for (int off = 1; off < 1024; off <<= 1) {
    int x = (t >= off) ? s[t - off] : 0;
    __syncthreads();
    s[t] += x;
    __syncthreads();
  }
  if (i < n) out[i] = s[t] - v;
  if (t == 1023) bsum[blockIdx.x] = s[t];
}

__global__ __launch_bounds__(64) void scan_top(int* __restrict__ bsum, int nb) {
  int lane = threadIdx.x;
  int v = (lane < nb) ? bsum[lane] : 0;
  int incl = v;
  for (int off = 1; off < 64; off <<= 1) {
    int x = __shfl_up(incl, off);
    if (lane >= off) incl += x;
  }
  int total = __shfl(incl, 63);
  if (lane < nb) bsum[lane] = incl - v;
  if (lane == 0) bsum[nb] = total;
}

__global__ __launch_bounds__(256) void scan_fix(int* __restrict__ rowptr,
                                                const int* __restrict__ bsum,
                                                int n, int nb,
                                                int* __restrict__ rowpos) {
  int i = blockIdx.x * 256 + threadIdx.x;
  if (i < n) {
    int v = rowptr[i] + bsum[i >> 10];
    rowptr[i] = v;
    rowpos[i] = v;
  } else if (i == n) {
    rowptr[n] = bsum[nb];
  }
}

__global__ __launch_bounds__(256) void fill_csr_l(const int* __restrict__ ei,
                                                  int* __restrict__ rowpos,
                                                  int* __restrict__ col) {
  int i = blockIdx.x * 256 + threadIdx.x;
  if (i < E_L) {
    int dst = ei[E_L + i];
    int p = atomicAdd(&rowpos[dst], 1);
    col[p] = ei[i];
  }
}

__global__ __launch_bounds__(256) void fill_csr_h(const int* __restrict__ hei,
                                                  int* __restrict__ rowpos,
                                                  int* __restrict__ col) {
  int i = blockIdx.x * 256 + threadIdx.x;
  if (i < E_HT) {
    int l = i >> 17, e = i & (E_H1 - 1);
    int base = l * 2 * E_H1;
    int dst = l * N_H1 + hei[base + E_H1 + e];
    int src = l * N_H1 + hei[base + e];
    int p = atomicAdd(&rowpos[dst], 1);
    col[p] = HBASE + src;  // global row id
  }
}

// ---------------- weight pre-split (transposed) ----------------
// dst layout Wt[c][k] (hi/lo). element offsets:
// enc_w1:0 (K=256), enc_w2:32768, gnn_w1:49152, gnn_w2:65536, lp_w1:81920, hp_w1:98304

__global__ __launch_bounds__(256) void conv_weights(
    const float* __restrict__ w0, const float* __restrict__ w1,
    const float* __restrict__ w2, const float* __restrict__ w3,
    const float* __restrict__ w4, const float* __restrict__ w5,
    unsigned short* __restrict__ th, unsigned short* __restrict__ tl) {
  int t = blockIdx.x * 256 + threadIdx.x;
  const float* src; int K, dstoff, idx;
  if (t < 32768) { src = w0; K = 256; dstoff = 0; idx = t; }
  else {
    int s = (t - 32768) >> 14;
    idx = (t - 32768) & 16383;
    K = 128;
    dstoff = 32768 + s * 16384;
    src = s == 0 ? w1 : s == 1 ? w2 : s == 2 ? w3 : s == 3 ? w4 : w5;
  }
  int k = idx >> 7, c = idx & 127;
  unsigned short h_, l_;
  split2(src[idx], h_, l_);
  th[dstoff + c * K + k] = h_;
  tl[dstoff + c * K + k] = l_;
}

// ---------------- MFMA matmul (r1 structure) ----------------
// C[M,128] = act(A[M,K] @ W[K,128] + b), A split-bf16 (or fp32 w/ CONV),
// W pre-transposed split-bf16 Wt[128][K]. 128-row tile, 4 waves, KC=64.
// LDS XOR-swizzle: 16B unit x of row r stored at unit r*8 + (x ^ (r&7)).
// FUSE: epilogue computes sigmoid(dot(relu(o), pw2)+pb2) per row -> pout.

template <int K, bool CONV, bool RELU, bool BIAS, bool SPLITOUT, bool FUSE>
__global__ __launch_bounds__(256) void mm_mfma(
    const float* __restrict__ Af,
    const unsigned short* __restrict__ Ah, const unsigned short* __restrict__ Al,
    const unsigned short* __restrict__ Wth, const unsigned short* __restrict__ Wtl,
    const float* __restrict__ bias,
    float* __restrict__ Cf, unsigned short* __restrict__ Ch,
    unsigned short* __restrict__ Cl,
    const float* __restrict__ pw2, const float* __restrict__ pb2,
    float* __restrict__ pout, int Mreal, int nvalid) {
  __shared__ __align__(16) char lds[65536];
  char* As_h = lds;
  char* As_l = lds + 16384;
  char* Ws_h = lds + 32768;
  char* Ws_l = lds + 49152;

  const int tid = threadIdx.x;
  const int lane = tid & 63;
  const int wv = tid >> 6;
  const int g = lane >> 4;
  const int li = lane & 15;
  const int row0 = blockIdx.x * 128;

  f32x4 acc[2][8];
#pragma unroll
  for (int m = 0; m < 2; ++m)
#pragma unroll
    for (int j = 0; j < 8; ++j) acc[m][j] = f32x4{0.f, 0.f, 0.f, 0.f};

  const int rsub = lane >> 3;                    // row-within-8 for staging
  const int xr = (lane & 7) ^ ((lane >> 3) & 7); // pre-swizzled source unit

  for (int kc = 0; kc < K; kc += 64) {
    __syncthreads();
    // stage W chunk (both splits): 16 KB each, 4 issues/wave
#pragma unroll
    for (int j = 0; j < 4; ++j) {
      int q = wv * 4 + j;
      int c = q * 8 + rsub;
      size_t gb = ((size_t)c * K + kc) * 2 + (size_t)xr * 16;
      gload16((const char*)Wth + gb, Ws_h + q * 1024);
      gload16((const char*)Wtl + gb, Ws_l + q * 1024);
    }
    if constexpr (!CONV) {
#pragma unroll
      for (int j = 0; j < 4; ++j) {
        int q = wv * 4 + j;
        int r = q * 8 + rsub;
        size_t gb = ((size_t)(row0 + r) * K + kc) * 2 + (size_t)xr * 16;
        gload16((const char*)Ah + gb, As_h + q * 1024);
        gload16((const char*)Al + gb, As_l + q * 1024);
      }
    } else {
      // fp32 A -> convert to split bf16, swizzled ds_write
      int r = tid >> 1, hf = tid & 1;
      int grow = min(row0 + r, Mreal - 1);
      const float* src = Af + (size_t)grow * K + kc + hf * 32;
#pragma unroll
      for (int i = 0; i < 4; ++i) {
        float4 a = ((const float4*)src)[2 * i];
        float4 b = ((const float4*)src)[2 * i + 1];
        float f[8] = {a.x, a.y, a.z, a.w, b.x, b.y, b.z, b.w};
        short8 vh, vl;
#pragma unroll
        for (int e = 0; e < 8; ++e) {
          unsigned short h_, l_;
          split2(f[e], h_, l_);
          vh[e] = (short)h_;
          vl[e] = (short)l_;
        }
        int x = hf * 4 + i;
        int u = r * 8 + (x ^ (r & 7));
        *(short8*)(As_h + u * 16) = vh;
        *(short8*)(As_l + u * 16) = vl;
      }
    }
    __syncthreads();

    // A fragments: rows wv*32 + m*16 + li, k = ks*32 + 8g + e
    short8 fa_h[2][2], fa_l[2][2];
#pragma unroll
    for (int m = 0; m < 2; ++m)
#pragma unroll
      for (int ks = 0; ks < 2; ++ks) {
        int row = wv * 32 + m * 16 + li;
        int off = row * 128 + ks * 64 + g * 16;
        off ^= (row & 7) << 4;
        fa_h[m][ks] = *(const short8*)(As_h + off);
        fa_l[m][ks] = *(const short8*)(As_l + off);
      }
#pragma unroll
    for (int nh = 0; nh < 2; ++nh) {
      short8 fb_h[4][2], fb_l[4][2];
#pragma unroll
      for (int n = 0; n < 4; ++n)
#pragma unroll
        for (int ks = 0; ks < 2; ++ks) {
          int c = nh * 64 + n * 16 + li;
          int off = c * 128 + ks * 64 + g * 16;
          off ^= (c & 7) << 4;
          fb_h[n][ks] = *(const short8*)(Ws_h + off);
          fb_l[n][ks] = *(const short8*)(Ws_l + off);
        }
#pragma unroll
      for (int m = 0; m < 2; ++m)
#pragma unroll
        for (int n = 0; n < 4; ++n)
#pragma unroll
          for (int ks = 0; ks < 2; ++ks) {
            f32x4 a_ = acc[m][nh * 4 + n];
            a_ = __builtin_amdgcn_mfma_f32_16x16x32_bf16(fa_h[m][ks], fb_h[n][ks], a_, 0, 0, 0);
            a_ = __builtin_amdgcn_mfma_f32_16x16x32_bf16(fa_h[m][ks], fb_l[n][ks], a_, 0, 0, 0);
            a_ = __builtin_amdgcn_mfma_f32_16x16x32_bf16(fa_l[m][ks], fb_h[n][ks], a_, 0, 0, 0);
            acc[m][nh * 4 + n] = a_;
          }
    }
  }

  if constexpr (FUSE) {
    // fused policy head: p = sigmoid( sum_c relu(acc+bias)[c] * w2[c] + b2 )
    float w2c[8], bj[8];
#pragma unroll
    for (int j = 0; j < 8; ++j) {
      w2c[j] = pw2[j * 16 + li];
      bj[j]  = bias[j * 16 + li];
    }
#pragma unroll
    for (int m = 0; m < 2; ++m)
#pragma unroll
      for (int r = 0; r < 4; ++r) {
        float p = 0.f;
#pragma unroll
        for (int j = 0; j < 8; ++j) {
          float o = fmaxf(acc[m][j][r] + bj[j], 0.f);
          p = fmaf(o, w2c[j], p);
        }
        p += __shfl_xor(p, 1);
        p += __shfl_xor(p, 2);
        p += __shfl_xor(p, 4);
        p += __shfl_xor(p, 8);
        if (li == 0) {
          int rowg = row0 + wv * 32 + m * 16 + g * 4 + r;
          if (rowg < nvalid)
            pout[rowg] = 1.0f / (1.0f + expf(-(p + pb2[0])));
        }
      }
  } else {
    // epilogue: D row = (lane>>4)*4 + reg, col = lane&15
#pragma unroll
    for (int m = 0; m < 2; ++m)
#pragma unroll
      for (int j = 0; j < 8; ++j) {
        int c = j * 16 + li;
        float bv = BIAS ? bias[c] : 0.f;
#pragma unroll
        for (int r = 0; r < 4; ++r) {
          int rowg = row0 + wv * 32 + m * 16 + g * 4 + r;
          float o = acc[m][j][r] + bv;
          if (RELU) o = fmaxf(o, 0.f);
          size_t idx = (size_t)rowg * 128 + c;
          if constexpr (SPLITOUT) {
            unsigned short h_, l_;
            split2(o, h_, l_);
            Ch[idx] = h_;
            Cl[idx] = l_;
          } else {
            Cf[idx] = o;
          }
        }
      }
  }
}

// ---------------- GCN aggregation (gather), split-bf16 out ----------------
// swz=1: remap blocks so head graph g (4 MiB table) stays on one XCD.

__global__ __launch_bounds__(256) void agg_split(const float* __restrict__ Hin,
                                                 const float* __restrict__ dinvg,
                                                 const int* __restrict__ rowptr,
                                                 const int* __restrict__ col,
                                                 const float* __restrict__ bias,
                                                 unsigned short* __restrict__ Oh,
                                                 unsigned short* __restrict__ Ol,
                                                 int n, int base, int swz) {
  int b = blockIdx.x;
  if (swz) b = (b & 7) * (gridDim.x >> 3) + (b >> 3);
  int v = b * 4 + (threadIdx.x >> 6);
  int lane = threadIdx.x & 63;
  int gnode = base + v;
  float2 acc;
  acc.x = 0.f;
  acc.y = 0.f;
  if (v < n) {
    const float2* H2 = (const float2*)Hin;
    float dv = dinvg[gnode];
    float2 h = H2[(size_t)gnode * 64 + lane];
    acc.x = h.x * dv * dv;
    acc.y = h.y * dv * dv;
    int e = rowptr[v], e1 = rowptr[v + 1];
    for (; e + 8 <= e1; e += 8) {
      int u0 = col[e],     u1 = col[e + 1], u2 = col[e + 2], u3 = col[e + 3];
      int u4 = col[e + 4], u5 = col[e + 5], u6 = col[e + 6], u7 = col[e + 7];
      float c0 = dinvg[u0] * dv, c1 = dinvg[u1] * dv;
      float c2 = dinvg[u2] * dv, c3 = dinvg[u3] * dv;
      float c4 = dinvg[u4] * dv, c5 = dinvg[u5] * dv;
      float c6 = dinvg[u6] * dv, c7 = dinvg[u7] * dv;
      float2 x0 = H2[(size_t)u0 * 64 + lane];
      float2 x1 = H2[(size_t)u1 * 64 + lane];
      float2 x2 = H2[(size_t)u2 * 64 + lane];
      float2 x3 = H2[(size_t)u3 * 64 + lane];
      float2 x4 = H2[(size_t)u4 * 64 + lane];
      float2 x5 = H2[(size_t)u5 * 64 + lane];
      float2 x6 = H2[(size_t)u6 * 64 + lane];
      float2 x7 = H2[(size_t)u7 * 64 + lane];
      acc.x += x0.x * c0 + x1.x * c1 + x2.x * c2 + x3.x * c3;
      acc.y += x0.y * c0 + x1.y * c1 + x2.y * c2 + x3.y * c3;
      acc.x += x4.x * c4 + x5.x * c5 + x6.x * c6 + x7.x * c7;
      acc.y += x4.y * c4 + x5.y * c5 + x6.y * c6 + x7.y * c7;
    }
    for (; e < e1; ++e) {
      int u = col[e];
      float c = dinvg[u] * dv;
      float2 x = H2[(size_t)u * 64 + lane];
      acc.x += x.x * c;
      acc.y += x.y * c;
    }
    float2 b2 = ((const float2*)bias)[lane];
    acc.x = fmaxf(acc.x + b2.x, 0.f);
    acc.y = fmaxf(acc.y + b2.y, 0.f);
  }
  unsigned short hx, lx, hy, ly;
  split2(acc.x, hx, lx);
  split2(acc.y, hy, ly);
  ushort2 th, tl;
  th.x = hx; th.y = hy;
  tl.x = lx; tl.y = ly;
  ((ushort2*)Oh)[(size_t)gnode * 64 + lane] = th;
  ((ushort2*)Ol)[(size_t)gnode * 64 + lane] = tl;
}

// ---------------- value head ----------------

__global__ __launch_bounds__(128) void colsum_split(const unsigned short* __restrict__ Hh,
                                                    const unsigned short* __restrict__ Hl,
                                                    float* __restrict__ hsum, int n) {
  int f = threadIdx.x;
  int r0 = blockIdx.x * 128;
  int r1 = min(r0 + 128, n);
  float acc = 0.f;
  for (int r = r0; r < r1; ++r) {
    size_t idx = (size_t)r * 128 + f;
    acc += bfhi_f(Hh[idx]) + bfhi_f(Hl[idx]);
  }
  atomicAdd(&hsum[f], acc);
}

__global__ __launch_bounds__(128) void value_kernel(const float* __restrict__ hsum,
                                                    const float* __restrict__ w1,
                                                    const float* __restrict__ b1,
                                                    const float* __restrict__ w2,
                                                    const float* __restrict__ b2,
                                                    float* __restrict__ out) {
  __shared__ float hm[128];
  __shared__ float red[128];
  int t = threadIdx.x;
  hm[t] = hsum[t] * (1.0f / (float)N_L);
  __syncthreads();
  float acc = b1[t];
  for (int k = 0; k < 128; ++k) acc = fmaf(hm[k], w1[k * 128 + t], acc);
  red[t] = fmaxf(acc, 0.f) * w2[t];
  for (int off = 64; off > 0; off >>= 1) {
    __syncthreads();
    if (t < off) red[t] += red[t + off];
  }
  __syncthreads();
  if (t == 0) out[0] = red[0] + b2[0];
}

__global__ __launch_bounds__(64) void mask_kernel(const float* __restrict__ lp,
                                                  float* __restrict__ out) {
  int i = threadIdx.x;
  if (i < L_H) out[i] = (lp[i] > 0.5f) ? 1.0f : 0.0f;
}

// ---------------- driver ----------------

extern "C" void kernel_launch(void* const* d_in, const int* in_sizes, int n_in,
                              void* d_out, int out_size, void* d_ws, size_t ws_size,
                              hipStream_t stream) {
  const float* x      = (const float*)d_in[0];
  const int*   ei     = (const int*)d_in[1];
  const float* head_x = (const float*)d_in[2];
  const int*   hei    = (const int*)d_in[3];
  const float* enc_w1 = (const float*)d_in[4];
  const float* enc_b1 = (const float*)d_in[5];
  const float* enc_w2 = (const float*)d_in[6];
  const float* enc_b2 = (const float*)d_in[7];
  const float* gnn_w1 = (const float*)d_in[8];
  const float* gnn_b1 = (const float*)d_in[9];
  const float* gnn_w2 = (const float*)d_in[10];
  const float* gnn_b2 = (const float*)d_in[11];
  const float* lp_w1  = (const float*)d_in[12];
  const float* lp_b1  = (const float*)d_in[13];
  const float* lp_w2  = (const float*)d_in[14];
  const float* lp_b2  = (const float*)d_in[15];
  const float* hp_w1  = (const float*)d_in[16];
  const float* hp_b1  = (const float*)d_in[17];
  const float* hp_w2  = (const float*)d_in[18];
  const float* hp_b2  = (const float*)d_in[19];
  const float* v_w1   = (const float*)d_in[20];
  const float* v_b1   = (const float*)d_in[21];
  const float* v_w2   = (const float*)d_in[22];
  const float* v_b2   = (const float*)d_in[23];
  float* out = (float*)d_out;

  // ---- workspace layout ----
  const size_t ELE = (size_t)R_T * 128;
  char* base = (char*)d_ws;
  float* SAf = (float*)base;
  unsigned short* SAh = (unsigned short*)base;
  unsigned short* SAl = SAh + ELE;
  char* baseB = base + ELE * 4;
  unsigned short* SBh = (unsigned short*)baseB;
  unsigned short* SBl = SBh + ELE;
  unsigned short* WTh = (unsigned short*)(baseB + ELE * 4);
  unsigned short* WTl = WTh + 114688;
  float* dinv_g = (float*)(WTl + 114688);
  float* hsum   = dinv_g + R_T;
  int* ip       = (int*)(hsum + 128);
  int* indeg_l  = ip;  ip += 40000;   // doubles as rowpos_l
  int* rowptr_l = ip;  ip += 40065;
  int* col_l    = ip;  ip += 640000;
  int* indeg_h  = ip;  ip += 65536;   // doubles as rowpos_h
  int* rowptr_h = ip;  ip += 65537;
  int* col_h    = ip;  ip += 1048576;
  int* bsum_l   = ip;  ip += 48;
  int* bsum_h   = ip;  ip += 72;

  const int WT_ENC1 = 0, WT_ENC2 = 32768, WT_G1 = 49152, WT_G2 = 65536,
            WT_LP = 81920, WT_HP = 98304;

  const int OUT_LP = 0, OUT_HP = N_L, OUT_MASK = N_L + N_HT, OUT_SV = N_L + N_HT + L_H;

  // ---- CSR + dinv + weight split ----
  hipMemsetAsync(indeg_l, 0, 40000 * sizeof(int), stream);
  hipMemsetAsync(indeg_h, 0, (size_t)N_HT * sizeof(int), stream);
  hipMemsetAsync(hsum, 0, 128 * sizeof(float), stream);

  conv_weights<<<448, 256, 0, stream>>>(enc_w1, enc_w2, gnn_w1, gnn_w2, lp_w1, hp_w1,
                                        WTh, WTl);

  count_deg_l<<<E_L / 256, 256, 0, stream>>>(ei, indeg_l);
  count_deg_h<<<E_HT / 256, 256, 0, stream>>>(hei, indeg_h);
  dinv_kernel<<<(N_L + 255) / 256, 256, 0, stream>>>(indeg_l, dinv_g, N_L);
  dinv_kernel<<<N_HT / 256, 256, 0, stream>>>(indeg_h, dinv_g + HBASE, N_HT);

  scan_block<<<40, 1024, 0, stream>>>(indeg_l, N_L, rowptr_l, bsum_l);
  scan_top<<<1, 64, 0, stream>>>(bsum_l, 40);
  scan_fix<<<(N_L + 256) / 256, 256, 0, stream>>>(rowptr_l, bsum_l, N_L, 40, indeg_l);
  fill_csr_l<<<E_L / 256, 256, 0, stream>>>(ei, indeg_l, col_l);

  scan_block<<<64, 1024, 0, stream>>>(indeg_h, N_HT, rowptr_h, bsum_h);
  scan_top<<<1, 64, 0, stream>>>(bsum_h, 64);
  scan_fix<<<(N_HT + 256) / 256, 256, 0, stream>>>(rowptr_h, bsum_h, N_HT, 64, indeg_h);
  fill_csr_h<<<E_HT / 256, 256, 0, stream>>>(hei, indeg_h, col_h);

  // ---- encoder (enc1 layer + head, fp32 CONV path) ----
  mm_mfma<256, true, true, true, true, false><<<NLP / 128, 256, 0, stream>>>(
      x, nullptr, nullptr, WTh + WT_ENC1, WTl + WT_ENC1, enc_b1,
      nullptr, SAh, SAl, nullptr, nullptr, nullptr, N_L, 0);
  mm_mfma<256, true, true, true, true, false><<<N_HT / 128, 256, 0, stream>>>(
      head_x, nullptr, nullptr, WTh + WT_ENC1, WTl + WT_ENC1, enc_b1,
      nullptr, SAh + (size_t)HBASE * 128, SAl + (size_t)HBASE * 128,
      nullptr, nullptr, nullptr, N_HT, 0);

  mm_mfma<128, false, true, true, true, false><<<R_T / 128, 256, 0, stream>>>(
      nullptr, SAh, SAl, WTh + WT_ENC2, WTl + WT_ENC2, enc_b2,
      nullptr, SBh, SBl, nullptr, nullptr, nullptr, R_T, 0);

  // ---- GCN layer 1 ----
  mm_mfma<128, false, false, false, false, false><<<R_T / 128, 256, 0, stream>>>(
      nullptr, SBh, SBl, WTh + WT_G1, WTl + WT_G1, nullptr,
      SAf, nullptr, nullptr, nullptr, nullptr, nullptr, R_T, 0);
  agg_split<<<NLP / 4, 256, 0, stream>>>(SAf, dinv_g, rowptr_l, col_l, gnn_b1,
                                         SBh, SBl, N_L, 0, 0);
  agg_split<<<N_HT / 4, 256, 0, stream>>>(SAf, dinv_g, rowptr_h, col_h, gnn_b1,
                                          SBh, SBl, N_HT, HBASE, 1);

  // ---- GCN layer 2 ----
  mm_mfma<128, false, false, false, false, false><<<R_T / 128, 256, 0, stream>>>(
      nullptr, SBh, SBl, WTh + WT_G2, WTl + WT_G2, nullptr,
      SAf, nullptr, nullptr, nullptr, nullptr, nullptr, R_T, 0);
  agg_split<<<NLP / 4, 256, 0, stream>>>(SAf, dinv_g, rowptr_l, col_l, gnn_b2,
                                         SBh, SBl, N_L, 0, 0);
  agg_split<<<N_HT / 4, 256, 0, stream>>>(SAf, dinv_g, rowptr_h, col_h, gnn_b2,
                                          SBh, SBl, N_HT, HBASE, 1);

  // ---- layer policy (fused) + value ----
  mm_mfma<128, false, true, true, false, true><<<NLP / 128, 256, 0, stream>>>(
      nullptr, SBh, SBl, WTh + WT_LP, WTl + WT_LP, lp_b1,
      nullptr, nullptr, nullptr, lp_w2, lp_b2, out + OUT_LP, NLP, N_L);

  colsum_split<<<(N_L + 127) / 128, 128, 0, stream>>>(SBh, SBl, hsum, N_L);
  value_kernel<<<1, 128, 0, stream>>>(hsum, v_w1, v_b1, v_w2, v_b2, out + OUT_SV);

  // ---- head policy (fused) ----
  mm_mfma<128, false, true, true, false, true><<<N_HT / 128, 256, 0, stream>>>(
      nullptr, SBh + (size_t)HBASE * 128, SBl + (size_t)HBASE * 128,
      WTh + WT_HP, WTl + WT_HP, hp_b1,
      nullptr, nullptr, nullptr, hp_w2, hp_b2, out + OUT_HP, N_HT, N_HT);

  // ---- mask ----
  mask_kernel<<<1, 64, 0, stream>>>(out + OUT_LP, out + OUT_MASK);
}

// Round 5
// 539.956 us; speedup vs baseline: 1.3827x; 1.0507x over previous
//
#include <hip/hip_runtime.h>
#include <hip/hip_fp16.h>
#include <math.h>

// PruningAgent r4:
//  - agg: packed-edge CSR (uint = src | fp16(dinv_s*dinv_d)<<17), lane-
//    cooperative 16-edge batches (1 coalesced edge load + 16 in-flight
//    H gathers), combined layer+head dispatch w/ per-XCD graph pinning.
//  - mm: r1-proven structure; enc1 layer+head merged; lp+hp merged (fused
//    sigmoid epilogue). Split-bf16 x3-MFMA fp32-accuracy everywhere.

typedef unsigned short ushort_t;
using short8 = __attribute__((ext_vector_type(8))) short;
using f32x4  = __attribute__((ext_vector_type(4))) float;

constexpr int N_L  = 40000;
constexpr int E_L  = 640000;
constexpr int H_   = 128;
constexpr int L_H  = 8;
constexpr int N_H1 = 8192;
constexpr int E_H1 = 131072;
constexpr int N_HT = 65536;    // 8*8192
constexpr int E_HT = 1048576;  // 8*131072
constexpr int E_T  = E_L + E_HT;
constexpr int NLP  = 40064;    // layer rows padded to 128
constexpr int R_T  = 105600;   // NLP + N_HT (combined row space)
constexpr int HBASE = 40064;   // head rows start here

// ---------------- numeric helpers ----------------

__device__ __forceinline__ unsigned short bf16_rne(float f) {
  unsigned u = __float_as_uint(f);
  unsigned r = u + 0x7FFFu + ((u >> 16) & 1u);
  return (unsigned short)(r >> 16);
}
__device__ __forceinline__ float bfhi_f(unsigned short h) {
  return __uint_as_float((unsigned)h << 16);
}
__device__ __forceinline__ void split2(float f, unsigned short& h, unsigned short& l) {
  h = bf16_rne(f);
  l = bf16_rne(f - bfhi_f(h));
}

__device__ __forceinline__ void gload16(const void* g, void* l) {
  __builtin_amdgcn_global_load_lds((__attribute__((address_space(1))) void*)(g),
                                   (__attribute__((address_space(3))) void*)(l),
                                   16, 0, 0);
}

// ---------------- degree / CSR build (combined graph) ----------------

__global__ __launch_bounds__(256) void count_deg_l(const int* __restrict__ ei,
                                                   int* __restrict__ indeg) {
  int i = blockIdx.x * 256 + threadIdx.x;
  if (i < E_L) atomicAdd(&indeg[ei[E_L + i]], 1);
}

__global__ __launch_bounds__(256) void count_deg_h(const int* __restrict__ hei,
                                                   int* __restrict__ indeg) {
  int i = blockIdx.x * 256 + threadIdx.x;
  if (i < E_HT) {
    int l = i >> 17, e = i & (E_H1 - 1);
    atomicAdd(&indeg[HBASE + l * N_H1 + hei[l * 2 * E_H1 + E_H1 + e]], 1);
  }
}

__global__ __launch_bounds__(256) void dinv_kernel(const int* __restrict__ indeg,
                                                   float* __restrict__ dinv, int n) {
  int i = blockIdx.x * 256 + threadIdx.x;
  if (i < n) dinv[i] = 1.0f / sqrtf((float)(indeg[i] + 1));
}

__global__ __launch_bounds__(1024) void scan_block(const int* __restrict__ in, int n,
                                                   int* __restrict__ out,
                                                   int* __restrict__ bsum) {
  __shared__ int s[1024];
  int t = threadIdx.x;
  int i = blockIdx.x * 1024 + t;
  int v = (i < n) ? in[i] : 0;
  s[t] = v;
  __syncthreads();
  for (int off = 1; off < 1024; off <<= 1) {
    int x = (t >= off) ? s[t - off] : 0;
    __syncthreads();
    s[t] += x;
    __syncthreads();
  }
  if (i < n) out[i] = s[t] - v;
  if (t == 1023) bsum[blockIdx.x] = s[t];
}

// single wave: exclusive scan of <=128 block sums; total at bsum[nb]
__global__ __launch_bounds__(64) void scan_top128(int* __restrict__ bsum, int nb) {
  int lane = threadIdx.x;
  int a = (lane < nb) ? bsum[lane] : 0;
  int b = (lane + 64 < nb) ? bsum[lane + 64] : 0;
  int ia = a;
  for (int off = 1; off < 64; off <<= 1) {
    int x = __shfl_up(ia, off);
    if (lane >= off) ia += x;
  }
  int ta = __shfl(ia, 63);
  int ib = b;
  for (int off = 1; off < 64; off <<= 1) {
    int x = __shfl_up(ib, off);
    if (lane >= off) ib += x;
  }
  int tb = __shfl(ib, 63);
  if (lane < nb) bsum[lane] = ia - a;
  if (lane + 64 < nb) bsum[lane + 64] = ta + ib - b;
  if (lane == 0) bsum[nb] = ta + tb;
}

__global__ __launch_bounds__(256) void scan_fix(int* __restrict__ rowptr,
                                                const int* __restrict__ bsum,
                                                int n, int nb,
                                                int* __restrict__ rowpos) {
  int i = blockIdx.x * 256 + threadIdx.x;
  if (i < n) {
    int v = rowptr[i] + bsum[i >> 10];
    rowptr[i] = v;
    rowpos[i] = v;
  } else if (i == n) {
    rowptr[n] = bsum[nb];
  }
}

// packed edge: src(17b) | fp16_bits(cw)<<17  (cw > 0 so sign bit is free)
__device__ __forceinline__ unsigned pack_edge(int src, float cw) {
  unsigned short hb = __half_as_ushort(__float2half(cw));
  return (unsigned)src | ((unsigned)hb << 17);
}

__global__ __launch_bounds__(256) void fill_csr_l(const int* __restrict__ ei,
                                                  const float* __restrict__ dinvg,
                                                  int* __restrict__ rowpos,
                                                  unsigned* __restrict__ eg) {
  int i = blockIdx.x * 256 + threadIdx.x;
  if (i < E_L) {
    int dst = ei[E_L + i];
    int src = ei[i];
    int p = atomicAdd(&rowpos[dst], 1);
    eg[p] = pack_edge(src, dinvg[src] * dinvg[dst]);
  }
}

__global__ __launch_bounds__(256) void fill_csr_h(const int* __restrict__ hei,
                                                  const float* __restrict__ dinvg,
                                                  int* __restrict__ rowpos,
                                                  unsigned* __restrict__ eg) {
  int i = blockIdx.x * 256 + threadIdx.x;
  if (i < E_HT) {
    int l = i >> 17, e = i & (E_H1 - 1);
    int base = l * 2 * E_H1;
    int dst = HBASE + l * N_H1 + hei[base + E_H1 + e];
    int src = HBASE + l * N_H1 + hei[base + e];
    int p = atomicAdd(&rowpos[dst], 1);
    eg[p] = pack_edge(src, dinvg[src] * dinvg[dst]);
  }
}

// ---------------- weight pre-split (transposed) ----------------

__global__ __launch_bounds__(256) void conv_weights(
    const float* __restrict__ w0, const float* __restrict__ w1,
    const float* __restrict__ w2, const float* __restrict__ w3,
    const float* __restrict__ w4, const float* __restrict__ w5,
    unsigned short* __restrict__ th, unsigned short* __restrict__ tl) {
  int t = blockIdx.x * 256 + threadIdx.x;
  const float* src; int K, dstoff, idx;
  if (t < 32768) { src = w0; K = 256; dstoff = 0; idx = t; }
  else {
    int s = (t - 32768) >> 14;
    idx = (t - 32768) & 16383;
    K = 128;
    dstoff = 32768 + s * 16384;
    src = s == 0 ? w1 : s == 1 ? w2 : s == 2 ? w3 : s == 3 ? w4 : w5;
  }
  int k = idx >> 7, c = idx & 127;
  unsigned short h_, l_;
  split2(src[idx], h_, l_);
  th[dstoff + c * K + k] = h_;
  tl[dstoff + c * K + k] = l_;
}

// ---------------- MFMA matmul (r1 structure) ----------------

template <int K, bool CONV, bool RELU, bool SPLITOUT>
__global__ __launch_bounds__(256) void mm_mfma(
    const float* __restrict__ Af, const float* __restrict__ Af2,
    const unsigned short* __restrict__ Ah, const unsigned short* __restrict__ Al,
    const unsigned short* __restrict__ Wth, const unsigned short* __restrict__ Wtl,
    const float* __restrict__ bias,
    float* __restrict__ Cf, unsigned short* __restrict__ Ch,
    unsigned short* __restrict__ Cl) {
  __shared__ __align__(16) char lds[65536];
  char* As_h = lds;
  char* As_l = lds + 16384;
  char* Ws_h = lds + 32768;
  char* Ws_l = lds + 49152;

  const int tid = threadIdx.x;
  const int lane = tid & 63;
  const int wv = tid >> 6;
  const int g = lane >> 4;
  const int li = lane & 15;
  const int row0 = blockIdx.x * 128;

  f32x4 acc[2][8];
#pragma unroll
  for (int m = 0; m < 2; ++m)
#pragma unroll
    for (int j = 0; j < 8; ++j) acc[m][j] = f32x4{0.f, 0.f, 0.f, 0.f};

  const int rsub = lane >> 3;
  const int xr = (lane & 7) ^ ((lane >> 3) & 7);

  for (int kc = 0; kc < K; kc += 64) {
    __syncthreads();
#pragma unroll
    for (int j = 0; j < 4; ++j) {
      int q = wv * 4 + j;
      int c = q * 8 + rsub;
      size_t gb = ((size_t)c * K + kc) * 2 + (size_t)xr * 16;
      gload16((const char*)Wth + gb, Ws_h + q * 1024);
      gload16((const char*)Wtl + gb, Ws_l + q * 1024);
    }
    if constexpr (!CONV) {
#pragma unroll
      for (int j = 0; j < 4; ++j) {
        int q = wv * 4 + j;
        int r = q * 8 + rsub;
        size_t gb = ((size_t)(row0 + r) * K + kc) * 2 + (size_t)xr * 16;
        gload16((const char*)Ah + gb, As_h + q * 1024);
        gload16((const char*)Al + gb, As_l + q * 1024);
      }
    } else {
      // fp32 A (two source regions) -> split bf16, swizzled ds_write
      int r = tid >> 1, hf = tid & 1;
      int grow = row0 + r;
      const float* srcb;
      int lrow;
      if (grow < NLP) { srcb = Af;  lrow = min(grow, N_L - 1); }
      else            { srcb = Af2; lrow = grow - NLP; }
      const float* src = srcb + (size_t)lrow * K + kc + hf * 32;
#pragma unroll
      for (int i = 0; i < 4; ++i) {
        float4 a = ((const float4*)src)[2 * i];
        float4 b = ((const float4*)src)[2 * i + 1];
        float f[8] = {a.x, a.y, a.z, a.w, b.x, b.y, b.z, b.w};
        short8 vh, vl;
#pragma unroll
        for (int e = 0; e < 8; ++e) {
          unsigned short h_, l_;
          split2(f[e], h_, l_);
          vh[e] = (short)h_;
          vl[e] = (short)l_;
        }
        int x = hf * 4 + i;
        int u = r * 8 + (x ^ (r & 7));
        *(short8*)(As_h + u * 16) = vh;
        *(short8*)(As_l + u * 16) = vl;
      }
    }
    __syncthreads();

    short8 fa_h[2][2], fa_l[2][2];
#pragma unroll
    for (int m = 0; m < 2; ++m)
#pragma unroll
      for (int ks = 0; ks < 2; ++ks) {
        int row = wv * 32 + m * 16 + li;
        int off = row * 128 + ks * 64 + g * 16;
        off ^= (row & 7) << 4;
        fa_h[m][ks] = *(const short8*)(As_h + off);
        fa_l[m][ks] = *(const short8*)(As_l + off);
      }
#pragma unroll
    for (int nh = 0; nh < 2; ++nh) {
      short8 fb_h[4][2], fb_l[4][2];
#pragma unroll
      for (int n = 0; n < 4; ++n)
#pragma unroll
        for (int ks = 0; ks < 2; ++ks) {
          int c = nh * 64 + n * 16 + li;
          int off = c * 128 + ks * 64 + g * 16;
          off ^= (c & 7) << 4;
          fb_h[n][ks] = *(const short8*)(Ws_h + off);
          fb_l[n][ks] = *(const short8*)(Ws_l + off);
        }
#pragma unroll
      for (int m = 0; m < 2; ++m)
#pragma unroll
        for (int n = 0; n < 4; ++n)
#pragma unroll
          for (int ks = 0; ks < 2; ++ks) {
            f32x4 a_ = acc[m][nh * 4 + n];
            a_ = __builtin_amdgcn_mfma_f32_16x16x32_bf16(fa_h[m][ks], fb_h[n][ks], a_, 0, 0, 0);
            a_ = __builtin_amdgcn_mfma_f32_16x16x32_bf16(fa_h[m][ks], fb_l[n][ks], a_, 0, 0, 0);
            a_ = __builtin_amdgcn_mfma_f32_16x16x32_bf16(fa_l[m][ks], fb_h[n][ks], a_, 0, 0, 0);
            acc[m][nh * 4 + n] = a_;
          }
    }
  }

  // epilogue: D row = (lane>>4)*4 + reg, col = lane&15
#pragma unroll
  for (int m = 0; m < 2; ++m)
#pragma unroll
    for (int j = 0; j < 8; ++j) {
      int c = j * 16 + li;
      float bv = bias ? bias[c] : 0.f;
#pragma unroll
      for (int r = 0; r < 4; ++r) {
        int rowg = row0 + wv * 32 + m * 16 + g * 4 + r;
        float o = acc[m][j][r] + bv;
        if (RELU) o = fmaxf(o, 0.f);
        size_t idx = (size_t)rowg * 128 + c;
        if constexpr (SPLITOUT) {
          unsigned short h_, l_;
          split2(o, h_, l_);
          Ch[idx] = h_;
          Cl[idx] = l_;
        } else {
          Cf[idx] = o;
        }
      }
    }
}

// ---------------- fused policy matmul (lp rows<NLP, hp rows>=NLP) --------

__global__ __launch_bounds__(256) void mm_policy(
    const unsigned short* __restrict__ Ah, const unsigned short* __restrict__ Al,
    const unsigned short* __restrict__ Wth_l, const unsigned short* __restrict__ Wtl_l,
    const unsigned short* __restrict__ Wth_h, const unsigned short* __restrict__ Wtl_h,
    const float* __restrict__ b1l, const float* __restrict__ b1h,
    const float* __restrict__ w2l, const float* __restrict__ w2h,
    const float* __restrict__ b2l, const float* __restrict__ b2h,
    float* __restrict__ out_l, float* __restrict__ out_h) {
  constexpr int K = 128;
  __shared__ __align__(16) char lds[65536];
  char* As_h = lds;
  char* As_l = lds + 16384;
  char* Ws_h = lds + 32768;
  char* Ws_l = lds + 49152;

  const int tid = threadIdx.x;
  const int lane = tid & 63;
  const int wv = tid >> 6;
  const int g = lane >> 4;
  const int li = lane & 15;
  const int row0 = blockIdx.x * 128;
  const bool isl = row0 < NLP;

  const unsigned short* Wth = isl ? Wth_l : Wth_h;
  const unsigned short* Wtl = isl ? Wtl_l : Wtl_h;
  const float* bias = isl ? b1l : b1h;
  const float* pw2  = isl ? w2l : w2h;
  const float* pb2  = isl ? b2l : b2h;

  f32x4 acc[2][8];
#pragma unroll
  for (int m = 0; m < 2; ++m)
#pragma unroll
    for (int j = 0; j < 8; ++j) acc[m][j] = f32x4{0.f, 0.f, 0.f, 0.f};

  const int rsub = lane >> 3;
  const int xr = (lane & 7) ^ ((lane >> 3) & 7);

  for (int kc = 0; kc < K; kc += 64) {
    __syncthreads();
#pragma unroll
    for (int j = 0; j < 4; ++j) {
      int q = wv * 4 + j;
      int c = q * 8 + rsub;
      size_t gb = ((size_t)c * K + kc) * 2 + (size_t)xr * 16;
      gload16((const char*)Wth + gb, Ws_h + q * 1024);
      gload16((const char*)Wtl + gb, Ws_l + q * 1024);
      int r = q * 8 + rsub;
      size_t ga = ((size_t)(row0 + r) * K + kc) * 2 + (size_t)xr * 16;
      gload16((const char*)Ah + ga, As_h + q * 1024);
      gload16((const char*)Al + ga, As_l + q * 1024);
    }
    __syncthreads();

    short8 fa_h[2][2], fa_l[2][2];
#pragma unroll
    for (int m = 0; m < 2; ++m)
#pragma unroll
      for (int ks = 0; ks < 2; ++ks) {
        int row = wv * 32 + m * 16 + li;
        int off = row * 128 + ks * 64 + g * 16;
        off ^= (row & 7) << 4;
        fa_h[m][ks] = *(const short8*)(As_h + off);
        fa_l[m][ks] = *(const short8*)(As_l + off);
      }
#pragma unroll
    for (int nh = 0; nh < 2; ++nh) {
      short8 fb_h[4][2], fb_l[4][2];
#pragma unroll
      for (int n = 0; n < 4; ++n)
#pragma unroll
        for (int ks = 0; ks < 2; ++ks) {
          int c = nh * 64 + n * 16 + li;
          int off = c * 128 + ks * 64 + g * 16;
          off ^= (c & 7) << 4;
          fb_h[n][ks] = *(const short8*)(Ws_h + off);
          fb_l[n][ks] = *(const short8*)(Ws_l + off);
        }
#pragma unroll
      for (int m = 0; m < 2; ++m)
#pragma unroll
        for (int n = 0; n < 4; ++n)
#pragma unroll
          for (int ks = 0; ks < 2; ++ks) {
            f32x4 a_ = acc[m][nh * 4 + n];
            a_ = __builtin_amdgcn_mfma_f32_16x16x32_bf16(fa_h[m][ks], fb_h[n][ks], a_, 0, 0, 0);
            a_ = __builtin_amdgcn_mfma_f32_16x16x32_bf16(fa_h[m][ks], fb_l[n][ks], a_, 0, 0, 0);
            a_ = __builtin_amdgcn_mfma_f32_16x16x32_bf16(fa_l[m][ks], fb_h[n][ks], a_, 0, 0, 0);
            acc[m][nh * 4 + n] = a_;
          }
    }
  }

  // fused head: p = sigmoid( sum_c relu(acc+b1)[c] * w2[c] + b2 )
  float w2c[8], bj[8];
#pragma unroll
  for (int j = 0; j < 8; ++j) {
    w2c[j] = pw2[j * 16 + li];
    bj[j]  = bias[j * 16 + li];
  }
#pragma unroll
  for (int m = 0; m < 2; ++m)
#pragma unroll
    for (int r = 0; r < 4; ++r) {
      float p = 0.f;
#pragma unroll
      for (int j = 0; j < 8; ++j) {
        float o = fmaxf(acc[m][j][r] + bj[j], 0.f);
        p = fmaf(o, w2c[j], p);
      }
      p += __shfl_xor(p, 1);
      p += __shfl_xor(p, 2);
      p += __shfl_xor(p, 4);
      p += __shfl_xor(p, 8);
      if (li == 0) {
        int rowg = row0 + wv * 32 + m * 16 + g * 4 + r;
        if (isl) {
          if (rowg < N_L) out_l[rowg] = 1.0f / (1.0f + expf(-(p + pb2[0])));
        } else {
          out_h[rowg - HBASE] = 1.0f / (1.0f + expf(-(p + pb2[0])));
        }
      }
    }
}

// ---------------- GCN aggregation (combined graphs, packed edges) --------
// out[v] = relu( dinv[v]^2*h[v] + sum_e c_e*h[src_e] + b ), split-bf16 out.
// Swizzle: XCD x <- layer chunk x (1252 blocks) + head graph x (2048 blocks).

__global__ __launch_bounds__(256) void agg_packed(const float* __restrict__ Hin,
                                                  const float* __restrict__ dinvg,
                                                  const int* __restrict__ rowptr,
                                                  const unsigned* __restrict__ eg,
                                                  const float* __restrict__ bias,
                                                  unsigned short* __restrict__ Oh,
                                                  unsigned short* __restrict__ Ol) {
  int b = blockIdx.x;                 // 26400 blocks
  {
    int x = b & 7, j = b >> 3;        // j in [0,3300)
    b = (j < 1252) ? (x * 1252 + j) : (10016 + x * 2048 + (j - 1252));
  }
  int v = b * 4 + (threadIdx.x >> 6);
  int lane = threadIdx.x & 63;
  const float2* H2 = (const float2*)Hin;

  float dv = dinvg[v];
  float2 h = H2[(size_t)v * 64 + lane];
  float2 acc;
  acc.x = h.x * dv * dv;
  acc.y = h.y * dv * dv;

  int e0 = rowptr[v], e1 = rowptr[v + 1];
  for (int e = e0; e < e1; e += 16) {
    unsigned pr = 0;
    if (lane < 16) pr = eg[e + lane];   // eg padded by 16 entries
    float2 xs[16];
    float cs[16];
#pragma unroll
    for (int i = 0; i < 16; ++i) {
      if (e + i < e1) {
        unsigned pe = (unsigned)__shfl((int)pr, i);
        int u = pe & 0x1FFFF;
        cs[i] = __half2float(__ushort_as_half((unsigned short)(pe >> 17)));
        xs[i] = H2[(size_t)u * 64 + lane];
      } else {
        cs[i] = 0.f;
        xs[i].x = 0.f;
        xs[i].y = 0.f;
      }
    }
#pragma unroll
    for (int i = 0; i < 16; ++i) {
      acc.x = fmaf(xs[i].x, cs[i], acc.x);
      acc.y = fmaf(xs[i].y, cs[i], acc.y);
    }
  }

  float2 b2 = ((const float2*)bias)[lane];
  acc.x = fmaxf(acc.x + b2.x, 0.f);
  acc.y = fmaxf(acc.y + b2.y, 0.f);

  unsigned short hx, lx, hy, ly;
  split2(acc.x, hx, lx);
  split2(acc.y, hy, ly);
  ushort2 th, tl;
  th.x = hx; th.y = hy;
  tl.x = lx; tl.y = ly;
  ((ushort2*)Oh)[(size_t)v * 64 + lane] = th;
  ((ushort2*)Ol)[(size_t)v * 64 + lane] = tl;
}

// ---------------- value head ----------------

__global__ __launch_bounds__(128) void colsum_split(const unsigned short* __restrict__ Hh,
                                                    const unsigned short* __restrict__ Hl,
                                                    float* __restrict__ hsum, int n) {
  int f = threadIdx.x;
  int r0 = blockIdx.x * 128;
  int r1 = min(r0 + 128, n);
  float acc = 0.f;
  for (int r = r0; r < r1; ++r) {
    size_t idx = (size_t)r * 128 + f;
    acc += bfhi_f(Hh[idx]) + bfhi_f(Hl[idx]);
  }
  atomicAdd(&hsum[f], acc);
}

__global__ __launch_bounds__(128) void value_kernel(const float* __restrict__ hsum,
                                                    const float* __restrict__ w1,
                                                    const float* __restrict__ b1,
                                                    const float* __restrict__ w2,
                                                    const float* __restrict__ b2,
                                                    float* __restrict__ out) {
  __shared__ float hm[128];
  __shared__ float red[128];
  int t = threadIdx.x;
  hm[t] = hsum[t] * (1.0f / (float)N_L);
  __syncthreads();
  float acc = b1[t];
  for (int k = 0; k < 128; ++k) acc = fmaf(hm[k], w1[k * 128 + t], acc);
  red[t] = fmaxf(acc, 0.f) * w2[t];
  for (int off = 64; off > 0; off >>= 1) {
    __syncthreads();
    if (t < off) red[t] += red[t + off];
  }
  __syncthreads();
  if (t == 0) out[0] = red[0] + b2[0];
}

__global__ __launch_bounds__(64) void mask_kernel(const float* __restrict__ lp,
                                                  float* __restrict__ out) {
  int i = threadIdx.x;
  if (i < L_H) out[i] = (lp[i] > 0.5f) ? 1.0f : 0.0f;
}

// ---------------- driver ----------------

extern "C" void kernel_launch(void* const* d_in, const int* in_sizes, int n_in,
                              void* d_out, int out_size, void* d_ws, size_t ws_size,
                              hipStream_t stream) {
  const float* x      = (const float*)d_in[0];
  const int*   ei     = (const int*)d_in[1];
  const float* head_x = (const float*)d_in[2];
  const int*   hei    = (const int*)d_in[3];
  const float* enc_w1 = (const float*)d_in[4];
  const float* enc_b1 = (const float*)d_in[5];
  const float* enc_w2 = (const float*)d_in[6];
  const float* enc_b2 = (const float*)d_in[7];
  const float* gnn_w1 = (const float*)d_in[8];
  const float* gnn_b1 = (const float*)d_in[9];
  const float* gnn_w2 = (const float*)d_in[10];
  const float* gnn_b2 = (const float*)d_in[11];
  const float* lp_w1  = (const float*)d_in[12];
  const float* lp_b1  = (const float*)d_in[13];
  const float* lp_w2  = (const float*)d_in[14];
  const float* lp_b2  = (const float*)d_in[15];
  const float* hp_w1  = (const float*)d_in[16];
  const float* hp_b1  = (const float*)d_in[17];
  const float* hp_w2  = (const float*)d_in[18];
  const float* hp_b2  = (const float*)d_in[19];
  const float* v_w1   = (const float*)d_in[20];
  const float* v_b1   = (const float*)d_in[21];
  const float* v_w2   = (const float*)d_in[22];
  const float* v_b2   = (const float*)d_in[23];
  float* out = (float*)d_out;

  // ---- workspace layout ----
  const size_t ELE = (size_t)R_T * 128;
  char* base = (char*)d_ws;
  float* SAf = (float*)base;                   // SLOT_A union fp32 / split
  unsigned short* SAh = (unsigned short*)base;
  unsigned short* SAl = SAh + ELE;
  char* baseB = base + ELE * 4;
  unsigned short* SBh = (unsigned short*)baseB;
  unsigned short* SBl = SBh + ELE;
  unsigned short* WTh = (unsigned short*)(baseB + ELE * 4);
  unsigned short* WTl = WTh + 114688;
  float* dinv_g = (float*)(WTl + 114688);      // [R_T]
  float* hsum   = dinv_g + R_T;                // [128]
  int* ip       = (int*)(hsum + 128);
  int* indeg_g  = ip;  ip += R_T;              // doubles as rowpos
  int* rowptr_g = ip;  ip += R_T + 1;
  unsigned* eg  = (unsigned*)ip;  ip += E_T + 16;
  int* bsum     = ip;  ip += 112;

  const int WT_ENC1 = 0, WT_ENC2 = 32768, WT_G1 = 49152, WT_G2 = 65536,
            WT_LP = 81920, WT_HP = 98304;

  const int OUT_LP = 0, OUT_HP = N_L, OUT_MASK = N_L + N_HT, OUT_SV = N_L + N_HT + L_H;

  // ---- CSR + dinv + weight split ----
  hipMemsetAsync(indeg_g, 0, (size_t)R_T * sizeof(int), stream);
  hipMemsetAsync(dinv_g, 0, (size_t)R_T * sizeof(float), stream);
  hipMemsetAsync(hsum, 0, 128 * sizeof(float), stream);

  conv_weights<<<448, 256, 0, stream>>>(enc_w1, enc_w2, gnn_w1, gnn_w2, lp_w1, hp_w1,
                                        WTh, WTl);

  count_deg_l<<<E_L / 256, 256, 0, stream>>>(ei, indeg_g);
  count_deg_h<<<E_HT / 256, 256, 0, stream>>>(hei, indeg_g);
  dinv_kernel<<<(R_T + 255) / 256, 256, 0, stream>>>(indeg_g, dinv_g, R_T);

  scan_block<<<(R_T + 1023) / 1024, 1024, 0, stream>>>(indeg_g, R_T, rowptr_g, bsum);
  scan_top128<<<1, 64, 0, stream>>>(bsum, (R_T + 1023) / 1024);
  scan_fix<<<(R_T + 256) / 256, 256, 0, stream>>>(rowptr_g, bsum, R_T,
                                                  (R_T + 1023) / 1024, indeg_g);
  fill_csr_l<<<E_L / 256, 256, 0, stream>>>(ei, dinv_g, indeg_g, eg);
  fill_csr_h<<<E_HT / 256, 256, 0, stream>>>(hei, dinv_g, indeg_g, eg);

  // ---- encoder (enc1 merged layer+head fp32 CONV; enc2) ----
  mm_mfma<256, true, true, true><<<R_T / 128, 256, 0, stream>>>(
      x, head_x, nullptr, nullptr, WTh + WT_ENC1, WTl + WT_ENC1, enc_b1,
      nullptr, SAh, SAl);

  mm_mfma<128, false, true, true><<<R_T / 128, 256, 0, stream>>>(
      nullptr, nullptr, SAh, SAl, WTh + WT_ENC2, WTl + WT_ENC2, enc_b2,
      nullptr, SBh, SBl);

  // ---- GCN layer 1 ----
  mm_mfma<128, false, false, false><<<R_T / 128, 256, 0, stream>>>(
      nullptr, nullptr, SBh, SBl, WTh + WT_G1, WTl + WT_G1, nullptr,
      SAf, nullptr, nullptr);
  agg_packed<<<R_T / 4, 256, 0, stream>>>(SAf, dinv_g, rowptr_g, eg, gnn_b1,
                                          SBh, SBl);

  // ---- GCN layer 2 ----
  mm_mfma<128, false, false, false><<<R_T / 128, 256, 0, stream>>>(
      nullptr, nullptr, SBh, SBl, WTh + WT_G2, WTl + WT_G2, nullptr,
      SAf, nullptr, nullptr);
  agg_packed<<<R_T / 4, 256, 0, stream>>>(SAf, dinv_g, rowptr_g, eg, gnn_b2,
                                          SBh, SBl);

  // ---- policy heads (merged lp+hp, fused sigmoid) ----
  mm_policy<<<R_T / 128, 256, 0, stream>>>(
      SBh, SBl,
      WTh + WT_LP, WTl + WT_LP, WTh + WT_HP, WTl + WT_HP,
      lp_b1, hp_b1, lp_w2, hp_w2, lp_b2, hp_b2,
      out + OUT_LP, out + OUT_HP);

  // ---- value ----
  colsum_split<<<(N_L + 127) / 128, 128, 0, stream>>>(SBh, SBl, hsum, N_L);
  value_kernel<<<1, 128, 0, stream>>>(hsum, v_w1, v_b1, v_w2, v_b2, out + OUT_SV);

  // ---- mask ----
  mask_kernel<<<1, 64, 0, stream>>>(out + OUT_LP, out + OUT_MASK);
}

// Round 6
// 507.509 us; speedup vs baseline: 1.4711x; 1.0639x over previous
//
#include <hip/hip_runtime.h>
#include <hip/hip_fp16.h>
#include <math.h>

// PruningAgent r5:
//  - enc_fused: enc1(K=256) -> enc2 -> g1-mm fused in one kernel; inter-matmul
//    handoff via in-LDS bias+relu+split2 ds_write_b16 in A-fragment layout
//    (saves 216 MB HBM round-trip + 2 dispatches).
//  - agg: r4 packed-edge combined dispatch (unchanged).
//  - g2-mm / policy mm: r4 structure (unchanged).

typedef unsigned short ushort_t;
using short8 = __attribute__((ext_vector_type(8))) short;
using f32x4  = __attribute__((ext_vector_type(4))) float;

constexpr int N_L  = 40000;
constexpr int E_L  = 640000;
constexpr int H_   = 128;
constexpr int L_H  = 8;
constexpr int N_H1 = 8192;
constexpr int E_H1 = 131072;
constexpr int N_HT = 65536;    // 8*8192
constexpr int E_HT = 1048576;  // 8*131072
constexpr int E_T  = E_L + E_HT;
constexpr int NLP  = 40064;    // layer rows padded to 128
constexpr int R_T  = 105600;   // NLP + N_HT (combined row space)
constexpr int HBASE = 40064;   // head rows start here

// ---------------- numeric helpers ----------------

__device__ __forceinline__ unsigned short bf16_rne(float f) {
  unsigned u = __float_as_uint(f);
  unsigned r = u + 0x7FFFu + ((u >> 16) & 1u);
  return (unsigned short)(r >> 16);
}
__device__ __forceinline__ float bfhi_f(unsigned short h) {
  return __uint_as_float((unsigned)h << 16);
}
__device__ __forceinline__ void split2(float f, unsigned short& h, unsigned short& l) {
  h = bf16_rne(f);
  l = bf16_rne(f - bfhi_f(h));
}

__device__ __forceinline__ void gload16(const void* g, void* l) {
  __builtin_amdgcn_global_load_lds((__attribute__((address_space(1))) void*)(g),
                                   (__attribute__((address_space(3))) void*)(l),
                                   16, 0, 0);
}

// ---------------- degree / CSR build (combined graph) ----------------

__global__ __launch_bounds__(256) void count_deg_l(const int* __restrict__ ei,
                                                   int* __restrict__ indeg) {
  int i = blockIdx.x * 256 + threadIdx.x;
  if (i < E_L) atomicAdd(&indeg[ei[E_L + i]], 1);
}

__global__ __launch_bounds__(256) void count_deg_h(const int* __restrict__ hei,
                                                   int* __restrict__ indeg) {
  int i = blockIdx.x * 256 + threadIdx.x;
  if (i < E_HT) {
    int l = i >> 17, e = i & (E_H1 - 1);
    atomicAdd(&indeg[HBASE + l * N_H1 + hei[l * 2 * E_H1 + E_H1 + e]], 1);
  }
}

__global__ __launch_bounds__(256) void dinv_kernel(const int* __restrict__ indeg,
                                                   float* __restrict__ dinv, int n) {
  int i = blockIdx.x * 256 + threadIdx.x;
  if (i < n) dinv[i] = 1.0f / sqrtf((float)(indeg[i] + 1));
}

__global__ __launch_bounds__(1024) void scan_block(const int* __restrict__ in, int n,
                                                   int* __restrict__ out,
                                                   int* __restrict__ bsum) {
  __shared__ int s[1024];
  int t = threadIdx.x;
  int i = blockIdx.x * 1024 + t;
  int v = (i < n) ? in[i] : 0;
  s[t] = v;
  __syncthreads();
  for (int off = 1; off < 1024; off <<= 1) {
    int x = (t >= off) ? s[t - off] : 0;
    __syncthreads();
    s[t] += x;
    __syncthreads();
  }
  if (i < n) out[i] = s[t] - v;
  if (t == 1023) bsum[blockIdx.x] = s[t];
}

// single wave: exclusive scan of <=128 block sums; total at bsum[nb]
__global__ __launch_bounds__(64) void scan_top128(int* __restrict__ bsum, int nb) {
  int lane = threadIdx.x;
  int a = (lane < nb) ? bsum[lane] : 0;
  int b = (lane + 64 < nb) ? bsum[lane + 64] : 0;
  int ia = a;
  for (int off = 1; off < 64; off <<= 1) {
    int x = __shfl_up(ia, off);
    if (lane >= off) ia += x;
  }
  int ta = __shfl(ia, 63);
  int ib = b;
  for (int off = 1; off < 64; off <<= 1) {
    int x = __shfl_up(ib, off);
    if (lane >= off) ib += x;
  }
  int tb = __shfl(ib, 63);
  if (lane < nb) bsum[lane] = ia - a;
  if (lane + 64 < nb) bsum[lane + 64] = ta + ib - b;
  if (lane == 0) bsum[nb] = ta + tb;
}

__global__ __launch_bounds__(256) void scan_fix(int* __restrict__ rowptr,
                                                const int* __restrict__ bsum,
                                                int n, int nb,
                                                int* __restrict__ rowpos) {
  int i = blockIdx.x * 256 + threadIdx.x;
  if (i < n) {
    int v = rowptr[i] + bsum[i >> 10];
    rowptr[i] = v;
    rowpos[i] = v;
  } else if (i == n) {
    rowptr[n] = bsum[nb];
  }
}

// packed edge: src(17b) | fp16_bits(cw)<<17  (cw > 0 so sign bit is free)
__device__ __forceinline__ unsigned pack_edge(int src, float cw) {
  unsigned short hb = __half_as_ushort(__float2half(cw));
  return (unsigned)src | ((unsigned)hb << 17);
}

__global__ __launch_bounds__(256) void fill_csr_l(const int* __restrict__ ei,
                                                  const float* __restrict__ dinvg,
                                                  int* __restrict__ rowpos,
                                                  unsigned* __restrict__ eg) {
  int i = blockIdx.x * 256 + threadIdx.x;
  if (i < E_L) {
    int dst = ei[E_L + i];
    int src = ei[i];
    int p = atomicAdd(&rowpos[dst], 1);
    eg[p] = pack_edge(src, dinvg[src] * dinvg[dst]);
  }
}

__global__ __launch_bounds__(256) void fill_csr_h(const int* __restrict__ hei,
                                                  const float* __restrict__ dinvg,
                                                  int* __restrict__ rowpos,
                                                  unsigned* __restrict__ eg) {
  int i = blockIdx.x * 256 + threadIdx.x;
  if (i < E_HT) {
    int l = i >> 17, e = i & (E_H1 - 1);
    int base = l * 2 * E_H1;
    int dst = HBASE + l * N_H1 + hei[base + E_H1 + e];
    int src = HBASE + l * N_H1 + hei[base + e];
    int p = atomicAdd(&rowpos[dst], 1);
    eg[p] = pack_edge(src, dinvg[src] * dinvg[dst]);
  }
}

// ---------------- weight pre-split (transposed) ----------------
// dst layout Wt[c][k] (hi/lo). element offsets:
// enc_w1:0 (K=256), enc_w2:32768, gnn_w1:49152, gnn_w2:65536, lp_w1:81920, hp_w1:98304

__global__ __launch_bounds__(256) void conv_weights(
    const float* __restrict__ w0, const float* __restrict__ w1,
    const float* __restrict__ w2, const float* __restrict__ w3,
    const float* __restrict__ w4, const float* __restrict__ w5,
    unsigned short* __restrict__ th, unsigned short* __restrict__ tl) {
  int t = blockIdx.x * 256 + threadIdx.x;
  const float* src; int K, dstoff, idx;
  if (t < 32768) { src = w0; K = 256; dstoff = 0; idx = t; }
  else {
    int s = (t - 32768) >> 14;
    idx = (t - 32768) & 16383;
    K = 128;
    dstoff = 32768 + s * 16384;
    src = s == 0 ? w1 : s == 1 ? w2 : s == 2 ? w3 : s == 3 ? w4 : w5;
  }
  int k = idx >> 7, c = idx & 127;
  unsigned short h_, l_;
  split2(src[idx], h_, l_);
  th[dstoff + c * K + k] = h_;
  tl[dstoff + c * K + k] = l_;
}

// ---------------- shared mm helpers (KC=64 chunk) ----------------

__device__ __forceinline__ void stage_w(const unsigned short* Wth,
                                        const unsigned short* Wtl, int K, int kc,
                                        char* Ws_h, char* Ws_l,
                                        int wv, int rsub, int xr) {
#pragma unroll
  for (int j = 0; j < 4; ++j) {
    int q = wv * 4 + j;
    int c = q * 8 + rsub;
    size_t gb = ((size_t)c * K + kc) * 2 + (size_t)xr * 16;
    gload16((const char*)Wth + gb, Ws_h + q * 1024);
    gload16((const char*)Wtl + gb, Ws_l + q * 1024);
  }
}

__device__ __forceinline__ void mfma_chunk(const char* As_h, const char* As_l,
                                           const char* Ws_h, const char* Ws_l,
                                           int wv, int g, int li,
                                           f32x4 acc[2][8]) {
  short8 fa_h[2][2], fa_l[2][2];
#pragma unroll
  for (int m = 0; m < 2; ++m)
#pragma unroll
    for (int ks = 0; ks < 2; ++ks) {
      int row = wv * 32 + m * 16 + li;
      int off = row * 128 + ks * 64 + g * 16;
      off ^= (row & 7) << 4;
      fa_h[m][ks] = *(const short8*)(As_h + off);
      fa_l[m][ks] = *(const short8*)(As_l + off);
    }
#pragma unroll
  for (int nh = 0; nh < 2; ++nh) {
    short8 fb_h[4][2], fb_l[4][2];
#pragma unroll
    for (int n = 0; n < 4; ++n)
#pragma unroll
      for (int ks = 0; ks < 2; ++ks) {
        int c = nh * 64 + n * 16 + li;
        int off = c * 128 + ks * 64 + g * 16;
        off ^= (c & 7) << 4;
        fb_h[n][ks] = *(const short8*)(Ws_h + off);
        fb_l[n][ks] = *(const short8*)(Ws_l + off);
      }
#pragma unroll
    for (int m = 0; m < 2; ++m)
#pragma unroll
      for (int n = 0; n < 4; ++n)
#pragma unroll
        for (int ks = 0; ks < 2; ++ks) {
          f32x4 a_ = acc[m][nh * 4 + n];
          a_ = __builtin_amdgcn_mfma_f32_16x16x32_bf16(fa_h[m][ks], fb_h[n][ks], a_, 0, 0, 0);
          a_ = __builtin_amdgcn_mfma_f32_16x16x32_bf16(fa_h[m][ks], fb_l[n][ks], a_, 0, 0, 0);
          a_ = __builtin_amdgcn_mfma_f32_16x16x32_bf16(fa_l[m][ks], fb_h[n][ks], a_, 0, 0, 0);
          acc[m][nh * 4 + n] = a_;
        }
  }
}

// write h slice (cols [kc,kc+64)) from acc (+bias, relu, split) into As in
// the A-fragment layout: byte = row*128 + (((k>>3)^(row&7))<<4) + (k&7)*2
__device__ __forceinline__ void write_h_slice(const f32x4 acc[2][8],
                                              const float* bj, int kc,
                                              char* As_h, char* As_l,
                                              int wv, int g, int li) {
#pragma unroll
  for (int m = 0; m < 2; ++m)
#pragma unroll
    for (int jj = 0; jj < 4; ++jj) {
      int j = (kc >> 4) + jj;
#pragma unroll
      for (int r = 0; r < 4; ++r) {
        float o = fmaxf(acc[m][j][r] + bj[j], 0.f);
        unsigned short h_, l_;
        split2(o, h_, l_);
        int row = wv * 32 + m * 16 + g * 4 + r;
        int cl = jj * 16 + li;
        int byte = row * 128 + ((((cl >> 3) ^ (row & 7)) << 4) | ((cl & 7) * 2));
        *(unsigned short*)(As_h + byte) = h_;
        *(unsigned short*)(As_l + byte) = l_;
      }
    }
}

// ---------------- fused encoder + g1 matmul ----------------
// per 128-row block: x(fp32,K=256) -> h1 -> h2 -> G1 = h2 @ Wg1 (fp32 out)

__global__ __launch_bounds__(256, 2) void enc_fused(
    const float* __restrict__ x, const float* __restrict__ head_x,
    const unsigned short* __restrict__ W1h, const unsigned short* __restrict__ W1l,
    const unsigned short* __restrict__ W2h, const unsigned short* __restrict__ W2l,
    const unsigned short* __restrict__ Wgh, const unsigned short* __restrict__ Wgl,
    const float* __restrict__ b1, const float* __restrict__ b2,
    float* __restrict__ G) {
  __shared__ __align__(16) char lds[65536];
  char* As_h = lds;
  char* As_l = lds + 16384;
  char* Ws_h = lds + 32768;
  char* Ws_l = lds + 49152;

  const int tid = threadIdx.x;
  const int lane = tid & 63;
  const int wv = tid >> 6;
  const int g = lane >> 4;
  const int li = lane & 15;
  const int row0 = blockIdx.x * 128;
  const int rsub = lane >> 3;
  const int xr = (lane & 7) ^ ((lane >> 3) & 7);

  float bj1[8], bj2[8];
#pragma unroll
  for (int j = 0; j < 8; ++j) {
    bj1[j] = b1[j * 16 + li];
    bj2[j] = b2[j * 16 + li];
  }

  // ---- phase 1: h1 = x @ We1 (acc1; bias+relu applied at handoff) ----
  f32x4 acc1[2][8];
#pragma unroll
  for (int m = 0; m < 2; ++m)
#pragma unroll
    for (int j = 0; j < 8; ++j) acc1[m][j] = f32x4{0.f, 0.f, 0.f, 0.f};

#pragma unroll
  for (int kc = 0; kc < 256; kc += 64) {
    __syncthreads();
    stage_w(W1h, W1l, 256, kc, Ws_h, Ws_l, wv, rsub, xr);
    {
      // fp32 x -> split bf16, swizzled ds_write (two source regions)
      int r = tid >> 1, hf = tid & 1;
      int grow = row0 + r;
      const float* srcb;
      int lrow;
      if (grow < NLP) { srcb = x;      lrow = min(grow, N_L - 1); }
      else            { srcb = head_x; lrow = grow - NLP; }
      const float* src = srcb + (size_t)lrow * 256 + kc + hf * 32;
#pragma unroll
      for (int i = 0; i < 4; ++i) {
        float4 a = ((const float4*)src)[2 * i];
        float4 b = ((const float4*)src)[2 * i + 1];
        float f[8] = {a.x, a.y, a.z, a.w, b.x, b.y, b.z, b.w};
        short8 vh, vl;
#pragma unroll
        for (int e = 0; e < 8; ++e) {
          unsigned short h_, l_;
          split2(f[e], h_, l_);
          vh[e] = (short)h_;
          vl[e] = (short)l_;
        }
        int xu = hf * 4 + i;
        int u = r * 8 + (xu ^ (r & 7));
        *(short8*)(As_h + u * 16) = vh;
        *(short8*)(As_l + u * 16) = vl;
      }
    }
    __syncthreads();
    mfma_chunk(As_h, As_l, Ws_h, Ws_l, wv, g, li, acc1);
  }

  // ---- phase 2: h2 = relu(h1+b1) @ We2 ----
  f32x4 acc2[2][8];
#pragma unroll
  for (int m = 0; m < 2; ++m)
#pragma unroll
    for (int j = 0; j < 8; ++j) acc2[m][j] = f32x4{0.f, 0.f, 0.f, 0.f};

#pragma unroll
  for (int kc = 0; kc < 128; kc += 64) {
    __syncthreads();
    stage_w(W2h, W2l, 128, kc, Ws_h, Ws_l, wv, rsub, xr);
    write_h_slice(acc1, bj1, kc, As_h, As_l, wv, g, li);
    __syncthreads();
    mfma_chunk(As_h, As_l, Ws_h, Ws_l, wv, g, li, acc2);
  }

  // ---- phase 3: G1 = relu(h2+b2) @ Wg1 (no bias/act on output) ----
  f32x4 acc3[2][8];
#pragma unroll
  for (int m = 0; m < 2; ++m)
#pragma unroll
    for (int j = 0; j < 8; ++j) acc3[m][j] = f32x4{0.f, 0.f, 0.f, 0.f};

#pragma unroll
  for (int kc = 0; kc < 128; kc += 64) {
    __syncthreads();
    stage_w(Wgh, Wgl, 128, kc, Ws_h, Ws_l, wv, rsub, xr);
    write_h_slice(acc2, bj2, kc, As_h, As_l, wv, g, li);
    __syncthreads();
    mfma_chunk(As_h, As_l, Ws_h, Ws_l, wv, g, li, acc3);
  }

  // ---- epilogue: fp32 G out (row-major, for agg gather) ----
#pragma unroll
  for (int m = 0; m < 2; ++m)
#pragma unroll
    for (int j = 0; j < 8; ++j) {
      int c = j * 16 + li;
#pragma unroll
      for (int r = 0; r < 4; ++r) {
        int rowg = row0 + wv * 32 + m * 16 + g * 4 + r;
        G[(size_t)rowg * 128 + c] = acc3[m][j][r];
      }
    }
}

// ---------------- MFMA matmul (g2: split-bf16 in, fp32 out) ----------------

__global__ __launch_bounds__(256) void mm_g(
    const unsigned short* __restrict__ Ah, const unsigned short* __restrict__ Al,
    const unsigned short* __restrict__ Wth, const unsigned short* __restrict__ Wtl,
    float* __restrict__ Cf) {
  constexpr int K = 128;
  __shared__ __align__(16) char lds[65536];
  char* As_h = lds;
  char* As_l = lds + 16384;
  char* Ws_h = lds + 32768;
  char* Ws_l = lds + 49152;

  const int tid = threadIdx.x;
  const int lane = tid & 63;
  const int wv = tid >> 6;
  const int g = lane >> 4;
  const int li = lane & 15;
  const int row0 = blockIdx.x * 128;
  const int rsub = lane >> 3;
  const int xr = (lane & 7) ^ ((lane >> 3) & 7);

  f32x4 acc[2][8];
#pragma unroll
  for (int m = 0; m < 2; ++m)
#pragma unroll
    for (int j = 0; j < 8; ++j) acc[m][j] = f32x4{0.f, 0.f, 0.f, 0.f};

#pragma unroll
  for (int kc = 0; kc < K; kc += 64) {
    __syncthreads();
    stage_w(Wth, Wtl, K, kc, Ws_h, Ws_l, wv, rsub, xr);
#pragma unroll
    for (int j = 0; j < 4; ++j) {
      int q = wv * 4 + j;
      int r = q * 8 + rsub;
      size_t gb = ((size_t)(row0 + r) * K + kc) * 2 + (size_t)xr * 16;
      gload16((const char*)Ah + gb, As_h + q * 1024);
      gload16((const char*)Al + gb, As_l + q * 1024);
    }
    __syncthreads();
    mfma_chunk(As_h, As_l, Ws_h, Ws_l, wv, g, li, acc);
  }

#pragma unroll
  for (int m = 0; m < 2; ++m)
#pragma unroll
    for (int j = 0; j < 8; ++j) {
      int c = j * 16 + li;
#pragma unroll
      for (int r = 0; r < 4; ++r) {
        int rowg = row0 + wv * 32 + m * 16 + g * 4 + r;
        Cf[(size_t)rowg * 128 + c] = acc[m][j][r];
      }
    }
}

// ---------------- fused policy matmul (lp rows<NLP, hp rows>=NLP) --------

__global__ __launch_bounds__(256) void mm_policy(
    const unsigned short* __restrict__ Ah, const unsigned short* __restrict__ Al,
    const unsigned short* __restrict__ Wth_l, const unsigned short* __restrict__ Wtl_l,
    const unsigned short* __restrict__ Wth_h, const unsigned short* __restrict__ Wtl_h,
    const float* __restrict__ b1l, const float* __restrict__ b1h,
    const float* __restrict__ w2l, const float* __restrict__ w2h,
    const float* __restrict__ b2l, const float* __restrict__ b2h,
    float* __restrict__ out_l, float* __restrict__ out_h) {
  constexpr int K = 128;
  __shared__ __align__(16) char lds[65536];
  char* As_h = lds;
  char* As_l = lds + 16384;
  char* Ws_h = lds + 32768;
  char* Ws_l = lds + 49152;

  const int tid = threadIdx.x;
  const int lane = tid & 63;
  const int wv = tid >> 6;
  const int g = lane >> 4;
  const int li = lane & 15;
  const int row0 = blockIdx.x * 128;
  const bool isl = row0 < NLP;

  const unsigned short* Wth = isl ? Wth_l : Wth_h;
  const unsigned short* Wtl = isl ? Wtl_l : Wtl_h;
  const float* bias = isl ? b1l : b1h;
  const float* pw2  = isl ? w2l : w2h;
  const float* pb2  = isl ? b2l : b2h;

  f32x4 acc[2][8];
#pragma unroll
  for (int m = 0; m < 2; ++m)
#pragma unroll
    for (int j = 0; j < 8; ++j) acc[m][j] = f32x4{0.f, 0.f, 0.f, 0.f};

  const int rsub = lane >> 3;
  const int xr = (lane & 7) ^ ((lane >> 3) & 7);

#pragma unroll
  for (int kc = 0; kc < K; kc += 64) {
    __syncthreads();
    stage_w(Wth, Wtl, K, kc, Ws_h, Ws_l, wv, rsub, xr);
#pragma unroll
    for (int j = 0; j < 4; ++j) {
      int q = wv * 4 + j;
      int r = q * 8 + rsub;
      size_t ga = ((size_t)(row0 + r) * K + kc) * 2 + (size_t)xr * 16;
      gload16((const char*)Ah + ga, As_h + q * 1024);
      gload16((const char*)Al + ga, As_l + q * 1024);
    }
    __syncthreads();
    mfma_chunk(As_h, As_l, Ws_h, Ws_l, wv, g, li, acc);
  }

  // fused head: p = sigmoid( sum_c relu(acc+b1)[c] * w2[c] + b2 )
  float w2c[8], bj[8];
#pragma unroll
  for (int j = 0; j < 8; ++j) {
    w2c[j] = pw2[j * 16 + li];
    bj[j]  = bias[j * 16 + li];
  }
#pragma unroll
  for (int m = 0; m < 2; ++m)
#pragma unroll
    for (int r = 0; r < 4; ++r) {
      float p = 0.f;
#pragma unroll
      for (int j = 0; j < 8; ++j) {
        float o = fmaxf(acc[m][j][r] + bj[j], 0.f);
        p = fmaf(o, w2c[j], p);
      }
      p += __shfl_xor(p, 1);
      p += __shfl_xor(p, 2);
      p += __shfl_xor(p, 4);
      p += __shfl_xor(p, 8);
      if (li == 0) {
        int rowg = row0 + wv * 32 + m * 16 + g * 4 + r;
        if (isl) {
          if (rowg < N_L) out_l[rowg] = 1.0f / (1.0f + expf(-(p + pb2[0])));
        } else {
          out_h[rowg - HBASE] = 1.0f / (1.0f + expf(-(p + pb2[0])));
        }
      }
    }
}

// ---------------- GCN aggregation (combined graphs, packed edges) --------

__global__ __launch_bounds__(256) void agg_packed(const float* __restrict__ Hin,
                                                  const float* __restrict__ dinvg,
                                                  const int* __restrict__ rowptr,
                                                  const unsigned* __restrict__ eg,
                                                  const float* __restrict__ bias,
                                                  unsigned short* __restrict__ Oh,
                                                  unsigned short* __restrict__ Ol) {
  int b = blockIdx.x;                 // 26400 blocks
  {
    int x = b & 7, j = b >> 3;        // j in [0,3300)
    b = (j < 1252) ? (x * 1252 + j) : (10016 + x * 2048 + (j - 1252));
  }
  int v = b * 4 + (threadIdx.x >> 6);
  int lane = threadIdx.x & 63;
  const float2* H2 = (const float2*)Hin;

  float dv = dinvg[v];
  float2 h = H2[(size_t)v * 64 + lane];
  float2 acc;
  acc.x = h.x * dv * dv;
  acc.y = h.y * dv * dv;

  int e0 = rowptr[v], e1 = rowptr[v + 1];
  for (int e = e0; e < e1; e += 16) {
    unsigned pr = 0;
    if (lane < 16) pr = eg[e + lane];   // eg padded by 16 entries
    float2 xs[16];
    float cs[16];
#pragma unroll
    for (int i = 0; i < 16; ++i) {
      if (e + i < e1) {
        unsigned pe = (unsigned)__shfl((int)pr, i);
        int u = pe & 0x1FFFF;
        cs[i] = __half2float(__ushort_as_half((unsigned short)(pe >> 17)));
        xs[i] = H2[(size_t)u * 64 + lane];
      } else {
        cs[i] = 0.f;
        xs[i].x = 0.f;
        xs[i].y = 0.f;
      }
    }
#pragma unroll
    for (int i = 0; i < 16; ++i) {
      acc.x = fmaf(xs[i].x, cs[i], acc.x);
      acc.y = fmaf(xs[i].y, cs[i], acc.y);
    }
  }

  float2 b2 = ((const float2*)bias)[lane];
  acc.x = fmaxf(acc.x + b2.x, 0.f);
  acc.y = fmaxf(acc.y + b2.y, 0.f);

  unsigned short hx, lx, hy, ly;
  split2(acc.x, hx, lx);
  split2(acc.y, hy, ly);
  ushort2 th, tl;
  th.x = hx; th.y = hy;
  tl.x = lx; tl.y = ly;
  ((ushort2*)Oh)[(size_t)v * 64 + lane] = th;
  ((ushort2*)Ol)[(size_t)v * 64 + lane] = tl;
}

// ---------------- value head ----------------

__global__ __launch_bounds__(128) void colsum_split(const unsigned short* __restrict__ Hh,
                                                    const unsigned short* __restrict__ Hl,
                                                    float* __restrict__ hsum, int n) {
  int f = threadIdx.x;
  int r0 = blockIdx.x * 128;
  int r1 = min(r0 + 128, n);
  float acc = 0.f;
  for (int r = r0; r < r1; ++r) {
    size_t idx = (size_t)r * 128 + f;
    acc += bfhi_f(Hh[idx]) + bfhi_f(Hl[idx]);
  }
  atomicAdd(&hsum[f], acc);
}

__global__ __launch_bounds__(128) void value_kernel(const float* __restrict__ hsum,
                                                    const float* __restrict__ w1,
                                                    const float* __restrict__ b1,
                                                    const float* __restrict__ w2,
                                                    const float* __restrict__ b2,
                                                    float* __restrict__ out) {
  __shared__ float hm[128];
  __shared__ float red[128];
  int t = threadIdx.x;
  hm[t] = hsum[t] * (1.0f / (float)N_L);
  __syncthreads();
  float acc = b1[t];
  for (int k = 0; k < 128; ++k) acc = fmaf(hm[k], w1[k * 128 + t], acc);
  red[t] = fmaxf(acc, 0.f) * w2[t];
  for (int off = 64; off > 0; off >>= 1) {
    __syncthreads();
    if (t < off) red[t] += red[t + off];
  }
  __syncthreads();
  if (t == 0) out[0] = red[0] + b2[0];
}

__global__ __launch_bounds__(64) void mask_kernel(const float* __restrict__ lp,
                                                  float* __restrict__ out) {
  int i = threadIdx.x;
  if (i < L_H) out[i] = (lp[i] > 0.5f) ? 1.0f : 0.0f;
}

// ---------------- driver ----------------

extern "C" void kernel_launch(void* const* d_in, const int* in_sizes, int n_in,
                              void* d_out, int out_size, void* d_ws, size_t ws_size,
                              hipStream_t stream) {
  const float* x      = (const float*)d_in[0];
  const int*   ei     = (const int*)d_in[1];
  const float* head_x = (const float*)d_in[2];
  const int*   hei    = (const int*)d_in[3];
  const float* enc_w1 = (const float*)d_in[4];
  const float* enc_b1 = (const float*)d_in[5];
  const float* enc_w2 = (const float*)d_in[6];
  const float* enc_b2 = (const float*)d_in[7];
  const float* gnn_w1 = (const float*)d_in[8];
  const float* gnn_b1 = (const float*)d_in[9];
  const float* gnn_w2 = (const float*)d_in[10];
  const float* gnn_b2 = (const float*)d_in[11];
  const float* lp_w1  = (const float*)d_in[12];
  const float* lp_b1  = (const float*)d_in[13];
  const float* lp_w2  = (const float*)d_in[14];
  const float* lp_b2  = (const float*)d_in[15];
  const float* hp_w1  = (const float*)d_in[16];
  const float* hp_b1  = (const float*)d_in[17];
  const float* hp_w2  = (const float*)d_in[18];
  const float* hp_b2  = (const float*)d_in[19];
  const float* v_w1   = (const float*)d_in[20];
  const float* v_b1   = (const float*)d_in[21];
  const float* v_w2   = (const float*)d_in[22];
  const float* v_b2   = (const float*)d_in[23];
  float* out = (float*)d_out;

  // ---- workspace layout ----
  const size_t ELE = (size_t)R_T * 128;
  char* base = (char*)d_ws;
  float* SAf = (float*)base;                   // SLOT_A (fp32 G buffer)
  char* baseB = base + ELE * 4;
  unsigned short* SBh = (unsigned short*)baseB;
  unsigned short* SBl = SBh + ELE;
  unsigned short* WTh = (unsigned short*)(baseB + ELE * 4);
  unsigned short* WTl = WTh + 114688;
  float* dinv_g = (float*)(WTl + 114688);      // [R_T]
  float* hsum   = dinv_g + R_T;                // [128]
  int* ip       = (int*)(hsum + 128);
  int* indeg_g  = ip;  ip += R_T;              // doubles as rowpos
  int* rowptr_g = ip;  ip += R_T + 1;
  unsigned* eg  = (unsigned*)ip;  ip += E_T + 16;
  int* bsum     = ip;  ip += 112;

  const int WT_ENC1 = 0, WT_ENC2 = 32768, WT_G1 = 49152, WT_G2 = 65536,
            WT_LP = 81920, WT_HP = 98304;

  const int OUT_LP = 0, OUT_HP = N_L, OUT_MASK = N_L + N_HT, OUT_SV = N_L + N_HT + L_H;

  // ---- CSR + dinv + weight split ----
  hipMemsetAsync(indeg_g, 0, (size_t)R_T * sizeof(int), stream);
  hipMemsetAsync(hsum, 0, 128 * sizeof(float), stream);

  conv_weights<<<448, 256, 0, stream>>>(enc_w1, enc_w2, gnn_w1, gnn_w2, lp_w1, hp_w1,
                                        WTh, WTl);

  count_deg_l<<<E_L / 256, 256, 0, stream>>>(ei, indeg_g);
  count_deg_h<<<E_HT / 256, 256, 0, stream>>>(hei, indeg_g);
  dinv_kernel<<<(R_T + 255) / 256, 256, 0, stream>>>(indeg_g, dinv_g, R_T);

  scan_block<<<(R_T + 1023) / 1024, 1024, 0, stream>>>(indeg_g, R_T, rowptr_g, bsum);
  scan_top128<<<1, 64, 0, stream>>>(bsum, (R_T + 1023) / 1024);
  scan_fix<<<(R_T + 256) / 256, 256, 0, stream>>>(rowptr_g, bsum, R_T,
                                                  (R_T + 1023) / 1024, indeg_g);
  fill_csr_l<<<E_L / 256, 256, 0, stream>>>(ei, dinv_g, indeg_g, eg);
  fill_csr_h<<<E_HT / 256, 256, 0, stream>>>(hei, dinv_g, indeg_g, eg);

  // ---- fused encoder + g1-mm: x -> h1 -> h2 -> G1 (fp32) ----
  enc_fused<<<R_T / 128, 256, 0, stream>>>(
      x, head_x,
      WTh + WT_ENC1, WTl + WT_ENC1,
      WTh + WT_ENC2, WTl + WT_ENC2,
      WTh + WT_G1,   WTl + WT_G1,
      enc_b1, enc_b2, SAf);

  // ---- GCN layer 1 aggregate ----
  agg_packed<<<R_T / 4, 256, 0, stream>>>(SAf, dinv_g, rowptr_g, eg, gnn_b1,
                                          SBh, SBl);

  // ---- GCN layer 2 ----
  mm_g<<<R_T / 128, 256, 0, stream>>>(SBh, SBl, WTh + WT_G2, WTl + WT_G2, SAf);
  agg_packed<<<R_T / 4, 256, 0, stream>>>(SAf, dinv_g, rowptr_g, eg, gnn_b2,
                                          SBh, SBl);

  // ---- policy heads (merged lp+hp, fused sigmoid) ----
  mm_policy<<<R_T / 128, 256, 0, stream>>>(
      SBh, SBl,
      WTh + WT_LP, WTl + WT_LP, WTh + WT_HP, WTl + WT_HP,
      lp_b1, hp_b1, lp_w2, hp_w2, lp_b2, hp_b2,
      out + OUT_LP, out + OUT_HP);

  // ---- value ----
  colsum_split<<<(N_L + 127) / 128, 128, 0, stream>>>(SBh, SBl, hsum, N_L);
  value_kernel<<<1, 128, 0, stream>>>(hsum, v_w1, v_b1, v_w2, v_b2, out + OUT_SV);

  // ---- mask ----
  mask_kernel<<<1, 64, 0, stream>>>(out + OUT_LP, out + OUT_MASK);
}

// Round 7
// 507.485 us; speedup vs baseline: 1.4712x; 1.0000x over previous
//
#include <hip/hip_runtime.h>
#include <hip/hip_fp16.h>
#include <math.h>

// PruningAgent r6:
//  - agg_packed: wave-uniform scalar path (readfirstlane -> s_load edge words,
//    SGPR coefficients, no ds_bpermute in the gather chain).
//  - CSR count/fill merged into single dispatches.
//  - enc_fused / mm_g / mm_policy / value: r5 structure unchanged.

typedef unsigned short ushort_t;
using short8 = __attribute__((ext_vector_type(8))) short;
using f32x4  = __attribute__((ext_vector_type(4))) float;

constexpr int N_L  = 40000;
constexpr int E_L  = 640000;
constexpr int H_   = 128;
constexpr int L_H  = 8;
constexpr int N_H1 = 8192;
constexpr int E_H1 = 131072;
constexpr int N_HT = 65536;    // 8*8192
constexpr int E_HT = 1048576;  // 8*131072
constexpr int E_T  = E_L + E_HT;
constexpr int NLP  = 40064;    // layer rows padded to 128
constexpr int R_T  = 105600;   // NLP + N_HT (combined row space)
constexpr int HBASE = 40064;   // head rows start here

// ---------------- numeric helpers ----------------

__device__ __forceinline__ unsigned short bf16_rne(float f) {
  unsigned u = __float_as_uint(f);
  unsigned r = u + 0x7FFFu + ((u >> 16) & 1u);
  return (unsigned short)(r >> 16);
}
__device__ __forceinline__ float bfhi_f(unsigned short h) {
  return __uint_as_float((unsigned)h << 16);
}
__device__ __forceinline__ void split2(float f, unsigned short& h, unsigned short& l) {
  h = bf16_rne(f);
  l = bf16_rne(f - bfhi_f(h));
}

__device__ __forceinline__ void gload16(const void* g, void* l) {
  __builtin_amdgcn_global_load_lds((__attribute__((address_space(1))) void*)(g),
                                   (__attribute__((address_space(3))) void*)(l),
                                   16, 0, 0);
}

// ---------------- degree / CSR build (combined graph) ----------------

__global__ __launch_bounds__(256) void count_deg_all(const int* __restrict__ ei,
                                                     const int* __restrict__ hei,
                                                     int* __restrict__ indeg) {
  int i = blockIdx.x * 256 + threadIdx.x;
  if (i < E_L) {
    atomicAdd(&indeg[ei[E_L + i]], 1);
  } else if (i < E_T) {
    int t = i - E_L;
    int l = t >> 17, e = t & (E_H1 - 1);
    atomicAdd(&indeg[HBASE + l * N_H1 + hei[l * 2 * E_H1 + E_H1 + e]], 1);
  }
}

__global__ __launch_bounds__(256) void dinv_kernel(const int* __restrict__ indeg,
                                                   float* __restrict__ dinv, int n) {
  int i = blockIdx.x * 256 + threadIdx.x;
  if (i < n) dinv[i] = 1.0f / sqrtf((float)(indeg[i] + 1));
}

__global__ __launch_bounds__(1024) void scan_block(const int* __restrict__ in, int n,
                                                   int* __restrict__ out,
                                                   int* __restrict__ bsum) {
  __shared__ int s[1024];
  int t = threadIdx.x;
  int i = blockIdx.x * 1024 + t;
  int v = (i < n) ? in[i] : 0;
  s[t] = v;
  __syncthreads();
  for (int off = 1; off < 1024; off <<= 1) {
    int x = (t >= off) ? s[t - off] : 0;
    __syncthreads();
    s[t] += x;
    __syncthreads();
  }
  if (i < n) out[i] = s[t] - v;
  if (t == 1023) bsum[blockIdx.x] = s[t];
}

// single wave: exclusive scan of <=128 block sums; total at bsum[nb]
__global__ __launch_bounds__(64) void scan_top128(int* __restrict__ bsum, int nb) {
  int lane = threadIdx.x;
  int a = (lane < nb) ? bsum[lane] : 0;
  int b = (lane + 64 < nb) ? bsum[lane + 64] : 0;
  int ia = a;
  for (int off = 1; off < 64; off <<= 1) {
    int x = __shfl_up(ia, off);
    if (lane >= off) ia += x;
  }
  int ta = __shfl(ia, 63);
  int ib = b;
  for (int off = 1; off < 64; off <<= 1) {
    int x = __shfl_up(ib, off);
    if (lane >= off) ib += x;
  }
  int tb = __shfl(ib, 63);
  if (lane < nb) bsum[lane] = ia - a;
  if (lane + 64 < nb) bsum[lane + 64] = ta + ib - b;
  if (lane == 0) bsum[nb] = ta + tb;
}

__global__ __launch_bounds__(256) void scan_fix(int* __restrict__ rowptr,
                                                const int* __restrict__ bsum,
                                                int n, int nb,
                                                int* __restrict__ rowpos) {
  int i = blockIdx.x * 256 + threadIdx.x;
  if (i < n) {
    int v = rowptr[i] + bsum[i >> 10];
    rowptr[i] = v;
    rowpos[i] = v;
  } else if (i == n) {
    rowptr[n] = bsum[nb];
  }
}

// packed edge: src(17b) | fp16_bits(cw)<<17  (cw > 0 so sign bit is free)
__device__ __forceinline__ unsigned pack_edge(int src, float cw) {
  unsigned short hb = __half_as_ushort(__float2half(cw));
  return (unsigned)src | ((unsigned)hb << 17);
}

__global__ __launch_bounds__(256) void fill_csr_all(const int* __restrict__ ei,
                                                    const int* __restrict__ hei,
                                                    const float* __restrict__ dinvg,
                                                    int* __restrict__ rowpos,
                                                    unsigned* __restrict__ eg) {
  int i = blockIdx.x * 256 + threadIdx.x;
  if (i < E_L) {
    int dst = ei[E_L + i];
    int src = ei[i];
    int p = atomicAdd(&rowpos[dst], 1);
    eg[p] = pack_edge(src, dinvg[src] * dinvg[dst]);
  } else if (i < E_T) {
    int t = i - E_L;
    int l = t >> 17, e = t & (E_H1 - 1);
    int base = l * 2 * E_H1;
    int dst = HBASE + l * N_H1 + hei[base + E_H1 + e];
    int src = HBASE + l * N_H1 + hei[base + e];
    int p = atomicAdd(&rowpos[dst], 1);
    eg[p] = pack_edge(src, dinvg[src] * dinvg[dst]);
  }
}

// ---------------- weight pre-split (transposed) ----------------
// dst layout Wt[c][k] (hi/lo). element offsets:
// enc_w1:0 (K=256), enc_w2:32768, gnn_w1:49152, gnn_w2:65536, lp_w1:81920, hp_w1:98304

__global__ __launch_bounds__(256) void conv_weights(
    const float* __restrict__ w0, const float* __restrict__ w1,
    const float* __restrict__ w2, const float* __restrict__ w3,
    const float* __restrict__ w4, const float* __restrict__ w5,
    unsigned short* __restrict__ th, unsigned short* __restrict__ tl) {
  int t = blockIdx.x * 256 + threadIdx.x;
  const float* src; int K, dstoff, idx;
  if (t < 32768) { src = w0; K = 256; dstoff = 0; idx = t; }
  else {
    int s = (t - 32768) >> 14;
    idx = (t - 32768) & 16383;
    K = 128;
    dstoff = 32768 + s * 16384;
    src = s == 0 ? w1 : s == 1 ? w2 : s == 2 ? w3 : s == 3 ? w4 : w5;
  }
  int k = idx >> 7, c = idx & 127;
  unsigned short h_, l_;
  split2(src[idx], h_, l_);
  th[dstoff + c * K + k] = h_;
  tl[dstoff + c * K + k] = l_;
}

// ---------------- shared mm helpers (KC=64 chunk) ----------------

__device__ __forceinline__ void stage_w(const unsigned short* Wth,
                                        const unsigned short* Wtl, int K, int kc,
                                        char* Ws_h, char* Ws_l,
                                        int wv, int rsub, int xr) {
#pragma unroll
  for (int j = 0; j < 4; ++j) {
    int q = wv * 4 + j;
    int c = q * 8 + rsub;
    size_t gb = ((size_t)c * K + kc) * 2 + (size_t)xr * 16;
    gload16((const char*)Wth + gb, Ws_h + q * 1024);
    gload16((const char*)Wtl + gb, Ws_l + q * 1024);
  }
}

__device__ __forceinline__ void mfma_chunk(const char* As_h, const char* As_l,
                                           const char* Ws_h, const char* Ws_l,
                                           int wv, int g, int li,
                                           f32x4 acc[2][8]) {
  short8 fa_h[2][2], fa_l[2][2];
#pragma unroll
  for (int m = 0; m < 2; ++m)
#pragma unroll
    for (int ks = 0; ks < 2; ++ks) {
      int row = wv * 32 + m * 16 + li;
      int off = row * 128 + ks * 64 + g * 16;
      off ^= (row & 7) << 4;
      fa_h[m][ks] = *(const short8*)(As_h + off);
      fa_l[m][ks] = *(const short8*)(As_l + off);
    }
#pragma unroll
  for (int nh = 0; nh < 2; ++nh) {
    short8 fb_h[4][2], fb_l[4][2];
#pragma unroll
    for (int n = 0; n < 4; ++n)
#pragma unroll
      for (int ks = 0; ks < 2; ++ks) {
        int c = nh * 64 + n * 16 + li;
        int off = c * 128 + ks * 64 + g * 16;
        off ^= (c & 7) << 4;
        fb_h[n][ks] = *(const short8*)(Ws_h + off);
        fb_l[n][ks] = *(const short8*)(Ws_l + off);
      }
#pragma unroll
    for (int m = 0; m < 2; ++m)
#pragma unroll
      for (int n = 0; n < 4; ++n)
#pragma unroll
        for (int ks = 0; ks < 2; ++ks) {
          f32x4 a_ = acc[m][nh * 4 + n];
          a_ = __builtin_amdgcn_mfma_f32_16x16x32_bf16(fa_h[m][ks], fb_h[n][ks], a_, 0, 0, 0);
          a_ = __builtin_amdgcn_mfma_f32_16x16x32_bf16(fa_h[m][ks], fb_l[n][ks], a_, 0, 0, 0);
          a_ = __builtin_amdgcn_mfma_f32_16x16x32_bf16(fa_l[m][ks], fb_h[n][ks], a_, 0, 0, 0);
          acc[m][nh * 4 + n] = a_;
        }
  }
}

// write h slice (cols [kc,kc+64)) from acc (+bias, relu, split) into As in
// the A-fragment layout: byte = row*128 + (((k>>3)^(row&7))<<4) + (k&7)*2
__device__ __forceinline__ void write_h_slice(const f32x4 acc[2][8],
                                              const float* bj, int kc,
                                              char* As_h, char* As_l,
                                              int wv, int g, int li) {
#pragma unroll
  for (int m = 0; m < 2; ++m)
#pragma unroll
    for (int jj = 0; jj < 4; ++jj) {
      int j = (kc >> 4) + jj;
#pragma unroll
      for (int r = 0; r < 4; ++r) {
        float o = fmaxf(acc[m][j][r] + bj[j], 0.f);
        unsigned short h_, l_;
        split2(o, h_, l_);
        int row = wv * 32 + m * 16 + g * 4 + r;
        int cl = jj * 16 + li;
        int byte = row * 128 + ((((cl >> 3) ^ (row & 7)) << 4) | ((cl & 7) * 2));
        *(unsigned short*)(As_h + byte) = h_;
        *(unsigned short*)(As_l + byte) = l_;
      }
    }
}

// ---------------- fused encoder + g1 matmul ----------------
// per 128-row block: x(fp32,K=256) -> h1 -> h2 -> G1 = h2 @ Wg1 (fp32 out)

__global__ __launch_bounds__(256, 2) void enc_fused(
    const float* __restrict__ x, const float* __restrict__ head_x,
    const unsigned short* __restrict__ W1h, const unsigned short* __restrict__ W1l,
    const unsigned short* __restrict__ W2h, const unsigned short* __restrict__ W2l,
    const unsigned short* __restrict__ Wgh, const unsigned short* __restrict__ Wgl,
    const float* __restrict__ b1, const float* __restrict__ b2,
    float* __restrict__ G) {
  __shared__ __align__(16) char lds[65536];
  char* As_h = lds;
  char* As_l = lds + 16384;
  char* Ws_h = lds + 32768;
  char* Ws_l = lds + 49152;

  const int tid = threadIdx.x;
  const int lane = tid & 63;
  const int wv = tid >> 6;
  const int g = lane >> 4;
  const int li = lane & 15;
  const int row0 = blockIdx.x * 128;
  const int rsub = lane >> 3;
  const int xr = (lane & 7) ^ ((lane >> 3) & 7);

  float bj1[8], bj2[8];
#pragma unroll
  for (int j = 0; j < 8; ++j) {
    bj1[j] = b1[j * 16 + li];
    bj2[j] = b2[j * 16 + li];
  }

  // ---- phase 1: h1 = x @ We1 ----
  f32x4 acc1[2][8];
#pragma unroll
  for (int m = 0; m < 2; ++m)
#pragma unroll
    for (int j = 0; j < 8; ++j) acc1[m][j] = f32x4{0.f, 0.f, 0.f, 0.f};

#pragma unroll
  for (int kc = 0; kc < 256; kc += 64) {
    __syncthreads();
    stage_w(W1h, W1l, 256, kc, Ws_h, Ws_l, wv, rsub, xr);
    {
      int r = tid >> 1, hf = tid & 1;
      int grow = row0 + r;
      const float* srcb;
      int lrow;
      if (grow < NLP) { srcb = x;      lrow = min(grow, N_L - 1); }
      else            { srcb = head_x; lrow = grow - NLP; }
      const float* src = srcb + (size_t)lrow * 256 + kc + hf * 32;
#pragma unroll
      for (int i = 0; i < 4; ++i) {
        float4 a = ((const float4*)src)[2 * i];
        float4 b = ((const float4*)src)[2 * i + 1];
        float f[8] = {a.x, a.y, a.z, a.w, b.x, b.y, b.z, b.w};
        short8 vh, vl;
#pragma unroll
        for (int e = 0; e < 8; ++e) {
          unsigned short h_, l_;
          split2(f[e], h_, l_);
          vh[e] = (short)h_;
          vl[e] = (short)l_;
        }
        int xu = hf * 4 + i;
        int u = r * 8 + (xu ^ (r & 7));
        *(short8*)(As_h + u * 16) = vh;
        *(short8*)(As_l + u * 16) = vl;
      }
    }
    __syncthreads();
    mfma_chunk(As_h, As_l, Ws_h, Ws_l, wv, g, li, acc1);
  }

  // ---- phase 2: h2 = relu(h1+b1) @ We2 ----
  f32x4 acc2[2][8];
#pragma unroll
  for (int m = 0; m < 2; ++m)
#pragma unroll
    for (int j = 0; j < 8; ++j) acc2[m][j] = f32x4{0.f, 0.f, 0.f, 0.f};

#pragma unroll
  for (int kc = 0; kc < 128; kc += 64) {
    __syncthreads();
    stage_w(W2h, W2l, 128, kc, Ws_h, Ws_l, wv, rsub, xr);
    write_h_slice(acc1, bj1, kc, As_h, As_l, wv, g, li);
    __syncthreads();
    mfma_chunk(As_h, As_l, Ws_h, Ws_l, wv, g, li, acc2);
  }

  // ---- phase 3: G1 = relu(h2+b2) @ Wg1 ----
  f32x4 acc3[2][8];
#pragma unroll
  for (int m = 0; m < 2; ++m)
#pragma unroll
    for (int j = 0; j < 8; ++j) acc3[m][j] = f32x4{0.f, 0.f, 0.f, 0.f};

#pragma unroll
  for (int kc = 0; kc < 128; kc += 64) {
    __syncthreads();
    stage_w(Wgh, Wgl, 128, kc, Ws_h, Ws_l, wv, rsub, xr);
    write_h_slice(acc2, bj2, kc, As_h, As_l, wv, g, li);
    __syncthreads();
    mfma_chunk(As_h, As_l, Ws_h, Ws_l, wv, g, li, acc3);
  }

  // ---- epilogue: fp32 G out ----
#pragma unroll
  for (int m = 0; m < 2; ++m)
#pragma unroll
    for (int j = 0; j < 8; ++j) {
      int c = j * 16 + li;
#pragma unroll
      for (int r = 0; r < 4; ++r) {
        int rowg = row0 + wv * 32 + m * 16 + g * 4 + r;
        G[(size_t)rowg * 128 + c] = acc3[m][j][r];
      }
    }
}

// ---------------- MFMA matmul (g2: split-bf16 in, fp32 out) ----------------

__global__ __launch_bounds__(256) void mm_g(
    const unsigned short* __restrict__ Ah, const unsigned short* __restrict__ Al,
    const unsigned short* __restrict__ Wth, const unsigned short* __restrict__ Wtl,
    float* __restrict__ Cf) {
  constexpr int K = 128;
  __shared__ __align__(16) char lds[65536];
  char* As_h = lds;
  char* As_l = lds + 16384;
  char* Ws_h = lds + 32768;
  char* Ws_l = lds + 49152;

  const int tid = threadIdx.x;
  const int lane = tid & 63;
  const int wv = tid >> 6;
  const int g = lane >> 4;
  const int li = lane & 15;
  const int row0 = blockIdx.x * 128;
  const int rsub = lane >> 3;
  const int xr = (lane & 7) ^ ((lane >> 3) & 7);

  f32x4 acc[2][8];
#pragma unroll
  for (int m = 0; m < 2; ++m)
#pragma unroll
    for (int j = 0; j < 8; ++j) acc[m][j] = f32x4{0.f, 0.f, 0.f, 0.f};

#pragma unroll
  for (int kc = 0; kc < K; kc += 64) {
    __syncthreads();
    stage_w(Wth, Wtl, K, kc, Ws_h, Ws_l, wv, rsub, xr);
#pragma unroll
    for (int j = 0; j < 4; ++j) {
      int q = wv * 4 + j;
      int r = q * 8 + rsub;
      size_t gb = ((size_t)(row0 + r) * K + kc) * 2 + (size_t)xr * 16;
      gload16((const char*)Ah + gb, As_h + q * 1024);
      gload16((const char*)Al + gb, As_l + q * 1024);
    }
    __syncthreads();
    mfma_chunk(As_h, As_l, Ws_h, Ws_l, wv, g, li, acc);
  }

#pragma unroll
  for (int m = 0; m < 2; ++m)
#pragma unroll
    for (int j = 0; j < 8; ++j) {
      int c = j * 16 + li;
#pragma unroll
      for (int r = 0; r < 4; ++r) {
        int rowg = row0 + wv * 32 + m * 16 + g * 4 + r;
        Cf[(size_t)rowg * 128 + c] = acc[m][j][r];
      }
    }
}

// ---------------- fused policy matmul (lp rows<NLP, hp rows>=NLP) --------

__global__ __launch_bounds__(256) void mm_policy(
    const unsigned short* __restrict__ Ah, const unsigned short* __restrict__ Al,
    const unsigned short* __restrict__ Wth_l, const unsigned short* __restrict__ Wtl_l,
    const unsigned short* __restrict__ Wth_h, const unsigned short* __restrict__ Wtl_h,
    const float* __restrict__ b1l, const float* __restrict__ b1h,
    const float* __restrict__ w2l, const float* __restrict__ w2h,
    const float* __restrict__ b2l, const float* __restrict__ b2h,
    float* __restrict__ out_l, float* __restrict__ out_h) {
  constexpr int K = 128;
  __shared__ __align__(16) char lds[65536];
  char* As_h = lds;
  char* As_l = lds + 16384;
  char* Ws_h = lds + 32768;
  char* Ws_l = lds + 49152;

  const int tid = threadIdx.x;
  const int lane = tid & 63;
  const int wv = tid >> 6;
  const int g = lane >> 4;
  const int li = lane & 15;
  const int row0 = blockIdx.x * 128;
  const bool isl = row0 < NLP;

  const unsigned short* Wth = isl ? Wth_l : Wth_h;
  const unsigned short* Wtl = isl ? Wtl_l : Wtl_h;
  const float* bias = isl ? b1l : b1h;
  const float* pw2  = isl ? w2l : w2h;
  const float* pb2  = isl ? b2l : b2h;

  f32x4 acc[2][8];
#pragma unroll
  for (int m = 0; m < 2; ++m)
#pragma unroll
    for (int j = 0; j < 8; ++j) acc[m][j] = f32x4{0.f, 0.f, 0.f, 0.f};

  const int rsub = lane >> 3;
  const int xr = (lane & 7) ^ ((lane >> 3) & 7);

#pragma unroll
  for (int kc = 0; kc < K; kc += 64) {
    __syncthreads();
    stage_w(Wth, Wtl, K, kc, Ws_h, Ws_l, wv, rsub, xr);
#pragma unroll
    for (int j = 0; j < 4; ++j) {
      int q = wv * 4 + j;
      int r = q * 8 + rsub;
      size_t ga = ((size_t)(row0 + r) * K + kc) * 2 + (size_t)xr * 16;
      gload16((const char*)Ah + ga, As_h + q * 1024);
      gload16((const char*)Al + ga, As_l + q * 1024);
    }
    __syncthreads();
    mfma_chunk(As_h, As_l, Ws_h, Ws_l, wv, g, li, acc);
  }

  // fused head: p = sigmoid( sum_c relu(acc+b1)[c] * w2[c] + b2 )
  float w2c[8], bj[8];
#pragma unroll
  for (int j = 0; j < 8; ++j) {
    w2c[j] = pw2[j * 16 + li];
    bj[j]  = bias[j * 16 + li];
  }
#pragma unroll
  for (int m = 0; m < 2; ++m)
#pragma unroll
    for (int r = 0; r < 4; ++r) {
      float p = 0.f;
#pragma unroll
      for (int j = 0; j < 8; ++j) {
        float o = fmaxf(acc[m][j][r] + bj[j], 0.f);
        p = fmaf(o, w2c[j], p);
      }
      p += __shfl_xor(p, 1);
      p += __shfl_xor(p, 2);
      p += __shfl_xor(p, 4);
      p += __shfl_xor(p, 8);
      if (li == 0) {
        int rowg = row0 + wv * 32 + m * 16 + g * 4 + r;
        if (isl) {
          if (rowg < N_L) out_l[rowg] = 1.0f / (1.0f + expf(-(p + pb2[0])));
        } else {
          out_h[rowg - HBASE] = 1.0f / (1.0f + expf(-(p + pb2[0])));
        }
      }
    }
}

// ---------------- GCN aggregation (scalar edge path) ----------------
// out[v] = relu( dinv[v]^2*h[v] + sum_e c_e*h[src_e] + b ), split-bf16 out.
// v, e0, e1, edge words all wave-uniform -> SGPRs; gathers issue 16-deep
// from scalar bases with no cross-lane ops in the chain.

__global__ __launch_bounds__(256) void agg_packed(const float* __restrict__ Hin,
                                                  const float* __restrict__ dinvg,
                                                  const int* __restrict__ rowptr,
                                                  const unsigned* __restrict__ eg,
                                                  const float* __restrict__ bias,
                                                  unsigned short* __restrict__ Oh,
                                                  unsigned short* __restrict__ Ol) {
  int b = blockIdx.x;                 // 26400 blocks
  {
    int x = b & 7, j = b >> 3;        // j in [0,3300)
    b = (j < 1252) ? (x * 1252 + j) : (10016 + x * 2048 + (j - 1252));
  }
  const int v = __builtin_amdgcn_readfirstlane(b * 4 + (threadIdx.x >> 6));
  const int lane = threadIdx.x & 63;
  const float2* H2 = (const float2*)Hin;

  const int e0 = __builtin_amdgcn_readfirstlane(rowptr[v]);
  const int e1 = __builtin_amdgcn_readfirstlane(rowptr[v + 1]);

  float dv = dinvg[v];                 // uniform address -> scalar load
  float2 h = H2[(size_t)v * 64 + lane];
  float2 acc;
  acc.x = h.x * dv * dv;
  acc.y = h.y * dv * dv;

  for (int e = e0; e < e1; e += 16) {
    // wave-uniform edge words (SGPR); eg padded, over-read is safe
    unsigned pe[16];
#pragma unroll
    for (int i = 0; i < 16; ++i)
      pe[i] = __builtin_amdgcn_readfirstlane(eg[e + i]);

    float2 xs[16];
    float cs[16];
#pragma unroll
    for (int i = 0; i < 16; ++i) {
      unsigned p = pe[i];
      xs[i] = H2[(size_t)(p & 0x1FFFF) * 64 + lane];
      cs[i] = (e + i < e1)
                  ? __half2float(__ushort_as_half((unsigned short)(p >> 17)))
                  : 0.f;
    }
#pragma unroll
    for (int i = 0; i < 16; ++i) {
      acc.x = fmaf(xs[i].x, cs[i], acc.x);
      acc.y = fmaf(xs[i].y, cs[i], acc.y);
    }
  }

  float2 b2 = ((const float2*)bias)[lane];
  acc.x = fmaxf(acc.x + b2.x, 0.f);
  acc.y = fmaxf(acc.y + b2.y, 0.f);

  unsigned short hx, lx, hy, ly;
  split2(acc.x, hx, lx);
  split2(acc.y, hy, ly);
  ushort2 th, tl;
  th.x = hx; th.y = hy;
  tl.x = lx; tl.y = ly;
  ((ushort2*)Oh)[(size_t)v * 64 + lane] = th;
  ((ushort2*)Ol)[(size_t)v * 64 + lane] = tl;
}

// ---------------- value head ----------------

__global__ __launch_bounds__(128) void colsum_split(const unsigned short* __restrict__ Hh,
                                                    const unsigned short* __restrict__ Hl,
                                                    float* __restrict__ hsum, int n) {
  int f = threadIdx.x;
  int r0 = blockIdx.x * 128;
  int r1 = min(r0 + 128, n);
  float acc = 0.f;
  for (int r = r0; r < r1; ++r) {
    size_t idx = (size_t)r * 128 + f;
    acc += bfhi_f(Hh[idx]) + bfhi_f(Hl[idx]);
  }
  atomicAdd(&hsum[f], acc);
}

__global__ __launch_bounds__(128) void value_kernel(const float* __restrict__ hsum,
                                                    const float* __restrict__ w1,
                                                    const float* __restrict__ b1,
                                                    const float* __restrict__ w2,
                                                    const float* __restrict__ b2,
                                                    float* __restrict__ out) {
  __shared__ float hm[128];
  __shared__ float red[128];
  int t = threadIdx.x;
  hm[t] = hsum[t] * (1.0f / (float)N_L);
  __syncthreads();
  float acc = b1[t];
  for (int k = 0; k < 128; ++k) acc = fmaf(hm[k], w1[k * 128 + t], acc);
  red[t] = fmaxf(acc, 0.f) * w2[t];
  for (int off = 64; off > 0; off >>= 1) {
    __syncthreads();
    if (t < off) red[t] += red[t + off];
  }
  __syncthreads();
  if (t == 0) out[0] = red[0] + b2[0];
}

__global__ __launch_bounds__(64) void mask_kernel(const float* __restrict__ lp,
                                                  float* __restrict__ out) {
  int i = threadIdx.x;
  if (i < L_H) out[i] = (lp[i] > 0.5f) ? 1.0f : 0.0f;
}

// ---------------- driver ----------------

extern "C" void kernel_launch(void* const* d_in, const int* in_sizes, int n_in,
                              void* d_out, int out_size, void* d_ws, size_t ws_size,
                              hipStream_t stream) {
  const float* x      = (const float*)d_in[0];
  const int*   ei     = (const int*)d_in[1];
  const float* head_x = (const float*)d_in[2];
  const int*   hei    = (const int*)d_in[3];
  const float* enc_w1 = (const float*)d_in[4];
  const float* enc_b1 = (const float*)d_in[5];
  const float* enc_w2 = (const float*)d_in[6];
  const float* enc_b2 = (const float*)d_in[7];
  const float* gnn_w1 = (const float*)d_in[8];
  const float* gnn_b1 = (const float*)d_in[9];
  const float* gnn_w2 = (const float*)d_in[10];
  const float* gnn_b2 = (const float*)d_in[11];
  const float* lp_w1  = (const float*)d_in[12];
  const float* lp_b1  = (const float*)d_in[13];
  const float* lp_w2  = (const float*)d_in[14];
  const float* lp_b2  = (const float*)d_in[15];
  const float* hp_w1  = (const float*)d_in[16];
  const float* hp_b1  = (const float*)d_in[17];
  const float* hp_w2  = (const float*)d_in[18];
  const float* hp_b2  = (const float*)d_in[19];
  const float* v_w1   = (const float*)d_in[20];
  const float* v_b1   = (const float*)d_in[21];
  const float* v_w2   = (const float*)d_in[22];
  const float* v_b2   = (const float*)d_in[23];
  float* out = (float*)d_out;

  // ---- workspace layout ----
  const size_t ELE = (size_t)R_T * 128;
  char* base = (char*)d_ws;
  float* SAf = (float*)base;                   // SLOT_A (fp32 G buffer)
  char* baseB = base + ELE * 4;
  unsigned short* SBh = (unsigned short*)baseB;
  unsigned short* SBl = SBh + ELE;
  unsigned short* WTh = (unsigned short*)(baseB + ELE * 4);
  unsigned short* WTl = WTh + 114688;
  float* dinv_g = (float*)(WTl + 114688);      // [R_T]
  float* hsum   = dinv_g + R_T;                // [128]
  int* ip       = (int*)(hsum + 128);
  int* indeg_g  = ip;  ip += R_T;              // doubles as rowpos
  int* rowptr_g = ip;  ip += R_T + 1;
  unsigned* eg  = (unsigned*)ip;  ip += E_T + 16;
  int* bsum     = ip;  ip += 112;

  const int WT_ENC1 = 0, WT_ENC2 = 32768, WT_G1 = 49152, WT_G2 = 65536,
            WT_LP = 81920, WT_HP = 98304;

  const int OUT_LP = 0, OUT_HP = N_L, OUT_MASK = N_L + N_HT, OUT_SV = N_L + N_HT + L_H;

  // ---- CSR + dinv + weight split ----
  hipMemsetAsync(indeg_g, 0, (size_t)R_T * sizeof(int), stream);
  hipMemsetAsync(hsum, 0, 128 * sizeof(float), stream);

  conv_weights<<<448, 256, 0, stream>>>(enc_w1, enc_w2, gnn_w1, gnn_w2, lp_w1, hp_w1,
                                        WTh, WTl);

  count_deg_all<<<(E_T + 255) / 256, 256, 0, stream>>>(ei, hei, indeg_g);
  dinv_kernel<<<(R_T + 255) / 256, 256, 0, stream>>>(indeg_g, dinv_g, R_T);

  scan_block<<<(R_T + 1023) / 1024, 1024, 0, stream>>>(indeg_g, R_T, rowptr_g, bsum);
  scan_top128<<<1, 64, 0, stream>>>(bsum, (R_T + 1023) / 1024);
  scan_fix<<<(R_T + 256) / 256, 256, 0, stream>>>(rowptr_g, bsum, R_T,
                                                  (R_T + 1023) / 1024, indeg_g);
  fill_csr_all<<<(E_T + 255) / 256, 256, 0, stream>>>(ei, hei, dinv_g, indeg_g, eg);

  // ---- fused encoder + g1-mm: x -> h1 -> h2 -> G1 (fp32) ----
  enc_fused<<<R_T / 128, 256, 0, stream>>>(
      x, head_x,
      WTh + WT_ENC1, WTl + WT_ENC1,
      WTh + WT_ENC2, WTl + WT_ENC2,
      WTh + WT_G1,   WTl + WT_G1,
      enc_b1, enc_b2, SAf);

  // ---- GCN layer 1 aggregate ----
  agg_packed<<<R_T / 4, 256, 0, stream>>>(SAf, dinv_g, rowptr_g, eg, gnn_b1,
                                          SBh, SBl);

  // ---- GCN layer 2 ----
  mm_g<<<R_T / 128, 256, 0, stream>>>(SBh, SBl, WTh + WT_G2, WTl + WT_G2, SAf);
  agg_packed<<<R_T / 4, 256, 0, stream>>>(SAf, dinv_g, rowptr_g, eg, gnn_b2,
                                          SBh, SBl);

  // ---- policy heads (merged lp+hp, fused sigmoid) ----
  mm_policy<<<R_T / 128, 256, 0, stream>>>(
      SBh, SBl,
      WTh + WT_LP, WTl + WT_LP, WTh + WT_HP, WTl + WT_HP,
      lp_b1, hp_b1, lp_w2, hp_w2, lp_b2, hp_b2,
      out + OUT_LP, out + OUT_HP);

  // ---- value ----
  colsum_split<<<(N_L + 127) / 128, 128, 0, stream>>>(SBh, SBl, hsum, N_L);
  value_kernel<<<1, 128, 0, stream>>>(hsum, v_w1, v_b1, v_w2, v_b2, out + OUT_SV);

  // ---- mask ----
  mask_kernel<<<1, 64, 0, stream>>>(out + OUT_LP, out + OUT_MASK);
}

// Round 8
// 497.484 us; speedup vs baseline: 1.5008x; 1.0201x over previous
//
#include <hip/hip_runtime.h>
#include <hip/hip_fp16.h>
#include <math.h>

// PruningAgent r7:
//  - agg_packed: r5-proven shfl edge broadcast (r6 scalar path reverted) +
//    HYBRID precision gather: layer rows fp32 (mask knife-edge exact),
//    head rows bf16 (halves 62% of gather volume; head_probs tolerance 2e-2).
//  - head bf16 table packed into the unused head region of the fp32 G buffer.
//  - enc_fused / mm_g epilogues: fp32 for layer rows, bf16 for head rows.

typedef unsigned short ushort_t;
using short8 = __attribute__((ext_vector_type(8))) short;
using f32x4  = __attribute__((ext_vector_type(4))) float;

constexpr int N_L  = 40000;
constexpr int E_L  = 640000;
constexpr int H_   = 128;
constexpr int L_H  = 8;
constexpr int N_H1 = 8192;
constexpr int E_H1 = 131072;
constexpr int N_HT = 65536;    // 8*8192
constexpr int E_HT = 1048576;  // 8*131072
constexpr int E_T  = E_L + E_HT;
constexpr int NLP  = 40064;    // layer rows padded to 128 (313*128)
constexpr int R_T  = 105600;   // NLP + N_HT (combined row space)
constexpr int HBASE = 40064;   // head rows start here

// ---------------- numeric helpers ----------------

__device__ __forceinline__ unsigned short bf16_rne(float f) {
  unsigned u = __float_as_uint(f);
  unsigned r = u + 0x7FFFu + ((u >> 16) & 1u);
  return (unsigned short)(r >> 16);
}
__device__ __forceinline__ float bfhi_f(unsigned short h) {
  return __uint_as_float((unsigned)h << 16);
}
__device__ __forceinline__ void split2(float f, unsigned short& h, unsigned short& l) {
  h = bf16_rne(f);
  l = bf16_rne(f - bfhi_f(h));
}

__device__ __forceinline__ void gload16(const void* g, void* l) {
  __builtin_amdgcn_global_load_lds((__attribute__((address_space(1))) void*)(g),
                                   (__attribute__((address_space(3))) void*)(l),
                                   16, 0, 0);
}

// ---------------- degree / CSR build (combined graph) ----------------

__global__ __launch_bounds__(256) void count_deg_all(const int* __restrict__ ei,
                                                     const int* __restrict__ hei,
                                                     int* __restrict__ indeg) {
  int i = blockIdx.x * 256 + threadIdx.x;
  if (i < E_L) {
    atomicAdd(&indeg[ei[E_L + i]], 1);
  } else if (i < E_T) {
    int t = i - E_L;
    int l = t >> 17, e = t & (E_H1 - 1);
    atomicAdd(&indeg[HBASE + l * N_H1 + hei[l * 2 * E_H1 + E_H1 + e]], 1);
  }
}

__global__ __launch_bounds__(256) void dinv_kernel(const int* __restrict__ indeg,
                                                   float* __restrict__ dinv, int n) {
  int i = blockIdx.x * 256 + threadIdx.x;
  if (i < n) dinv[i] = 1.0f / sqrtf((float)(indeg[i] + 1));
}

__global__ __launch_bounds__(1024) void scan_block(const int* __restrict__ in, int n,
                                                   int* __restrict__ out,
                                                   int* __restrict__ bsum) {
  __shared__ int s[1024];
  int t = threadIdx.x;
  int i = blockIdx.x * 1024 + t;
  int v = (i < n) ? in[i] : 0;
  s[t] = v;
  __syncthreads();
  for (int off = 1; off < 1024; off <<= 1) {
    int x = (t >= off) ? s[t - off] : 0;
    __syncthreads();
    s[t] += x;
    __syncthreads();
  }
  if (i < n) out[i] = s[t] - v;
  if (t == 1023) bsum[blockIdx.x] = s[t];
}

// single wave: exclusive scan of <=128 block sums; total at bsum[nb]
__global__ __launch_bounds__(64) void scan_top128(int* __restrict__ bsum, int nb) {
  int lane = threadIdx.x;
  int a = (lane < nb) ? bsum[lane] : 0;
  int b = (lane + 64 < nb) ? bsum[lane + 64] : 0;
  int ia = a;
  for (int off = 1; off < 64; off <<= 1) {
    int x = __shfl_up(ia, off);
    if (lane >= off) ia += x;
  }
  int ta = __shfl(ia, 63);
  int ib = b;
  for (int off = 1; off < 64; off <<= 1) {
    int x = __shfl_up(ib, off);
    if (lane >= off) ib += x;
  }
  int tb = __shfl(ib, 63);
  if (lane < nb) bsum[lane] = ia - a;
  if (lane + 64 < nb) bsum[lane + 64] = ta + ib - b;
  if (lane == 0) bsum[nb] = ta + tb;
}

__global__ __launch_bounds__(256) void scan_fix(int* __restrict__ rowptr,
                                                const int* __restrict__ bsum,
                                                int n, int nb,
                                                int* __restrict__ rowpos) {
  int i = blockIdx.x * 256 + threadIdx.x;
  if (i < n) {
    int v = rowptr[i] + bsum[i >> 10];
    rowptr[i] = v;
    rowpos[i] = v;
  } else if (i == n) {
    rowptr[n] = bsum[nb];
  }
}

// packed edge: src(17b) | fp16_bits(cw)<<17  (cw > 0 so sign bit is free)
__device__ __forceinline__ unsigned pack_edge(int src, float cw) {
  unsigned short hb = __half_as_ushort(__float2half(cw));
  return (unsigned)src | ((unsigned)hb << 17);
}

__global__ __launch_bounds__(256) void fill_csr_all(const int* __restrict__ ei,
                                                    const int* __restrict__ hei,
                                                    const float* __restrict__ dinvg,
                                                    int* __restrict__ rowpos,
                                                    unsigned* __restrict__ eg) {
  int i = blockIdx.x * 256 + threadIdx.x;
  if (i < E_L) {
    int dst = ei[E_L + i];
    int src = ei[i];
    int p = atomicAdd(&rowpos[dst], 1);
    eg[p] = pack_edge(src, dinvg[src] * dinvg[dst]);
  } else if (i < E_T) {
    int t = i - E_L;
    int l = t >> 17, e = t & (E_H1 - 1);
    int base = l * 2 * E_H1;
    int dst = HBASE + l * N_H1 + hei[base + E_H1 + e];
    int src = HBASE + l * N_H1 + hei[base + e];
    int p = atomicAdd(&rowpos[dst], 1);
    eg[p] = pack_edge(src, dinvg[src] * dinvg[dst]);
  }
}

// ---------------- weight pre-split (transposed) ----------------

__global__ __launch_bounds__(256) void conv_weights(
    const float* __restrict__ w0, const float* __restrict__ w1,
    const float* __restrict__ w2, const float* __restrict__ w3,
    const float* __restrict__ w4, const float* __restrict__ w5,
    unsigned short* __restrict__ th, unsigned short* __restrict__ tl) {
  int t = blockIdx.x * 256 + threadIdx.x;
  const float* src; int K, dstoff, idx;
  if (t < 32768) { src = w0; K = 256; dstoff = 0; idx = t; }
  else {
    int s = (t - 32768) >> 14;
    idx = (t - 32768) & 16383;
    K = 128;
    dstoff = 32768 + s * 16384;
    src = s == 0 ? w1 : s == 1 ? w2 : s == 2 ? w3 : s == 3 ? w4 : w5;
  }
  int k = idx >> 7, c = idx & 127;
  unsigned short h_, l_;
  split2(src[idx], h_, l_);
  th[dstoff + c * K + k] = h_;
  tl[dstoff + c * K + k] = l_;
}

// ---------------- shared mm helpers (KC=64 chunk) ----------------

__device__ __forceinline__ void stage_w(const unsigned short* Wth,
                                        const unsigned short* Wtl, int K, int kc,
                                        char* Ws_h, char* Ws_l,
                                        int wv, int rsub, int xr) {
#pragma unroll
  for (int j = 0; j < 4; ++j) {
    int q = wv * 4 + j;
    int c = q * 8 + rsub;
    size_t gb = ((size_t)c * K + kc) * 2 + (size_t)xr * 16;
    gload16((const char*)Wth + gb, Ws_h + q * 1024);
    gload16((const char*)Wtl + gb, Ws_l + q * 1024);
  }
}

__device__ __forceinline__ void mfma_chunk(const char* As_h, const char* As_l,
                                           const char* Ws_h, const char* Ws_l,
                                           int wv, int g, int li,
                                           f32x4 acc[2][8]) {
  short8 fa_h[2][2], fa_l[2][2];
#pragma unroll
  for (int m = 0; m < 2; ++m)
#pragma unroll
    for (int ks = 0; ks < 2; ++ks) {
      int row = wv * 32 + m * 16 + li;
      int off = row * 128 + ks * 64 + g * 16;
      off ^= (row & 7) << 4;
      fa_h[m][ks] = *(const short8*)(As_h + off);
      fa_l[m][ks] = *(const short8*)(As_l + off);
    }
#pragma unroll
  for (int nh = 0; nh < 2; ++nh) {
    short8 fb_h[4][2], fb_l[4][2];
#pragma unroll
    for (int n = 0; n < 4; ++n)
#pragma unroll
      for (int ks = 0; ks < 2; ++ks) {
        int c = nh * 64 + n * 16 + li;
        int off = c * 128 + ks * 64 + g * 16;
        off ^= (c & 7) << 4;
        fb_h[n][ks] = *(const short8*)(Ws_h + off);
        fb_l[n][ks] = *(const short8*)(Ws_l + off);
      }
#pragma unroll
    for (int m = 0; m < 2; ++m)
#pragma unroll
      for (int n = 0; n < 4; ++n)
#pragma unroll
        for (int ks = 0; ks < 2; ++ks) {
          f32x4 a_ = acc[m][nh * 4 + n];
          a_ = __builtin_amdgcn_mfma_f32_16x16x32_bf16(fa_h[m][ks], fb_h[n][ks], a_, 0, 0, 0);
          a_ = __builtin_amdgcn_mfma_f32_16x16x32_bf16(fa_h[m][ks], fb_l[n][ks], a_, 0, 0, 0);
          a_ = __builtin_amdgcn_mfma_f32_16x16x32_bf16(fa_l[m][ks], fb_h[n][ks], a_, 0, 0, 0);
          acc[m][nh * 4 + n] = a_;
        }
  }
}

// write h slice (cols [kc,kc+64)) from acc (+bias, relu, split) into As in
// the A-fragment layout: byte = row*128 + (((k>>3)^(row&7))<<4) + (k&7)*2
__device__ __forceinline__ void write_h_slice(const f32x4 acc[2][8],
                                              const float* bj, int kc,
                                              char* As_h, char* As_l,
                                              int wv, int g, int li) {
#pragma unroll
  for (int m = 0; m < 2; ++m)
#pragma unroll
    for (int jj = 0; jj < 4; ++jj) {
      int j = (kc >> 4) + jj;
#pragma unroll
      for (int r = 0; r < 4; ++r) {
        float o = fmaxf(acc[m][j][r] + bj[j], 0.f);
        unsigned short h_, l_;
        split2(o, h_, l_);
        int row = wv * 32 + m * 16 + g * 4 + r;
        int cl = jj * 16 + li;
        int byte = row * 128 + ((((cl >> 3) ^ (row & 7)) << 4) | ((cl & 7) * 2));
        *(unsigned short*)(As_h + byte) = h_;
        *(unsigned short*)(As_l + byte) = l_;
      }
    }
}

// G epilogue: layer rows -> fp32 G; head rows -> bf16 Hb (halved gather bytes)
__device__ __forceinline__ void write_g_out(const f32x4 acc[2][8],
                                            float* __restrict__ G,
                                            unsigned short* __restrict__ Hb,
                                            int row0, int wv, int g, int li) {
  if (row0 < NLP) {
#pragma unroll
    for (int m = 0; m < 2; ++m)
#pragma unroll
      for (int j = 0; j < 8; ++j) {
        int c = j * 16 + li;
#pragma unroll
        for (int r = 0; r < 4; ++r) {
          int rowg = row0 + wv * 32 + m * 16 + g * 4 + r;
          G[(size_t)rowg * 128 + c] = acc[m][j][r];
        }
      }
  } else {
#pragma unroll
    for (int m = 0; m < 2; ++m)
#pragma unroll
      for (int j = 0; j < 8; ++j) {
        int c = j * 16 + li;
#pragma unroll
        for (int r = 0; r < 4; ++r) {
          int rowg = row0 - HBASE + wv * 32 + m * 16 + g * 4 + r;
          Hb[(size_t)rowg * 128 + c] = bf16_rne(acc[m][j][r]);
        }
      }
  }
}

// ---------------- fused encoder + g1 matmul ----------------

__global__ __launch_bounds__(256, 2) void enc_fused(
    const float* __restrict__ x, const float* __restrict__ head_x,
    const unsigned short* __restrict__ W1h, const unsigned short* __restrict__ W1l,
    const unsigned short* __restrict__ W2h, const unsigned short* __restrict__ W2l,
    const unsigned short* __restrict__ Wgh, const unsigned short* __restrict__ Wgl,
    const float* __restrict__ b1, const float* __restrict__ b2,
    float* __restrict__ G, unsigned short* __restrict__ Hb) {
  __shared__ __align__(16) char lds[65536];
  char* As_h = lds;
  char* As_l = lds + 16384;
  char* Ws_h = lds + 32768;
  char* Ws_l = lds + 49152;

  const int tid = threadIdx.x;
  const int lane = tid & 63;
  const int wv = tid >> 6;
  const int g = lane >> 4;
  const int li = lane & 15;
  const int row0 = blockIdx.x * 128;
  const int rsub = lane >> 3;
  const int xr = (lane & 7) ^ ((lane >> 3) & 7);

  float bj1[8], bj2[8];
#pragma unroll
  for (int j = 0; j < 8; ++j) {
    bj1[j] = b1[j * 16 + li];
    bj2[j] = b2[j * 16 + li];
  }

  // ---- phase 1: h1 = x @ We1 ----
  f32x4 acc1[2][8];
#pragma unroll
  for (int m = 0; m < 2; ++m)
#pragma unroll
    for (int j = 0; j < 8; ++j) acc1[m][j] = f32x4{0.f, 0.f, 0.f, 0.f};

#pragma unroll
  for (int kc = 0; kc < 256; kc += 64) {
    __syncthreads();
    stage_w(W1h, W1l, 256, kc, Ws_h, Ws_l, wv, rsub, xr);
    {
      int r = tid >> 1, hf = tid & 1;
      int grow = row0 + r;
      const float* srcb;
      int lrow;
      if (grow < NLP) { srcb = x;      lrow = min(grow, N_L - 1); }
      else            { srcb = head_x; lrow = grow - NLP; }
      const float* src = srcb + (size_t)lrow * 256 + kc + hf * 32;
#pragma unroll
      for (int i = 0; i < 4; ++i) {
        float4 a = ((const float4*)src)[2 * i];
        float4 b = ((const float4*)src)[2 * i + 1];
        float f[8] = {a.x, a.y, a.z, a.w, b.x, b.y, b.z, b.w};
        short8 vh, vl;
#pragma unroll
        for (int e = 0; e < 8; ++e) {
          unsigned short h_, l_;
          split2(f[e], h_, l_);
          vh[e] = (short)h_;
          vl[e] = (short)l_;
        }
        int xu = hf * 4 + i;
        int u = r * 8 + (xu ^ (r & 7));
        *(short8*)(As_h + u * 16) = vh;
        *(short8*)(As_l + u * 16) = vl;
      }
    }
    __syncthreads();
    mfma_chunk(As_h, As_l, Ws_h, Ws_l, wv, g, li, acc1);
  }

  // ---- phase 2: h2 = relu(h1+b1) @ We2 ----
  f32x4 acc2[2][8];
#pragma unroll
  for (int m = 0; m < 2; ++m)
#pragma unroll
    for (int j = 0; j < 8; ++j) acc2[m][j] = f32x4{0.f, 0.f, 0.f, 0.f};

#pragma unroll
  for (int kc = 0; kc < 128; kc += 64) {
    __syncthreads();
    stage_w(W2h, W2l, 128, kc, Ws_h, Ws_l, wv, rsub, xr);
    write_h_slice(acc1, bj1, kc, As_h, As_l, wv, g, li);
    __syncthreads();
    mfma_chunk(As_h, As_l, Ws_h, Ws_l, wv, g, li, acc2);
  }

  // ---- phase 3: G1 = relu(h2+b2) @ Wg1 ----
  f32x4 acc3[2][8];
#pragma unroll
  for (int m = 0; m < 2; ++m)
#pragma unroll
    for (int j = 0; j < 8; ++j) acc3[m][j] = f32x4{0.f, 0.f, 0.f, 0.f};

#pragma unroll
  for (int kc = 0; kc < 128; kc += 64) {
    __syncthreads();
    stage_w(Wgh, Wgl, 128, kc, Ws_h, Ws_l, wv, rsub, xr);
    write_h_slice(acc2, bj2, kc, As_h, As_l, wv, g, li);
    __syncthreads();
    mfma_chunk(As_h, As_l, Ws_h, Ws_l, wv, g, li, acc3);
  }

  write_g_out(acc3, G, Hb, row0, wv, g, li);
}

// ---------------- MFMA matmul (g2: split-bf16 in, hybrid out) --------------

__global__ __launch_bounds__(256) void mm_g(
    const unsigned short* __restrict__ Ah, const unsigned short* __restrict__ Al,
    const unsigned short* __restrict__ Wth, const unsigned short* __restrict__ Wtl,
    float* __restrict__ Cf, unsigned short* __restrict__ Hb) {
  constexpr int K = 128;
  __shared__ __align__(16) char lds[65536];
  char* As_h = lds;
  char* As_l = lds + 16384;
  char* Ws_h = lds + 32768;
  char* Ws_l = lds + 49152;

  const int tid = threadIdx.x;
  const int lane = tid & 63;
  const int wv = tid >> 6;
  const int g = lane >> 4;
  const int li = lane & 15;
  const int row0 = blockIdx.x * 128;
  const int rsub = lane >> 3;
  const int xr = (lane & 7) ^ ((lane >> 3) & 7);

  f32x4 acc[2][8];
#pragma unroll
  for (int m = 0; m < 2; ++m)
#pragma unroll
    for (int j = 0; j < 8; ++j) acc[m][j] = f32x4{0.f, 0.f, 0.f, 0.f};

#pragma unroll
  for (int kc = 0; kc < K; kc += 64) {
    __syncthreads();
    stage_w(Wth, Wtl, K, kc, Ws_h, Ws_l, wv, rsub, xr);
#pragma unroll
    for (int j = 0; j < 4; ++j) {
      int q = wv * 4 + j;
      int r = q * 8 + rsub;
      size_t gb = ((size_t)(row0 + r) * K + kc) * 2 + (size_t)xr * 16;
      gload16((const char*)Ah + gb, As_h + q * 1024);
      gload16((const char*)Al + gb, As_l + q * 1024);
    }
    __syncthreads();
    mfma_chunk(As_h, As_l, Ws_h, Ws_l, wv, g, li, acc);
  }

  write_g_out(acc, Cf, Hb, row0, wv, g, li);
}

// ---------------- fused policy matmul (lp rows<NLP, hp rows>=NLP) --------

__global__ __launch_bounds__(256) void mm_policy(
    const unsigned short* __restrict__ Ah, const unsigned short* __restrict__ Al,
    const unsigned short* __restrict__ Wth_l, const unsigned short* __restrict__ Wtl_l,
    const unsigned short* __restrict__ Wth_h, const unsigned short* __restrict__ Wtl_h,
    const float* __restrict__ b1l, const float* __restrict__ b1h,
    const float* __restrict__ w2l, const float* __restrict__ w2h,
    const float* __restrict__ b2l, const float* __restrict__ b2h,
    float* __restrict__ out_l, float* __restrict__ out_h) {
  constexpr int K = 128;
  __shared__ __align__(16) char lds[65536];
  char* As_h = lds;
  char* As_l = lds + 16384;
  char* Ws_h = lds + 32768;
  char* Ws_l = lds + 49152;

  const int tid = threadIdx.x;
  const int lane = tid & 63;
  const int wv = tid >> 6;
  const int g = lane >> 4;
  const int li = lane & 15;
  const int row0 = blockIdx.x * 128;
  const bool isl = row0 < NLP;

  const unsigned short* Wth = isl ? Wth_l : Wth_h;
  const unsigned short* Wtl = isl ? Wtl_l : Wtl_h;
  const float* bias = isl ? b1l : b1h;
  const float* pw2  = isl ? w2l : w2h;
  const float* pb2  = isl ? b2l : b2h;

  f32x4 acc[2][8];
#pragma unroll
  for (int m = 0; m < 2; ++m)
#pragma unroll
    for (int j = 0; j < 8; ++j) acc[m][j] = f32x4{0.f, 0.f, 0.f, 0.f};

  const int rsub = lane >> 3;
  const int xr = (lane & 7) ^ ((lane >> 3) & 7);

#pragma unroll
  for (int kc = 0; kc < K; kc += 64) {
    __syncthreads();
    stage_w(Wth, Wtl, K, kc, Ws_h, Ws_l, wv, rsub, xr);
#pragma unroll
    for (int j = 0; j < 4; ++j) {
      int q = wv * 4 + j;
      int r = q * 8 + rsub;
      size_t ga = ((size_t)(row0 + r) * K + kc) * 2 + (size_t)xr * 16;
      gload16((const char*)Ah + ga, As_h + q * 1024);
      gload16((const char*)Al + ga, As_l + q * 1024);
    }
    __syncthreads();
    mfma_chunk(As_h, As_l, Ws_h, Ws_l, wv, g, li, acc);
  }

  // fused head: p = sigmoid( sum_c relu(acc+b1)[c] * w2[c] + b2 )
  float w2c[8], bj[8];
#pragma unroll
  for (int j = 0; j < 8; ++j) {
    w2c[j] = pw2[j * 16 + li];
    bj[j]  = bias[j * 16 + li];
  }
#pragma unroll
  for (int m = 0; m < 2; ++m)
#pragma unroll
    for (int r = 0; r < 4; ++r) {
      float p = 0.f;
#pragma unroll
      for (int j = 0; j < 8; ++j) {
        float o = fmaxf(acc[m][j][r] + bj[j], 0.f);
        p = fmaf(o, w2c[j], p);
      }
      p += __shfl_xor(p, 1);
      p += __shfl_xor(p, 2);
      p += __shfl_xor(p, 4);
      p += __shfl_xor(p, 8);
      if (li == 0) {
        int rowg = row0 + wv * 32 + m * 16 + g * 4 + r;
        if (isl) {
          if (rowg < N_L) out_l[rowg] = 1.0f / (1.0f + expf(-(p + pb2[0])));
        } else {
          out_h[rowg - HBASE] = 1.0f / (1.0f + expf(-(p + pb2[0])));
        }
      }
    }
}

// ---------------- GCN aggregation (hybrid precision gather) ----------------
// layer nodes (v<NLP): gather fp32 rows from G. head nodes: gather bf16 rows
// from Hb (half the bytes). Branch is wave-uniform (one node per wave).

__global__ __launch_bounds__(256) void agg_packed(const float* __restrict__ Hin,
                                                  const unsigned short* __restrict__ Hb,
                                                  const float* __restrict__ dinvg,
                                                  const int* __restrict__ rowptr,
                                                  const unsigned* __restrict__ eg,
                                                  const float* __restrict__ bias,
                                                  unsigned short* __restrict__ Oh,
                                                  unsigned short* __restrict__ Ol) {
  int b = blockIdx.x;                 // 26400 blocks
  {
    int x = b & 7, j = b >> 3;        // j in [0,3300)
    b = (j < 1252) ? (x * 1252 + j) : (10016 + x * 2048 + (j - 1252));
  }
  int v = b * 4 + (threadIdx.x >> 6);
  int lane = threadIdx.x & 63;
  const float2* H2 = (const float2*)Hin;
  const ushort2* Hb2 = (const ushort2*)Hb;

  float dv = dinvg[v];
  float2 acc;
  if (v < NLP) {
    float2 h = H2[(size_t)v * 64 + lane];
    acc.x = h.x * dv * dv;
    acc.y = h.y * dv * dv;
  } else {
    ushort2 t = Hb2[(size_t)(v - HBASE) * 64 + lane];
    acc.x = bfhi_f(t.x) * dv * dv;
    acc.y = bfhi_f(t.y) * dv * dv;
  }

  int e0 = rowptr[v], e1 = rowptr[v + 1];
  if (v < NLP) {
    for (int e = e0; e < e1; e += 16) {
      unsigned pr = 0;
      if (lane < 16) pr = eg[e + lane];
      float2 xs[16];
      float cs[16];
#pragma unroll
      for (int i = 0; i < 16; ++i) {
        unsigned pe = (unsigned)__shfl((int)pr, i);
        int u = pe & 0x1FFFF;
        cs[i] = (e + i < e1)
                    ? __half2float(__ushort_as_half((unsigned short)(pe >> 17)))
                    : 0.f;
        xs[i] = H2[(size_t)u * 64 + lane];
      }
#pragma unroll
      for (int i = 0; i < 16; ++i) {
        acc.x = fmaf(xs[i].x, cs[i], acc.x);
        acc.y = fmaf(xs[i].y, cs[i], acc.y);
      }
    }
  } else {
    for (int e = e0; e < e1; e += 16) {
      unsigned pr = 0;
      if (lane < 16) pr = eg[e + lane];
      ushort2 xs[16];
      float cs[16];
#pragma unroll
      for (int i = 0; i < 16; ++i) {
        unsigned pe = (unsigned)__shfl((int)pr, i);
        int u = pe & 0x1FFFF;
        cs[i] = (e + i < e1)
                    ? __half2float(__ushort_as_half((unsigned short)(pe >> 17)))
                    : 0.f;
        xs[i] = Hb2[(size_t)(u - HBASE) * 64 + lane];
      }
#pragma unroll
      for (int i = 0; i < 16; ++i) {
        acc.x = fmaf(bfhi_f(xs[i].x), cs[i], acc.x);
        acc.y = fmaf(bfhi_f(xs[i].y), cs[i], acc.y);
      }
    }
  }

  float2 b2 = ((const float2*)bias)[lane];
  acc.x = fmaxf(acc.x + b2.x, 0.f);
  acc.y = fmaxf(acc.y + b2.y, 0.f);

  unsigned short hx, lx, hy, ly;
  split2(acc.x, hx, lx);
  split2(acc.y, hy, ly);
  ushort2 th, tl;
  th.x = hx; th.y = hy;
  tl.x = lx; tl.y = ly;
  ((ushort2*)Oh)[(size_t)v * 64 + lane] = th;
  ((ushort2*)Ol)[(size_t)v * 64 + lane] = tl;
}

// ---------------- value head ----------------

__global__ __launch_bounds__(128) void colsum_split(const unsigned short* __restrict__ Hh,
                                                    const unsigned short* __restrict__ Hl,
                                                    float* __restrict__ hsum, int n) {
  int f = threadIdx.x;
  int r0 = blockIdx.x * 128;
  int r1 = min(r0 + 128, n);
  float acc = 0.f;
  for (int r = r0; r < r1; ++r) {
    size_t idx = (size_t)r * 128 + f;
    acc += bfhi_f(Hh[idx]) + bfhi_f(Hl[idx]);
  }
  atomicAdd(&hsum[f], acc);
}

__global__ __launch_bounds__(128) void value_kernel(const float* __restrict__ hsum,
                                                    const float* __restrict__ w1,
                                                    const float* __restrict__ b1,
                                                    const float* __restrict__ w2,
                                                    const float* __restrict__ b2,
                                                    float* __restrict__ out) {
  __shared__ float hm[128];
  __shared__ float red[128];
  int t = threadIdx.x;
  hm[t] = hsum[t] * (1.0f / (float)N_L);
  __syncthreads();
  float acc = b1[t];
  for (int k = 0; k < 128; ++k) acc = fmaf(hm[k], w1[k * 128 + t], acc);
  red[t] = fmaxf(acc, 0.f) * w2[t];
  for (int off = 64; off > 0; off >>= 1) {
    __syncthreads();
    if (t < off) red[t] += red[t + off];
  }
  __syncthreads();
  if (t == 0) out[0] = red[0] + b2[0];
}

__global__ __launch_bounds__(64) void mask_kernel(const float* __restrict__ lp,
                                                  float* __restrict__ out) {
  int i = threadIdx.x;
  if (i < L_H) out[i] = (lp[i] > 0.5f) ? 1.0f : 0.0f;
}

// ---------------- driver ----------------

extern "C" void kernel_launch(void* const* d_in, const int* in_sizes, int n_in,
                              void* d_out, int out_size, void* d_ws, size_t ws_size,
                              hipStream_t stream) {
  const float* x      = (const float*)d_in[0];
  const int*   ei     = (const int*)d_in[1];
  const float* head_x = (const float*)d_in[2];
  const int*   hei    = (const int*)d_in[3];
  const float* enc_w1 = (const float*)d_in[4];
  const float* enc_b1 = (const float*)d_in[5];
  const float* enc_w2 = (const float*)d_in[6];
  const float* enc_b2 = (const float*)d_in[7];
  const float* gnn_w1 = (const float*)d_in[8];
  const float* gnn_b1 = (const float*)d_in[9];
  const float* gnn_w2 = (const float*)d_in[10];
  const float* gnn_b2 = (const float*)d_in[11];
  const float* lp_w1  = (const float*)d_in[12];
  const float* lp_b1  = (const float*)d_in[13];
  const float* lp_w2  = (const float*)d_in[14];
  const float* lp_b2  = (const float*)d_in[15];
  const float* hp_w1  = (const float*)d_in[16];
  const float* hp_b1  = (const float*)d_in[17];
  const float* hp_w2  = (const float*)d_in[18];
  const float* hp_b2  = (const float*)d_in[19];
  const float* v_w1   = (const float*)d_in[20];
  const float* v_b1   = (const float*)d_in[21];
  const float* v_w2   = (const float*)d_in[22];
  const float* v_b2   = (const float*)d_in[23];
  float* out = (float*)d_out;

  // ---- workspace layout ----
  const size_t ELE = (size_t)R_T * 128;
  char* base = (char*)d_ws;
  float* SAf = (float*)base;                    // G layer rows (fp32)
  unsigned short* Hb = (unsigned short*)(SAf + (size_t)NLP * 128);  // head bf16
  char* baseB = base + ELE * 4;
  unsigned short* SBh = (unsigned short*)baseB;
  unsigned short* SBl = SBh + ELE;
  unsigned short* WTh = (unsigned short*)(baseB + ELE * 4);
  unsigned short* WTl = WTh + 114688;
  float* dinv_g = (float*)(WTl + 114688);       // [R_T]
  float* hsum   = dinv_g + R_T;                 // [128]
  int* ip       = (int*)(hsum + 128);
  int* indeg_g  = ip;  ip += R_T;               // doubles as rowpos
  int* rowptr_g = ip;  ip += R_T + 1;
  unsigned* eg  = (unsigned*)ip;  ip += E_T + 16;
  int* bsum     = ip;  ip += 112;

  const int WT_ENC1 = 0, WT_ENC2 = 32768, WT_G1 = 49152, WT_G2 = 65536,
            WT_LP = 81920, WT_HP = 98304;

  const int OUT_LP = 0, OUT_HP = N_L, OUT_MASK = N_L + N_HT, OUT_SV = N_L + N_HT + L_H;

  // ---- CSR + dinv + weight split ----
  hipMemsetAsync(indeg_g, 0, (size_t)R_T * sizeof(int), stream);
  hipMemsetAsync(hsum, 0, 128 * sizeof(float), stream);

  conv_weights<<<448, 256, 0, stream>>>(enc_w1, enc_w2, gnn_w1, gnn_w2, lp_w1, hp_w1,
                                        WTh, WTl);

  count_deg_all<<<(E_T + 255) / 256, 256, 0, stream>>>(ei, hei, indeg_g);
  dinv_kernel<<<(R_T + 255) / 256, 256, 0, stream>>>(indeg_g, dinv_g, R_T);

  scan_block<<<(R_T + 1023) / 1024, 1024, 0, stream>>>(indeg_g, R_T, rowptr_g, bsum);
  scan_top128<<<1, 64, 0, stream>>>(bsum, (R_T + 1023) / 1024);
  scan_fix<<<(R_T + 256) / 256, 256, 0, stream>>>(rowptr_g, bsum, R_T,
                                                  (R_T + 1023) / 1024, indeg_g);
  fill_csr_all<<<(E_T + 255) / 256, 256, 0, stream>>>(ei, hei, dinv_g, indeg_g, eg);

  // ---- fused encoder + g1-mm: x -> h1 -> h2 -> G1 (layer fp32 / head bf16) ----
  enc_fused<<<R_T / 128, 256, 0, stream>>>(
      x, head_x,
      WTh + WT_ENC1, WTl + WT_ENC1,
      WTh + WT_ENC2, WTl + WT_ENC2,
      WTh + WT_G1,   WTl + WT_G1,
      enc_b1, enc_b2, SAf, Hb);

  // ---- GCN layer 1 aggregate ----
  agg_packed<<<R_T / 4, 256, 0, stream>>>(SAf, Hb, dinv_g, rowptr_g, eg, gnn_b1,
                                          SBh, SBl);

  // ---- GCN layer 2 ----
  mm_g<<<R_T / 128, 256, 0, stream>>>(SBh, SBl, WTh + WT_G2, WTl + WT_G2, SAf, Hb);
  agg_packed<<<R_T / 4, 256, 0, stream>>>(SAf, Hb, dinv_g, rowptr_g, eg, gnn_b2,
                                          SBh, SBl);

  // ---- policy heads (merged lp+hp, fused sigmoid) ----
  mm_policy<<<R_T / 128, 256, 0, stream>>>(
      SBh, SBl,
      WTh + WT_LP, WTl + WT_LP, WTh + WT_HP, WTl + WT_HP,
      lp_b1, hp_b1, lp_w2, hp_w2, lp_b2, hp_b2,
      out + OUT_LP, out + OUT_HP);

  // ---- value ----
  colsum_split<<<(N_L + 127) / 128, 128, 0, stream>>>(SBh, SBl, hsum, N_L);
  value_kernel<<<1, 128, 0, stream>>>(hsum, v_w1, v_b1, v_w2, v_b2, out + OUT_SV);

  // ---- mask ----
  mask_kernel<<<1, 64, 0, stream>>>(out + OUT_LP, out + OUT_MASK);
}

// Round 9
// 473.917 us; speedup vs baseline: 1.5754x; 1.0497x over previous
//
#include <hip/hip_runtime.h>
#include <hip/hip_fp16.h>
#include <math.h>

// PruningAgent r8:
//  - agg_packed: TWO nodes per wave (32-lane halves, float4/ushort4 per lane)
//    -> 32 gathers in flight per wave, half the waves. Hybrid precision kept
//    (layer fp32 / head bf16). Swizzle updated for 8-node blocks.
//  - everything else: r7 structure unchanged.

typedef unsigned short ushort_t;
using short8 = __attribute__((ext_vector_type(8))) short;
using f32x4  = __attribute__((ext_vector_type(4))) float;

constexpr int N_L  = 40000;
constexpr int E_L  = 640000;
constexpr int H_   = 128;
constexpr int L_H  = 8;
constexpr int N_H1 = 8192;
constexpr int E_H1 = 131072;
constexpr int N_HT = 65536;    // 8*8192
constexpr int E_HT = 1048576;  // 8*131072
constexpr int E_T  = E_L + E_HT;
constexpr int NLP  = 40064;    // layer rows padded to 128 (313*128)
constexpr int R_T  = 105600;   // NLP + N_HT (combined row space)
constexpr int HBASE = 40064;   // head rows start here

// ---------------- numeric helpers ----------------

__device__ __forceinline__ unsigned short bf16_rne(float f) {
  unsigned u = __float_as_uint(f);
  unsigned r = u + 0x7FFFu + ((u >> 16) & 1u);
  return (unsigned short)(r >> 16);
}
__device__ __forceinline__ float bfhi_f(unsigned short h) {
  return __uint_as_float((unsigned)h << 16);
}
__device__ __forceinline__ void split2(float f, unsigned short& h, unsigned short& l) {
  h = bf16_rne(f);
  l = bf16_rne(f - bfhi_f(h));
}

__device__ __forceinline__ void gload16(const void* g, void* l) {
  __builtin_amdgcn_global_load_lds((__attribute__((address_space(1))) void*)(g),
                                   (__attribute__((address_space(3))) void*)(l),
                                   16, 0, 0);
}

// ---------------- degree / CSR build (combined graph) ----------------

__global__ __launch_bounds__(256) void count_deg_all(const int* __restrict__ ei,
                                                     const int* __restrict__ hei,
                                                     int* __restrict__ indeg) {
  int i = blockIdx.x * 256 + threadIdx.x;
  if (i < E_L) {
    atomicAdd(&indeg[ei[E_L + i]], 1);
  } else if (i < E_T) {
    int t = i - E_L;
    int l = t >> 17, e = t & (E_H1 - 1);
    atomicAdd(&indeg[HBASE + l * N_H1 + hei[l * 2 * E_H1 + E_H1 + e]], 1);
  }
}

__global__ __launch_bounds__(256) void dinv_kernel(const int* __restrict__ indeg,
                                                   float* __restrict__ dinv, int n) {
  int i = blockIdx.x * 256 + threadIdx.x;
  if (i < n) dinv[i] = 1.0f / sqrtf((float)(indeg[i] + 1));
}

__global__ __launch_bounds__(1024) void scan_block(const int* __restrict__ in, int n,
                                                   int* __restrict__ out,
                                                   int* __restrict__ bsum) {
  __shared__ int s[1024];
  int t = threadIdx.x;
  int i = blockIdx.x * 1024 + t;
  int v = (i < n) ? in[i] : 0;
  s[t] = v;
  __syncthreads();
  for (int off = 1; off < 1024; off <<= 1) {
    int x = (t >= off) ? s[t - off] : 0;
    __syncthreads();
    s[t] += x;
    __syncthreads();
  }
  if (i < n) out[i] = s[t] - v;
  if (t == 1023) bsum[blockIdx.x] = s[t];
}

// single wave: exclusive scan of <=128 block sums; total at bsum[nb]
__global__ __launch_bounds__(64) void scan_top128(int* __restrict__ bsum, int nb) {
  int lane = threadIdx.x;
  int a = (lane < nb) ? bsum[lane] : 0;
  int b = (lane + 64 < nb) ? bsum[lane + 64] : 0;
  int ia = a;
  for (int off = 1; off < 64; off <<= 1) {
    int x = __shfl_up(ia, off);
    if (lane >= off) ia += x;
  }
  int ta = __shfl(ia, 63);
  int ib = b;
  for (int off = 1; off < 64; off <<= 1) {
    int x = __shfl_up(ib, off);
    if (lane >= off) ib += x;
  }
  int tb = __shfl(ib, 63);
  if (lane < nb) bsum[lane] = ia - a;
  if (lane + 64 < nb) bsum[lane + 64] = ta + ib - b;
  if (lane == 0) bsum[nb] = ta + tb;
}

__global__ __launch_bounds__(256) void scan_fix(int* __restrict__ rowptr,
                                                const int* __restrict__ bsum,
                                                int n, int nb,
                                                int* __restrict__ rowpos) {
  int i = blockIdx.x * 256 + threadIdx.x;
  if (i < n) {
    int v = rowptr[i] + bsum[i >> 10];
    rowptr[i] = v;
    rowpos[i] = v;
  } else if (i == n) {
    rowptr[n] = bsum[nb];
  }
}

// packed edge: src(17b) | fp16_bits(cw)<<17  (cw > 0 so sign bit is free)
__device__ __forceinline__ unsigned pack_edge(int src, float cw) {
  unsigned short hb = __half_as_ushort(__float2half(cw));
  return (unsigned)src | ((unsigned)hb << 17);
}

__global__ __launch_bounds__(256) void fill_csr_all(const int* __restrict__ ei,
                                                    const int* __restrict__ hei,
                                                    const float* __restrict__ dinvg,
                                                    int* __restrict__ rowpos,
                                                    unsigned* __restrict__ eg) {
  int i = blockIdx.x * 256 + threadIdx.x;
  if (i < E_L) {
    int dst = ei[E_L + i];
    int src = ei[i];
    int p = atomicAdd(&rowpos[dst], 1);
    eg[p] = pack_edge(src, dinvg[src] * dinvg[dst]);
  } else if (i < E_T) {
    int t = i - E_L;
    int l = t >> 17, e = t & (E_H1 - 1);
    int base = l * 2 * E_H1;
    int dst = HBASE + l * N_H1 + hei[base + E_H1 + e];
    int src = HBASE + l * N_H1 + hei[base + e];
    int p = atomicAdd(&rowpos[dst], 1);
    eg[p] = pack_edge(src, dinvg[src] * dinvg[dst]);
  }
}

// ---------------- weight pre-split (transposed) ----------------

__global__ __launch_bounds__(256) void conv_weights(
    const float* __restrict__ w0, const float* __restrict__ w1,
    const float* __restrict__ w2, const float* __restrict__ w3,
    const float* __restrict__ w4, const float* __restrict__ w5,
    unsigned short* __restrict__ th, unsigned short* __restrict__ tl) {
  int t = blockIdx.x * 256 + threadIdx.x;
  const float* src; int K, dstoff, idx;
  if (t < 32768) { src = w0; K = 256; dstoff = 0; idx = t; }
  else {
    int s = (t - 32768) >> 14;
    idx = (t - 32768) & 16383;
    K = 128;
    dstoff = 32768 + s * 16384;
    src = s == 0 ? w1 : s == 1 ? w2 : s == 2 ? w3 : s == 3 ? w4 : w5;
  }
  int k = idx >> 7, c = idx & 127;
  unsigned short h_, l_;
  split2(src[idx], h_, l_);
  th[dstoff + c * K + k] = h_;
  tl[dstoff + c * K + k] = l_;
}

// ---------------- shared mm helpers (KC=64 chunk) ----------------

__device__ __forceinline__ void stage_w(const unsigned short* Wth,
                                        const unsigned short* Wtl, int K, int kc,
                                        char* Ws_h, char* Ws_l,
                                        int wv, int rsub, int xr) {
#pragma unroll
  for (int j = 0; j < 4; ++j) {
    int q = wv * 4 + j;
    int c = q * 8 + rsub;
    size_t gb = ((size_t)c * K + kc) * 2 + (size_t)xr * 16;
    gload16((const char*)Wth + gb, Ws_h + q * 1024);
    gload16((const char*)Wtl + gb, Ws_l + q * 1024);
  }
}

__device__ __forceinline__ void mfma_chunk(const char* As_h, const char* As_l,
                                           const char* Ws_h, const char* Ws_l,
                                           int wv, int g, int li,
                                           f32x4 acc[2][8]) {
  short8 fa_h[2][2], fa_l[2][2];
#pragma unroll
  for (int m = 0; m < 2; ++m)
#pragma unroll
    for (int ks = 0; ks < 2; ++ks) {
      int row = wv * 32 + m * 16 + li;
      int off = row * 128 + ks * 64 + g * 16;
      off ^= (row & 7) << 4;
      fa_h[m][ks] = *(const short8*)(As_h + off);
      fa_l[m][ks] = *(const short8*)(As_l + off);
    }
#pragma unroll
  for (int nh = 0; nh < 2; ++nh) {
    short8 fb_h[4][2], fb_l[4][2];
#pragma unroll
    for (int n = 0; n < 4; ++n)
#pragma unroll
      for (int ks = 0; ks < 2; ++ks) {
        int c = nh * 64 + n * 16 + li;
        int off = c * 128 + ks * 64 + g * 16;
        off ^= (c & 7) << 4;
        fb_h[n][ks] = *(const short8*)(Ws_h + off);
        fb_l[n][ks] = *(const short8*)(Ws_l + off);
      }
#pragma unroll
    for (int m = 0; m < 2; ++m)
#pragma unroll
      for (int n = 0; n < 4; ++n)
#pragma unroll
        for (int ks = 0; ks < 2; ++ks) {
          f32x4 a_ = acc[m][nh * 4 + n];
          a_ = __builtin_amdgcn_mfma_f32_16x16x32_bf16(fa_h[m][ks], fb_h[n][ks], a_, 0, 0, 0);
          a_ = __builtin_amdgcn_mfma_f32_16x16x32_bf16(fa_h[m][ks], fb_l[n][ks], a_, 0, 0, 0);
          a_ = __builtin_amdgcn_mfma_f32_16x16x32_bf16(fa_l[m][ks], fb_h[n][ks], a_, 0, 0, 0);
          acc[m][nh * 4 + n] = a_;
        }
  }
}

// write h slice (cols [kc,kc+64)) from acc (+bias, relu, split) into As in
// the A-fragment layout: byte = row*128 + (((k>>3)^(row&7))<<4) + (k&7)*2
__device__ __forceinline__ void write_h_slice(const f32x4 acc[2][8],
                                              const float* bj, int kc,
                                              char* As_h, char* As_l,
                                              int wv, int g, int li) {
#pragma unroll
  for (int m = 0; m < 2; ++m)
#pragma unroll
    for (int jj = 0; jj < 4; ++jj) {
      int j = (kc >> 4) + jj;
#pragma unroll
      for (int r = 0; r < 4; ++r) {
        float o = fmaxf(acc[m][j][r] + bj[j], 0.f);
        unsigned short h_, l_;
        split2(o, h_, l_);
        int row = wv * 32 + m * 16 + g * 4 + r;
        int cl = jj * 16 + li;
        int byte = row * 128 + ((((cl >> 3) ^ (row & 7)) << 4) | ((cl & 7) * 2));
        *(unsigned short*)(As_h + byte) = h_;
        *(unsigned short*)(As_l + byte) = l_;
      }
    }
}

// G epilogue: layer rows -> fp32 G; head rows -> bf16 Hb (halved gather bytes)
__device__ __forceinline__ void write_g_out(const f32x4 acc[2][8],
                                            float* __restrict__ G,
                                            unsigned short* __restrict__ Hb,
                                            int row0, int wv, int g, int li) {
  if (row0 < NLP) {
#pragma unroll
    for (int m = 0; m < 2; ++m)
#pragma unroll
      for (int j = 0; j < 8; ++j) {
        int c = j * 16 + li;
#pragma unroll
        for (int r = 0; r < 4; ++r) {
          int rowg = row0 + wv * 32 + m * 16 + g * 4 + r;
          G[(size_t)rowg * 128 + c] = acc[m][j][r];
        }
      }
  } else {
#pragma unroll
    for (int m = 0; m < 2; ++m)
#pragma unroll
      for (int j = 0; j < 8; ++j) {
        int c = j * 16 + li;
#pragma unroll
        for (int r = 0; r < 4; ++r) {
          int rowg = row0 - HBASE + wv * 32 + m * 16 + g * 4 + r;
          Hb[(size_t)rowg * 128 + c] = bf16_rne(acc[m][j][r]);
        }
      }
  }
}

// ---------------- fused encoder + g1 matmul ----------------

__global__ __launch_bounds__(256, 2) void enc_fused(
    const float* __restrict__ x, const float* __restrict__ head_x,
    const unsigned short* __restrict__ W1h, const unsigned short* __restrict__ W1l,
    const unsigned short* __restrict__ W2h, const unsigned short* __restrict__ W2l,
    const unsigned short* __restrict__ Wgh, const unsigned short* __restrict__ Wgl,
    const float* __restrict__ b1, const float* __restrict__ b2,
    float* __restrict__ G, unsigned short* __restrict__ Hb) {
  __shared__ __align__(16) char lds[65536];
  char* As_h = lds;
  char* As_l = lds + 16384;
  char* Ws_h = lds + 32768;
  char* Ws_l = lds + 49152;

  const int tid = threadIdx.x;
  const int lane = tid & 63;
  const int wv = tid >> 6;
  const int g = lane >> 4;
  const int li = lane & 15;
  const int row0 = blockIdx.x * 128;
  const int rsub = lane >> 3;
  const int xr = (lane & 7) ^ ((lane >> 3) & 7);

  float bj1[8], bj2[8];
#pragma unroll
  for (int j = 0; j < 8; ++j) {
    bj1[j] = b1[j * 16 + li];
    bj2[j] = b2[j * 16 + li];
  }

  // ---- phase 1: h1 = x @ We1 ----
  f32x4 acc1[2][8];
#pragma unroll
  for (int m = 0; m < 2; ++m)
#pragma unroll
    for (int j = 0; j < 8; ++j) acc1[m][j] = f32x4{0.f, 0.f, 0.f, 0.f};

#pragma unroll
  for (int kc = 0; kc < 256; kc += 64) {
    __syncthreads();
    stage_w(W1h, W1l, 256, kc, Ws_h, Ws_l, wv, rsub, xr);
    {
      int r = tid >> 1, hf = tid & 1;
      int grow = row0 + r;
      const float* srcb;
      int lrow;
      if (grow < NLP) { srcb = x;      lrow = min(grow, N_L - 1); }
      else            { srcb = head_x; lrow = grow - NLP; }
      const float* src = srcb + (size_t)lrow * 256 + kc + hf * 32;
#pragma unroll
      for (int i = 0; i < 4; ++i) {
        float4 a = ((const float4*)src)[2 * i];
        float4 b = ((const float4*)src)[2 * i + 1];
        float f[8] = {a.x, a.y, a.z, a.w, b.x, b.y, b.z, b.w};
        short8 vh, vl;
#pragma unroll
        for (int e = 0; e < 8; ++e) {
          unsigned short h_, l_;
          split2(f[e], h_, l_);
          vh[e] = (short)h_;
          vl[e] = (short)l_;
        }
        int xu = hf * 4 + i;
        int u = r * 8 + (xu ^ (r & 7));
        *(short8*)(As_h + u * 16) = vh;
        *(short8*)(As_l + u * 16) = vl;
      }
    }
    __syncthreads();
    mfma_chunk(As_h, As_l, Ws_h, Ws_l, wv, g, li, acc1);
  }

  // ---- phase 2: h2 = relu(h1+b1) @ We2 ----
  f32x4 acc2[2][8];
#pragma unroll
  for (int m = 0; m < 2; ++m)
#pragma unroll
    for (int j = 0; j < 8; ++j) acc2[m][j] = f32x4{0.f, 0.f, 0.f, 0.f};

#pragma unroll
  for (int kc = 0; kc < 128; kc += 64) {
    __syncthreads();
    stage_w(W2h, W2l, 128, kc, Ws_h, Ws_l, wv, rsub, xr);
    write_h_slice(acc1, bj1, kc, As_h, As_l, wv, g, li);
    __syncthreads();
    mfma_chunk(As_h, As_l, Ws_h, Ws_l, wv, g, li, acc2);
  }

  // ---- phase 3: G1 = relu(h2+b2) @ Wg1 ----
  f32x4 acc3[2][8];
#pragma unroll
  for (int m = 0; m < 2; ++m)
#pragma unroll
    for (int j = 0; j < 8; ++j) acc3[m][j] = f32x4{0.f, 0.f, 0.f, 0.f};

#pragma unroll
  for (int kc = 0; kc < 128; kc += 64) {
    __syncthreads();
    stage_w(Wgh, Wgl, 128, kc, Ws_h, Ws_l, wv, rsub, xr);
    write_h_slice(acc2, bj2, kc, As_h, As_l, wv, g, li);
    __syncthreads();
    mfma_chunk(As_h, As_l, Ws_h, Ws_l, wv, g, li, acc3);
  }

  write_g_out(acc3, G, Hb, row0, wv, g, li);
}

// ---------------- MFMA matmul (g2: split-bf16 in, hybrid out) --------------

__global__ __launch_bounds__(256) void mm_g(
    const unsigned short* __restrict__ Ah, const unsigned short* __restrict__ Al,
    const unsigned short* __restrict__ Wth, const unsigned short* __restrict__ Wtl,
    float* __restrict__ Cf, unsigned short* __restrict__ Hb) {
  constexpr int K = 128;
  __shared__ __align__(16) char lds[65536];
  char* As_h = lds;
  char* As_l = lds + 16384;
  char* Ws_h = lds + 32768;
  char* Ws_l = lds + 49152;

  const int tid = threadIdx.x;
  const int lane = tid & 63;
  const int wv = tid >> 6;
  const int g = lane >> 4;
  const int li = lane & 15;
  const int row0 = blockIdx.x * 128;
  const int rsub = lane >> 3;
  const int xr = (lane & 7) ^ ((lane >> 3) & 7);

  f32x4 acc[2][8];
#pragma unroll
  for (int m = 0; m < 2; ++m)
#pragma unroll
    for (int j = 0; j < 8; ++j) acc[m][j] = f32x4{0.f, 0.f, 0.f, 0.f};

#pragma unroll
  for (int kc = 0; kc < K; kc += 64) {
    __syncthreads();
    stage_w(Wth, Wtl, K, kc, Ws_h, Ws_l, wv, rsub, xr);
#pragma unroll
    for (int j = 0; j < 4; ++j) {
      int q = wv * 4 + j;
      int r = q * 8 + rsub;
      size_t gb = ((size_t)(row0 + r) * K + kc) * 2 + (size_t)xr * 16;
      gload16((const char*)Ah + gb, As_h + q * 1024);
      gload16((const char*)Al + gb, As_l + q * 1024);
    }
    __syncthreads();
    mfma_chunk(As_h, As_l, Ws_h, Ws_l, wv, g, li, acc);
  }

  write_g_out(acc, Cf, Hb, row0, wv, g, li);
}

// ---------------- fused policy matmul (lp rows<NLP, hp rows>=NLP) --------

__global__ __launch_bounds__(256) void mm_policy(
    const unsigned short* __restrict__ Ah, const unsigned short* __restrict__ Al,
    const unsigned short* __restrict__ Wth_l, const unsigned short* __restrict__ Wtl_l,
    const unsigned short* __restrict__ Wth_h, const unsigned short* __restrict__ Wtl_h,
    const float* __restrict__ b1l, const float* __restrict__ b1h,
    const float* __restrict__ w2l, const float* __restrict__ w2h,
    const float* __restrict__ b2l, const float* __restrict__ b2h,
    float* __restrict__ out_l, float* __restrict__ out_h) {
  constexpr int K = 128;
  __shared__ __align__(16) char lds[65536];
  char* As_h = lds;
  char* As_l = lds + 16384;
  char* Ws_h = lds + 32768;
  char* Ws_l = lds + 49152;

  const int tid = threadIdx.x;
  const int lane = tid & 63;
  const int wv = tid >> 6;
  const int g = lane >> 4;
  const int li = lane & 15;
  const int row0 = blockIdx.x * 128;
  const bool isl = row0 < NLP;

  const unsigned short* Wth = isl ? Wth_l : Wth_h;
  const unsigned short* Wtl = isl ? Wtl_l : Wtl_h;
  const float* bias = isl ? b1l : b1h;
  const float* pw2  = isl ? w2l : w2h;
  const float* pb2  = isl ? b2l : b2h;

  f32x4 acc[2][8];
#pragma unroll
  for (int m = 0; m < 2; ++m)
#pragma unroll
    for (int j = 0; j < 8; ++j) acc[m][j] = f32x4{0.f, 0.f, 0.f, 0.f};

  const int rsub = lane >> 3;
  const int xr = (lane & 7) ^ ((lane >> 3) & 7);

#pragma unroll
  for (int kc = 0; kc < K; kc += 64) {
    __syncthreads();
    stage_w(Wth, Wtl, K, kc, Ws_h, Ws_l, wv, rsub, xr);
#pragma unroll
    for (int j = 0; j < 4; ++j) {
      int q = wv * 4 + j;
      int r = q * 8 + rsub;
      size_t ga = ((size_t)(row0 + r) * K + kc) * 2 + (size_t)xr * 16;
      gload16((const char*)Ah + ga, As_h + q * 1024);
      gload16((const char*)Al + ga, As_l + q * 1024);
    }
    __syncthreads();
    mfma_chunk(As_h, As_l, Ws_h, Ws_l, wv, g, li, acc);
  }

  // fused head: p = sigmoid( sum_c relu(acc+b1)[c] * w2[c] + b2 )
  float w2c[8], bj[8];
#pragma unroll
  for (int j = 0; j < 8; ++j) {
    w2c[j] = pw2[j * 16 + li];
    bj[j]  = bias[j * 16 + li];
  }
#pragma unroll
  for (int m = 0; m < 2; ++m)
#pragma unroll
    for (int r = 0; r < 4; ++r) {
      float p = 0.f;
#pragma unroll
      for (int j = 0; j < 8; ++j) {
        float o = fmaxf(acc[m][j][r] + bj[j], 0.f);
        p = fmaf(o, w2c[j], p);
      }
      p += __shfl_xor(p, 1);
      p += __shfl_xor(p, 2);
      p += __shfl_xor(p, 4);
      p += __shfl_xor(p, 8);
      if (li == 0) {
        int rowg = row0 + wv * 32 + m * 16 + g * 4 + r;
        if (isl) {
          if (rowg < N_L) out_l[rowg] = 1.0f / (1.0f + expf(-(p + pb2[0])));
        } else {
          out_h[rowg - HBASE] = 1.0f / (1.0f + expf(-(p + pb2[0])));
        }
      }
    }
}

// ---------------- GCN aggregation (2 nodes/wave, hybrid precision) ---------
// wave = two 32-lane halves, one node each; fp32 rows float4/lane, bf16 rows
// ushort4/lane. 32 gathers in flight per wave. 8 nodes per block.

__global__ __launch_bounds__(256) void agg_packed(const float* __restrict__ Hin,
                                                  const unsigned short* __restrict__ Hb,
                                                  const float* __restrict__ dinvg,
                                                  const int* __restrict__ rowptr,
                                                  const unsigned* __restrict__ eg,
                                                  const float* __restrict__ bias,
                                                  unsigned short* __restrict__ Oh,
                                                  unsigned short* __restrict__ Ol) {
  int b = blockIdx.x;                 // 13200 blocks: 5008 layer + 8192 head
  {
    int x = b & 7, j = b >> 3;        // j in [0,1650)
    b = (j < 626) ? (x * 626 + j) : (5008 + x * 1024 + (j - 626));
  }
  const int lane = threadIdx.x & 63;
  const int wv = threadIdx.x >> 6;
  const int half = lane >> 5;
  const int hl = lane & 31;
  const int v = b * 8 + wv * 2 + half;

  const float4* H4 = (const float4*)Hin;
  const ushort4* Hb4 = (const ushort4*)Hb;

  float dv = dinvg[v];
  int e0 = rowptr[v], e1 = rowptr[v + 1];

  float4 acc;
  if (v < NLP) {
    float4 h = H4[(size_t)v * 32 + hl];
    acc.x = h.x * dv * dv;
    acc.y = h.y * dv * dv;
    acc.z = h.z * dv * dv;
    acc.w = h.w * dv * dv;
  } else {
    ushort4 t = Hb4[(size_t)(v - HBASE) * 32 + hl];
    acc.x = bfhi_f(t.x) * dv * dv;
    acc.y = bfhi_f(t.y) * dv * dv;
    acc.z = bfhi_f(t.z) * dv * dv;
    acc.w = bfhi_f(t.w) * dv * dv;
  }

  int nb = (e1 - e0 + 15) >> 4;
  int nbo = __shfl_xor(nb, 32);
  int nbmax = max(nb, nbo);

  if (v < NLP) {
    for (int t = 0; t < nbmax; ++t) {
      int e = e0 + t * 16;
      unsigned pr = 0;
      if (hl < 16 && e + hl < e1) pr = eg[e + hl];
      float4 xs[16];
      float cs[16];
#pragma unroll
      for (int i = 0; i < 16; ++i) {
        unsigned pe = (unsigned)__shfl((int)pr, (half << 5) | i);
        int u = pe & 0x1FFFF;
        cs[i] = (e + i < e1)
                    ? __half2float(__ushort_as_half((unsigned short)(pe >> 17)))
                    : 0.f;
        xs[i] = H4[(size_t)u * 32 + hl];
      }
#pragma unroll
      for (int i = 0; i < 16; ++i) {
        acc.x = fmaf(xs[i].x, cs[i], acc.x);
        acc.y = fmaf(xs[i].y, cs[i], acc.y);
        acc.z = fmaf(xs[i].z, cs[i], acc.z);
        acc.w = fmaf(xs[i].w, cs[i], acc.w);
      }
    }
  } else {
    for (int t = 0; t < nbmax; ++t) {
      int e = e0 + t * 16;
      unsigned pr = 0;
      if (hl < 16 && e + hl < e1) pr = eg[e + hl];
      ushort4 xs[16];
      float cs[16];
#pragma unroll
      for (int i = 0; i < 16; ++i) {
        unsigned pe = (unsigned)__shfl((int)pr, (half << 5) | i);
        int u = pe & 0x1FFFF;
        cs[i] = (e + i < e1)
                    ? __half2float(__ushort_as_half((unsigned short)(pe >> 17)))
                    : 0.f;
        xs[i] = Hb4[(size_t)(u - HBASE) * 32 + hl];
      }
#pragma unroll
      for (int i = 0; i < 16; ++i) {
        acc.x = fmaf(bfhi_f(xs[i].x), cs[i], acc.x);
        acc.y = fmaf(bfhi_f(xs[i].y), cs[i], acc.y);
        acc.z = fmaf(bfhi_f(xs[i].z), cs[i], acc.z);
        acc.w = fmaf(bfhi_f(xs[i].w), cs[i], acc.w);
      }
    }
  }

  float4 bb = ((const float4*)bias)[hl];
  acc.x = fmaxf(acc.x + bb.x, 0.f);
  acc.y = fmaxf(acc.y + bb.y, 0.f);
  acc.z = fmaxf(acc.z + bb.z, 0.f);
  acc.w = fmaxf(acc.w + bb.w, 0.f);

  ushort4 th, tl;
  split2(acc.x, th.x, tl.x);
  split2(acc.y, th.y, tl.y);
  split2(acc.z, th.z, tl.z);
  split2(acc.w, th.w, tl.w);
  ((ushort4*)Oh)[(size_t)v * 32 + hl] = th;
  ((ushort4*)Ol)[(size_t)v * 32 + hl] = tl;
}

// ---------------- value head ----------------

__global__ __launch_bounds__(128) void colsum_split(const unsigned short* __restrict__ Hh,
                                                    const unsigned short* __restrict__ Hl,
                                                    float* __restrict__ hsum, int n) {
  int f = threadIdx.x;
  int r0 = blockIdx.x * 128;
  int r1 = min(r0 + 128, n);
  float acc = 0.f;
  for (int r = r0; r < r1; ++r) {
    size_t idx = (size_t)r * 128 + f;
    acc += bfhi_f(Hh[idx]) + bfhi_f(Hl[idx]);
  }
  atomicAdd(&hsum[f], acc);
}

__global__ __launch_bounds__(128) void value_kernel(const float* __restrict__ hsum,
                                                    const float* __restrict__ w1,
                                                    const float* __restrict__ b1,
                                                    const float* __restrict__ w2,
                                                    const float* __restrict__ b2,
                                                    float* __restrict__ out) {
  __shared__ float hm[128];
  __shared__ float red[128];
  int t = threadIdx.x;
  hm[t] = hsum[t] * (1.0f / (float)N_L);
  __syncthreads();
  float acc = b1[t];
  for (int k = 0; k < 128; ++k) acc = fmaf(hm[k], w1[k * 128 + t], acc);
  red[t] = fmaxf(acc, 0.f) * w2[t];
  for (int off = 64; off > 0; off >>= 1) {
    __syncthreads();
    if (t < off) red[t] += red[t + off];
  }
  __syncthreads();
  if (t == 0) out[0] = red[0] + b2[0];
}

__global__ __launch_bounds__(64) void mask_kernel(const float* __restrict__ lp,
                                                  float* __restrict__ out) {
  int i = threadIdx.x;
  if (i < L_H) out[i] = (lp[i] > 0.5f) ? 1.0f : 0.0f;
}

// ---------------- driver ----------------

extern "C" void kernel_launch(void* const* d_in, const int* in_sizes, int n_in,
                              void* d_out, int out_size, void* d_ws, size_t ws_size,
                              hipStream_t stream) {
  const float* x      = (const float*)d_in[0];
  const int*   ei     = (const int*)d_in[1];
  const float* head_x = (const float*)d_in[2];
  const int*   hei    = (const int*)d_in[3];
  const float* enc_w1 = (const float*)d_in[4];
  const float* enc_b1 = (const float*)d_in[5];
  const float* enc_w2 = (const float*)d_in[6];
  const float* enc_b2 = (const float*)d_in[7];
  const float* gnn_w1 = (const float*)d_in[8];
  const float* gnn_b1 = (const float*)d_in[9];
  const float* gnn_w2 = (const float*)d_in[10];
  const float* gnn_b2 = (const float*)d_in[11];
  const float* lp_w1  = (const float*)d_in[12];
  const float* lp_b1  = (const float*)d_in[13];
  const float* lp_w2  = (const float*)d_in[14];
  const float* lp_b2  = (const float*)d_in[15];
  const float* hp_w1  = (const float*)d_in[16];
  const float* hp_b1  = (const float*)d_in[17];
  const float* hp_w2  = (const float*)d_in[18];
  const float* hp_b2  = (const float*)d_in[19];
  const float* v_w1   = (const float*)d_in[20];
  const float* v_b1   = (const float*)d_in[21];
  const float* v_w2   = (const float*)d_in[22];
  const float* v_b2   = (const float*)d_in[23];
  float* out = (float*)d_out;

  // ---- workspace layout ----
  const size_t ELE = (size_t)R_T * 128;
  char* base = (char*)d_ws;
  float* SAf = (float*)base;                    // G layer rows (fp32)
  unsigned short* Hb = (unsigned short*)(SAf + (size_t)NLP * 128);  // head bf16
  char* baseB = base + ELE * 4;
  unsigned short* SBh = (unsigned short*)baseB;
  unsigned short* SBl = SBh + ELE;
  unsigned short* WTh = (unsigned short*)(baseB + ELE * 4);
  unsigned short* WTl = WTh + 114688;
  float* dinv_g = (float*)(WTl + 114688);       // [R_T]
  float* hsum   = dinv_g + R_T;                 // [128]
  int* ip       = (int*)(hsum + 128);
  int* indeg_g  = ip;  ip += R_T;               // doubles as rowpos
  int* rowptr_g = ip;  ip += R_T + 1;
  unsigned* eg  = (unsigned*)ip;  ip += E_T + 16;
  int* bsum     = ip;  ip += 112;

  const int WT_ENC1 = 0, WT_ENC2 = 32768, WT_G1 = 49152, WT_G2 = 65536,
            WT_LP = 81920, WT_HP = 98304;

  const int OUT_LP = 0, OUT_HP = N_L, OUT_MASK = N_L + N_HT, OUT_SV = N_L + N_HT + L_H;

  // ---- CSR + dinv + weight split ----
  hipMemsetAsync(indeg_g, 0, (size_t)R_T * sizeof(int), stream);
  hipMemsetAsync(hsum, 0, 128 * sizeof(float), stream);

  conv_weights<<<448, 256, 0, stream>>>(enc_w1, enc_w2, gnn_w1, gnn_w2, lp_w1, hp_w1,
                                        WTh, WTl);

  count_deg_all<<<(E_T + 255) / 256, 256, 0, stream>>>(ei, hei, indeg_g);
  dinv_kernel<<<(R_T + 255) / 256, 256, 0, stream>>>(indeg_g, dinv_g, R_T);

  scan_block<<<(R_T + 1023) / 1024, 1024, 0, stream>>>(indeg_g, R_T, rowptr_g, bsum);
  scan_top128<<<1, 64, 0, stream>>>(bsum, (R_T + 1023) / 1024);
  scan_fix<<<(R_T + 256) / 256, 256, 0, stream>>>(rowptr_g, bsum, R_T,
                                                  (R_T + 1023) / 1024, indeg_g);
  fill_csr_all<<<(E_T + 255) / 256, 256, 0, stream>>>(ei, hei, dinv_g, indeg_g, eg);

  // ---- fused encoder + g1-mm: x -> h1 -> h2 -> G1 (layer fp32 / head bf16) ----
  enc_fused<<<R_T / 128, 256, 0, stream>>>(
      x, head_x,
      WTh + WT_ENC1, WTl + WT_ENC1,
      WTh + WT_ENC2, WTl + WT_ENC2,
      WTh + WT_G1,   WTl + WT_G1,
      enc_b1, enc_b2, SAf, Hb);

  // ---- GCN layer 1 aggregate ----
  agg_packed<<<R_T / 8, 256, 0, stream>>>(SAf, Hb, dinv_g, rowptr_g, eg, gnn_b1,
                                          SBh, SBl);

  // ---- GCN layer 2 ----
  mm_g<<<R_T / 128, 256, 0, stream>>>(SBh, SBl, WTh + WT_G2, WTl + WT_G2, SAf, Hb);
  agg_packed<<<R_T / 8, 256, 0, stream>>>(SAf, Hb, dinv_g, rowptr_g, eg, gnn_b2,
                                          SBh, SBl);

  // ---- policy heads (merged lp+hp, fused sigmoid) ----
  mm_policy<<<R_T / 128, 256, 0, stream>>>(
      SBh, SBl,
      WTh + WT_LP, WTl + WT_LP, WTh + WT_HP, WTl + WT_HP,
      lp_b1, hp_b1, lp_w2, hp_w2, lp_b2, hp_b2,
      out + OUT_LP, out + OUT_HP);

  // ---- value ----
  colsum_split<<<(N_L + 127) / 128, 128, 0, stream>>>(SBh, SBl, hsum, N_L);
  value_kernel<<<1, 128, 0, stream>>>(hsum, v_w1, v_b1, v_w2, v_b2, out + OUT_SV);

  // ---- mask ----
  mask_kernel<<<1, 64, 0, stream>>>(out + OUT_LP, out + OUT_MASK);
}

// Round 10
// 420.120 us; speedup vs baseline: 1.7772x; 1.1281x over previous
//
#include <hip/hip_runtime.h>
#include <hip/hip_fp16.h>
#include <math.h>

// PruningAgent r9:
//  - CSR build: count pass stores atomicAdd return as per-edge rank
//    (coalesced); fill pass becomes ATOMIC-FREE (p = rowptr[dst]+rank[i]).
//    rank[] overlays SLOT_A (consumed before enc_fused writes it).
//  - everything else: r8 structure unchanged (2-node/wave hybrid agg,
//    enc_fused, mm_g, mm_policy, fused heads).

typedef unsigned short ushort_t;
using short8 = __attribute__((ext_vector_type(8))) short;
using f32x4  = __attribute__((ext_vector_type(4))) float;

constexpr int N_L  = 40000;
constexpr int E_L  = 640000;
constexpr int H_   = 128;
constexpr int L_H  = 8;
constexpr int N_H1 = 8192;
constexpr int E_H1 = 131072;
constexpr int N_HT = 65536;    // 8*8192
constexpr int E_HT = 1048576;  // 8*131072
constexpr int E_T  = E_L + E_HT;
constexpr int NLP  = 40064;    // layer rows padded to 128 (313*128)
constexpr int R_T  = 105600;   // NLP + N_HT (combined row space)
constexpr int HBASE = 40064;   // head rows start here

// ---------------- numeric helpers ----------------

__device__ __forceinline__ unsigned short bf16_rne(float f) {
  unsigned u = __float_as_uint(f);
  unsigned r = u + 0x7FFFu + ((u >> 16) & 1u);
  return (unsigned short)(r >> 16);
}
__device__ __forceinline__ float bfhi_f(unsigned short h) {
  return __uint_as_float((unsigned)h << 16);
}
__device__ __forceinline__ void split2(float f, unsigned short& h, unsigned short& l) {
  h = bf16_rne(f);
  l = bf16_rne(f - bfhi_f(h));
}

__device__ __forceinline__ void gload16(const void* g, void* l) {
  __builtin_amdgcn_global_load_lds((__attribute__((address_space(1))) void*)(g),
                                   (__attribute__((address_space(3))) void*)(l),
                                   16, 0, 0);
}

// ---------------- degree / CSR build (combined graph) ----------------
// count pass: indeg[dst]++ AND rank[i] = old value (free - atomic already
// returns it). fill pass: atomic-free placement.

__global__ __launch_bounds__(256) void count_deg_all(const int* __restrict__ ei,
                                                     const int* __restrict__ hei,
                                                     int* __restrict__ indeg,
                                                     int* __restrict__ rank) {
  int i = blockIdx.x * 256 + threadIdx.x;
  if (i < E_L) {
    rank[i] = atomicAdd(&indeg[ei[E_L + i]], 1);
  } else if (i < E_T) {
    int t = i - E_L;
    int l = t >> 17, e = t & (E_H1 - 1);
    rank[i] = atomicAdd(&indeg[HBASE + l * N_H1 + hei[l * 2 * E_H1 + E_H1 + e]], 1);
  }
}

__global__ __launch_bounds__(256) void dinv_kernel(const int* __restrict__ indeg,
                                                   float* __restrict__ dinv, int n) {
  int i = blockIdx.x * 256 + threadIdx.x;
  if (i < n) dinv[i] = 1.0f / sqrtf((float)(indeg[i] + 1));
}

__global__ __launch_bounds__(1024) void scan_block(const int* __restrict__ in, int n,
                                                   int* __restrict__ out,
                                                   int* __restrict__ bsum) {
  __shared__ int s[1024];
  int t = threadIdx.x;
  int i = blockIdx.x * 1024 + t;
  int v = (i < n) ? in[i] : 0;
  s[t] = v;
  __syncthreads();
  for (int off = 1; off < 1024; off <<= 1) {
    int x = (t >= off) ? s[t - off] : 0;
    __syncthreads();
    s[t] += x;
    __syncthreads();
  }
  if (i < n) out[i] = s[t] - v;
  if (t == 1023) bsum[blockIdx.x] = s[t];
}

// single wave: exclusive scan of <=128 block sums; total at bsum[nb]
__global__ __launch_bounds__(64) void scan_top128(int* __restrict__ bsum, int nb) {
  int lane = threadIdx.x;
  int a = (lane < nb) ? bsum[lane] : 0;
  int b = (lane + 64 < nb) ? bsum[lane + 64] : 0;
  int ia = a;
  for (int off = 1; off < 64; off <<= 1) {
    int x = __shfl_up(ia, off);
    if (lane >= off) ia += x;
  }
  int ta = __shfl(ia, 63);
  int ib = b;
  for (int off = 1; off < 64; off <<= 1) {
    int x = __shfl_up(ib, off);
    if (lane >= off) ib += x;
  }
  int tb = __shfl(ib, 63);
  if (lane < nb) bsum[lane] = ia - a;
  if (lane + 64 < nb) bsum[lane + 64] = ta + ib - b;
  if (lane == 0) bsum[nb] = ta + tb;
}

__global__ __launch_bounds__(256) void scan_fix(int* __restrict__ rowptr,
                                                const int* __restrict__ bsum,
                                                int n, int nb) {
  int i = blockIdx.x * 256 + threadIdx.x;
  if (i < n) {
    rowptr[i] += bsum[i >> 10];
  } else if (i == n) {
    rowptr[n] = bsum[nb];
  }
}

// packed edge: src(17b) | fp16_bits(cw)<<17  (cw > 0 so sign bit is free)
__device__ __forceinline__ unsigned pack_edge(int src, float cw) {
  unsigned short hb = __half_as_ushort(__float2half(cw));
  return (unsigned)src | ((unsigned)hb << 17);
}

__global__ __launch_bounds__(256) void fill_csr_all(const int* __restrict__ ei,
                                                    const int* __restrict__ hei,
                                                    const float* __restrict__ dinvg,
                                                    const int* __restrict__ rowptr,
                                                    const int* __restrict__ rank,
                                                    unsigned* __restrict__ eg) {
  int i = blockIdx.x * 256 + threadIdx.x;
  if (i < E_L) {
    int dst = ei[E_L + i];
    int src = ei[i];
    int p = rowptr[dst] + rank[i];
    eg[p] = pack_edge(src, dinvg[src] * dinvg[dst]);
  } else if (i < E_T) {
    int t = i - E_L;
    int l = t >> 17, e = t & (E_H1 - 1);
    int base = l * 2 * E_H1;
    int dst = HBASE + l * N_H1 + hei[base + E_H1 + e];
    int src = HBASE + l * N_H1 + hei[base + e];
    int p = rowptr[dst] + rank[i];
    eg[p] = pack_edge(src, dinvg[src] * dinvg[dst]);
  }
}

// ---------------- weight pre-split (transposed) ----------------

__global__ __launch_bounds__(256) void conv_weights(
    const float* __restrict__ w0, const float* __restrict__ w1,
    const float* __restrict__ w2, const float* __restrict__ w3,
    const float* __restrict__ w4, const float* __restrict__ w5,
    unsigned short* __restrict__ th, unsigned short* __restrict__ tl) {
  int t = blockIdx.x * 256 + threadIdx.x;
  const float* src; int K, dstoff, idx;
  if (t < 32768) { src = w0; K = 256; dstoff = 0; idx = t; }
  else {
    int s = (t - 32768) >> 14;
    idx = (t - 32768) & 16383;
    K = 128;
    dstoff = 32768 + s * 16384;
    src = s == 0 ? w1 : s == 1 ? w2 : s == 2 ? w3 : s == 3 ? w4 : w5;
  }
  int k = idx >> 7, c = idx & 127;
  unsigned short h_, l_;
  split2(src[idx], h_, l_);
  th[dstoff + c * K + k] = h_;
  tl[dstoff + c * K + k] = l_;
}

// ---------------- shared mm helpers (KC=64 chunk) ----------------

__device__ __forceinline__ void stage_w(const unsigned short* Wth,
                                        const unsigned short* Wtl, int K, int kc,
                                        char* Ws_h, char* Ws_l,
                                        int wv, int rsub, int xr) {
#pragma unroll
  for (int j = 0; j < 4; ++j) {
    int q = wv * 4 + j;
    int c = q * 8 + rsub;
    size_t gb = ((size_t)c * K + kc) * 2 + (size_t)xr * 16;
    gload16((const char*)Wth + gb, Ws_h + q * 1024);
    gload16((const char*)Wtl + gb, Ws_l + q * 1024);
  }
}

__device__ __forceinline__ void mfma_chunk(const char* As_h, const char* As_l,
                                           const char* Ws_h, const char* Ws_l,
                                           int wv, int g, int li,
                                           f32x4 acc[2][8]) {
  short8 fa_h[2][2], fa_l[2][2];
#pragma unroll
  for (int m = 0; m < 2; ++m)
#pragma unroll
    for (int ks = 0; ks < 2; ++ks) {
      int row = wv * 32 + m * 16 + li;
      int off = row * 128 + ks * 64 + g * 16;
      off ^= (row & 7) << 4;
      fa_h[m][ks] = *(const short8*)(As_h + off);
      fa_l[m][ks] = *(const short8*)(As_l + off);
    }
#pragma unroll
  for (int nh = 0; nh < 2; ++nh) {
    short8 fb_h[4][2], fb_l[4][2];
#pragma unroll
    for (int n = 0; n < 4; ++n)
#pragma unroll
      for (int ks = 0; ks < 2; ++ks) {
        int c = nh * 64 + n * 16 + li;
        int off = c * 128 + ks * 64 + g * 16;
        off ^= (c & 7) << 4;
        fb_h[n][ks] = *(const short8*)(Ws_h + off);
        fb_l[n][ks] = *(const short8*)(Ws_l + off);
      }
#pragma unroll
    for (int m = 0; m < 2; ++m)
#pragma unroll
      for (int n = 0; n < 4; ++n)
#pragma unroll
        for (int ks = 0; ks < 2; ++ks) {
          f32x4 a_ = acc[m][nh * 4 + n];
          a_ = __builtin_amdgcn_mfma_f32_16x16x32_bf16(fa_h[m][ks], fb_h[n][ks], a_, 0, 0, 0);
          a_ = __builtin_amdgcn_mfma_f32_16x16x32_bf16(fa_h[m][ks], fb_l[n][ks], a_, 0, 0, 0);
          a_ = __builtin_amdgcn_mfma_f32_16x16x32_bf16(fa_l[m][ks], fb_h[n][ks], a_, 0, 0, 0);
          acc[m][nh * 4 + n] = a_;
        }
  }
}

// write h slice (cols [kc,kc+64)) from acc (+bias, relu, split) into As in
// the A-fragment layout: byte = row*128 + (((k>>3)^(row&7))<<4) + (k&7)*2
__device__ __forceinline__ void write_h_slice(const f32x4 acc[2][8],
                                              const float* bj, int kc,
                                              char* As_h, char* As_l,
                                              int wv, int g, int li) {
#pragma unroll
  for (int m = 0; m < 2; ++m)
#pragma unroll
    for (int jj = 0; jj < 4; ++jj) {
      int j = (kc >> 4) + jj;
#pragma unroll
      for (int r = 0; r < 4; ++r) {
        float o = fmaxf(acc[m][j][r] + bj[j], 0.f);
        unsigned short h_, l_;
        split2(o, h_, l_);
        int row = wv * 32 + m * 16 + g * 4 + r;
        int cl = jj * 16 + li;
        int byte = row * 128 + ((((cl >> 3) ^ (row & 7)) << 4) | ((cl & 7) * 2));
        *(unsigned short*)(As_h + byte) = h_;
        *(unsigned short*)(As_l + byte) = l_;
      }
    }
}

// G epilogue: layer rows -> fp32 G; head rows -> bf16 Hb (halved gather bytes)
__device__ __forceinline__ void write_g_out(const f32x4 acc[2][8],
                                            float* __restrict__ G,
                                            unsigned short* __restrict__ Hb,
                                            int row0, int wv, int g, int li) {
  if (row0 < NLP) {
#pragma unroll
    for (int m = 0; m < 2; ++m)
#pragma unroll
      for (int j = 0; j < 8; ++j) {
        int c = j * 16 + li;
#pragma unroll
        for (int r = 0; r < 4; ++r) {
          int rowg = row0 + wv * 32 + m * 16 + g * 4 + r;
          G[(size_t)rowg * 128 + c] = acc[m][j][r];
        }
      }
  } else {
#pragma unroll
    for (int m = 0; m < 2; ++m)
#pragma unroll
      for (int j = 0; j < 8; ++j) {
        int c = j * 16 + li;
#pragma unroll
        for (int r = 0; r < 4; ++r) {
          int rowg = row0 - HBASE + wv * 32 + m * 16 + g * 4 + r;
          Hb[(size_t)rowg * 128 + c] = bf16_rne(acc[m][j][r]);
        }
      }
  }
}

// ---------------- fused encoder + g1 matmul ----------------

__global__ __launch_bounds__(256, 2) void enc_fused(
    const float* __restrict__ x, const float* __restrict__ head_x,
    const unsigned short* __restrict__ W1h, const unsigned short* __restrict__ W1l,
    const unsigned short* __restrict__ W2h, const unsigned short* __restrict__ W2l,
    const unsigned short* __restrict__ Wgh, const unsigned short* __restrict__ Wgl,
    const float* __restrict__ b1, const float* __restrict__ b2,
    float* __restrict__ G, unsigned short* __restrict__ Hb) {
  __shared__ __align__(16) char lds[65536];
  char* As_h = lds;
  char* As_l = lds + 16384;
  char* Ws_h = lds + 32768;
  char* Ws_l = lds + 49152;

  const int tid = threadIdx.x;
  const int lane = tid & 63;
  const int wv = tid >> 6;
  const int g = lane >> 4;
  const int li = lane & 15;
  const int row0 = blockIdx.x * 128;
  const int rsub = lane >> 3;
  const int xr = (lane & 7) ^ ((lane >> 3) & 7);

  float bj1[8], bj2[8];
#pragma unroll
  for (int j = 0; j < 8; ++j) {
    bj1[j] = b1[j * 16 + li];
    bj2[j] = b2[j * 16 + li];
  }

  // ---- phase 1: h1 = x @ We1 ----
  f32x4 acc1[2][8];
#pragma unroll
  for (int m = 0; m < 2; ++m)
#pragma unroll
    for (int j = 0; j < 8; ++j) acc1[m][j] = f32x4{0.f, 0.f, 0.f, 0.f};

#pragma unroll
  for (int kc = 0; kc < 256; kc += 64) {
    __syncthreads();
    stage_w(W1h, W1l, 256, kc, Ws_h, Ws_l, wv, rsub, xr);
    {
      int r = tid >> 1, hf = tid & 1;
      int grow = row0 + r;
      const float* srcb;
      int lrow;
      if (grow < NLP) { srcb = x;      lrow = min(grow, N_L - 1); }
      else            { srcb = head_x; lrow = grow - NLP; }
      const float* src = srcb + (size_t)lrow * 256 + kc + hf * 32;
#pragma unroll
      for (int i = 0; i < 4; ++i) {
        float4 a = ((const float4*)src)[2 * i];
        float4 b = ((const float4*)src)[2 * i + 1];
        float f[8] = {a.x, a.y, a.z, a.w, b.x, b.y, b.z, b.w};
        short8 vh, vl;
#pragma unroll
        for (int e = 0; e < 8; ++e) {
          unsigned short h_, l_;
          split2(f[e], h_, l_);
          vh[e] = (short)h_;
          vl[e] = (short)l_;
        }
        int xu = hf * 4 + i;
        int u = r * 8 + (xu ^ (r & 7));
        *(short8*)(As_h + u * 16) = vh;
        *(short8*)(As_l + u * 16) = vl;
      }
    }
    __syncthreads();
    mfma_chunk(As_h, As_l, Ws_h, Ws_l, wv, g, li, acc1);
  }

  // ---- phase 2: h2 = relu(h1+b1) @ We2 ----
  f32x4 acc2[2][8];
#pragma unroll
  for (int m = 0; m < 2; ++m)
#pragma unroll
    for (int j = 0; j < 8; ++j) acc2[m][j] = f32x4{0.f, 0.f, 0.f, 0.f};

#pragma unroll
  for (int kc = 0; kc < 128; kc += 64) {
    __syncthreads();
    stage_w(W2h, W2l, 128, kc, Ws_h, Ws_l, wv, rsub, xr);
    write_h_slice(acc1, bj1, kc, As_h, As_l, wv, g, li);
    __syncthreads();
    mfma_chunk(As_h, As_l, Ws_h, Ws_l, wv, g, li, acc2);
  }

  // ---- phase 3: G1 = relu(h2+b2) @ Wg1 ----
  f32x4 acc3[2][8];
#pragma unroll
  for (int m = 0; m < 2; ++m)
#pragma unroll
    for (int j = 0; j < 8; ++j) acc3[m][j] = f32x4{0.f, 0.f, 0.f, 0.f};

#pragma unroll
  for (int kc = 0; kc < 128; kc += 64) {
    __syncthreads();
    stage_w(Wgh, Wgl, 128, kc, Ws_h, Ws_l, wv, rsub, xr);
    write_h_slice(acc2, bj2, kc, As_h, As_l, wv, g, li);
    __syncthreads();
    mfma_chunk(As_h, As_l, Ws_h, Ws_l, wv, g, li, acc3);
  }

  write_g_out(acc3, G, Hb, row0, wv, g, li);
}

// ---------------- MFMA matmul (g2: split-bf16 in, hybrid out) --------------

__global__ __launch_bounds__(256) void mm_g(
    const unsigned short* __restrict__ Ah, const unsigned short* __restrict__ Al,
    const unsigned short* __restrict__ Wth, const unsigned short* __restrict__ Wtl,
    float* __restrict__ Cf, unsigned short* __restrict__ Hb) {
  constexpr int K = 128;
  __shared__ __align__(16) char lds[65536];
  char* As_h = lds;
  char* As_l = lds + 16384;
  char* Ws_h = lds + 32768;
  char* Ws_l = lds + 49152;

  const int tid = threadIdx.x;
  const int lane = tid & 63;
  const int wv = tid >> 6;
  const int g = lane >> 4;
  const int li = lane & 15;
  const int row0 = blockIdx.x * 128;
  const int rsub = lane >> 3;
  const int xr = (lane & 7) ^ ((lane >> 3) & 7);

  f32x4 acc[2][8];
#pragma unroll
  for (int m = 0; m < 2; ++m)
#pragma unroll
    for (int j = 0; j < 8; ++j) acc[m][j] = f32x4{0.f, 0.f, 0.f, 0.f};

#pragma unroll
  for (int kc = 0; kc < K; kc += 64) {
    __syncthreads();
    stage_w(Wth, Wtl, K, kc, Ws_h, Ws_l, wv, rsub, xr);
#pragma unroll
    for (int j = 0; j < 4; ++j) {
      int q = wv * 4 + j;
      int r = q * 8 + rsub;
      size_t gb = ((size_t)(row0 + r) * K + kc) * 2 + (size_t)xr * 16;
      gload16((const char*)Ah + gb, As_h + q * 1024);
      gload16((const char*)Al + gb, As_l + q * 1024);
    }
    __syncthreads();
    mfma_chunk(As_h, As_l, Ws_h, Ws_l, wv, g, li, acc);
  }

  write_g_out(acc, Cf, Hb, row0, wv, g, li);
}

// ---------------- fused policy matmul (lp rows<NLP, hp rows>=NLP) --------

__global__ __launch_bounds__(256) void mm_policy(
    const unsigned short* __restrict__ Ah, const unsigned short* __restrict__ Al,
    const unsigned short* __restrict__ Wth_l, const unsigned short* __restrict__ Wtl_l,
    const unsigned short* __restrict__ Wth_h, const unsigned short* __restrict__ Wtl_h,
    const float* __restrict__ b1l, const float* __restrict__ b1h,
    const float* __restrict__ w2l, const float* __restrict__ w2h,
    const float* __restrict__ b2l, const float* __restrict__ b2h,
    float* __restrict__ out_l, float* __restrict__ out_h) {
  constexpr int K = 128;
  __shared__ __align__(16) char lds[65536];
  char* As_h = lds;
  char* As_l = lds + 16384;
  char* Ws_h = lds + 32768;
  char* Ws_l = lds + 49152;

  const int tid = threadIdx.x;
  const int lane = tid & 63;
  const int wv = tid >> 6;
  const int g = lane >> 4;
  const int li = lane & 15;
  const int row0 = blockIdx.x * 128;
  const bool isl = row0 < NLP;

  const unsigned short* Wth = isl ? Wth_l : Wth_h;
  const unsigned short* Wtl = isl ? Wtl_l : Wtl_h;
  const float* bias = isl ? b1l : b1h;
  const float* pw2  = isl ? w2l : w2h;
  const float* pb2  = isl ? b2l : b2h;

  f32x4 acc[2][8];
#pragma unroll
  for (int m = 0; m < 2; ++m)
#pragma unroll
    for (int j = 0; j < 8; ++j) acc[m][j] = f32x4{0.f, 0.f, 0.f, 0.f};

  const int rsub = lane >> 3;
  const int xr = (lane & 7) ^ ((lane >> 3) & 7);

#pragma unroll
  for (int kc = 0; kc < K; kc += 64) {
    __syncthreads();
    stage_w(Wth, Wtl, K, kc, Ws_h, Ws_l, wv, rsub, xr);
#pragma unroll
    for (int j = 0; j < 4; ++j) {
      int q = wv * 4 + j;
      int r = q * 8 + rsub;
      size_t ga = ((size_t)(row0 + r) * K + kc) * 2 + (size_t)xr * 16;
      gload16((const char*)Ah + ga, As_h + q * 1024);
      gload16((const char*)Al + ga, As_l + q * 1024);
    }
    __syncthreads();
    mfma_chunk(As_h, As_l, Ws_h, Ws_l, wv, g, li, acc);
  }

  // fused head: p = sigmoid( sum_c relu(acc+b1)[c] * w2[c] + b2 )
  float w2c[8], bj[8];
#pragma unroll
  for (int j = 0; j < 8; ++j) {
    w2c[j] = pw2[j * 16 + li];
    bj[j]  = bias[j * 16 + li];
  }
#pragma unroll
  for (int m = 0; m < 2; ++m)
#pragma unroll
    for (int r = 0; r < 4; ++r) {
      float p = 0.f;
#pragma unroll
      for (int j = 0; j < 8; ++j) {
        float o = fmaxf(acc[m][j][r] + bj[j], 0.f);
        p = fmaf(o, w2c[j], p);
      }
      p += __shfl_xor(p, 1);
      p += __shfl_xor(p, 2);
      p += __shfl_xor(p, 4);
      p += __shfl_xor(p, 8);
      if (li == 0) {
        int rowg = row0 + wv * 32 + m * 16 + g * 4 + r;
        if (isl) {
          if (rowg < N_L) out_l[rowg] = 1.0f / (1.0f + expf(-(p + pb2[0])));
        } else {
          out_h[rowg - HBASE] = 1.0f / (1.0f + expf(-(p + pb2[0])));
        }
      }
    }
}

// ---------------- GCN aggregation (2 nodes/wave, hybrid precision) ---------

__global__ __launch_bounds__(256) void agg_packed(const float* __restrict__ Hin,
                                                  const unsigned short* __restrict__ Hb,
                                                  const float* __restrict__ dinvg,
                                                  const int* __restrict__ rowptr,
                                                  const unsigned* __restrict__ eg,
                                                  const float* __restrict__ bias,
                                                  unsigned short* __restrict__ Oh,
                                                  unsigned short* __restrict__ Ol) {
  int b = blockIdx.x;                 // 13200 blocks: 5008 layer + 8192 head
  {
    int x = b & 7, j = b >> 3;        // j in [0,1650)
    b = (j < 626) ? (x * 626 + j) : (5008 + x * 1024 + (j - 626));
  }
  const int lane = threadIdx.x & 63;
  const int wv = threadIdx.x >> 6;
  const int half = lane >> 5;
  const int hl = lane & 31;
  const int v = b * 8 + wv * 2 + half;

  const float4* H4 = (const float4*)Hin;
  const ushort4* Hb4 = (const ushort4*)Hb;

  float dv = dinvg[v];
  int e0 = rowptr[v], e1 = rowptr[v + 1];

  float4 acc;
  if (v < NLP) {
    float4 h = H4[(size_t)v * 32 + hl];
    acc.x = h.x * dv * dv;
    acc.y = h.y * dv * dv;
    acc.z = h.z * dv * dv;
    acc.w = h.w * dv * dv;
  } else {
    ushort4 t = Hb4[(size_t)(v - HBASE) * 32 + hl];
    acc.x = bfhi_f(t.x) * dv * dv;
    acc.y = bfhi_f(t.y) * dv * dv;
    acc.z = bfhi_f(t.z) * dv * dv;
    acc.w = bfhi_f(t.w) * dv * dv;
  }

  int nb = (e1 - e0 + 15) >> 4;
  int nbo = __shfl_xor(nb, 32);
  int nbmax = max(nb, nbo);

  if (v < NLP) {
    for (int t = 0; t < nbmax; ++t) {
      int e = e0 + t * 16;
      unsigned pr = 0;
      if (hl < 16 && e + hl < e1) pr = eg[e + hl];
      float4 xs[16];
      float cs[16];
#pragma unroll
      for (int i = 0; i < 16; ++i) {
        unsigned pe = (unsigned)__shfl((int)pr, (half << 5) | i);
        int u = pe & 0x1FFFF;
        cs[i] = (e + i < e1)
                    ? __half2float(__ushort_as_half((unsigned short)(pe >> 17)))
                    : 0.f;
        xs[i] = H4[(size_t)u * 32 + hl];
      }
#pragma unroll
      for (int i = 0; i < 16; ++i) {
        acc.x = fmaf(xs[i].x, cs[i], acc.x);
        acc.y = fmaf(xs[i].y, cs[i], acc.y);
        acc.z = fmaf(xs[i].z, cs[i], acc.z);
        acc.w = fmaf(xs[i].w, cs[i], acc.w);
      }
    }
  } else {
    for (int t = 0; t < nbmax; ++t) {
      int e = e0 + t * 16;
      unsigned pr = 0;
      if (hl < 16 && e + hl < e1) pr = eg[e + hl];
      ushort4 xs[16];
      float cs[16];
#pragma unroll
      for (int i = 0; i < 16; ++i) {
        unsigned pe = (unsigned)__shfl((int)pr, (half << 5) | i);
        int u = pe & 0x1FFFF;
        cs[i] = (e + i < e1)
                    ? __half2float(__ushort_as_half((unsigned short)(pe >> 17)))
                    : 0.f;
        xs[i] = Hb4[(size_t)(u - HBASE) * 32 + hl];
      }
#pragma unroll
      for (int i = 0; i < 16; ++i) {
        acc.x = fmaf(bfhi_f(xs[i].x), cs[i], acc.x);
        acc.y = fmaf(bfhi_f(xs[i].y), cs[i], acc.y);
        acc.z = fmaf(bfhi_f(xs[i].z), cs[i], acc.z);
        acc.w = fmaf(bfhi_f(xs[i].w), cs[i], acc.w);
      }
    }
  }

  float4 bb = ((const float4*)bias)[hl];
  acc.x = fmaxf(acc.x + bb.x, 0.f);
  acc.y = fmaxf(acc.y + bb.y, 0.f);
  acc.z = fmaxf(acc.z + bb.z, 0.f);
  acc.w = fmaxf(acc.w + bb.w, 0.f);

  ushort4 th, tl;
  split2(acc.x, th.x, tl.x);
  split2(acc.y, th.y, tl.y);
  split2(acc.z, th.z, tl.z);
  split2(acc.w, th.w, tl.w);
  ((ushort4*)Oh)[(size_t)v * 32 + hl] = th;
  ((ushort4*)Ol)[(size_t)v * 32 + hl] = tl;
}

// ---------------- value head ----------------

__global__ __launch_bounds__(128) void colsum_split(const unsigned short* __restrict__ Hh,
                                                    const unsigned short* __restrict__ Hl,
                                                    float* __restrict__ hsum, int n) {
  int f = threadIdx.x;
  int r0 = blockIdx.x * 128;
  int r1 = min(r0 + 128, n);
  float acc = 0.f;
  for (int r = r0; r < r1; ++r) {
    size_t idx = (size_t)r * 128 + f;
    acc += bfhi_f(Hh[idx]) + bfhi_f(Hl[idx]);
  }
  atomicAdd(&hsum[f], acc);
}

__global__ __launch_bounds__(128) void value_kernel(const float* __restrict__ hsum,
                                                    const float* __restrict__ w1,
                                                    const float* __restrict__ b1,
                                                    const float* __restrict__ w2,
                                                    const float* __restrict__ b2,
                                                    float* __restrict__ out) {
  __shared__ float hm[128];
  __shared__ float red[128];
  int t = threadIdx.x;
  hm[t] = hsum[t] * (1.0f / (float)N_L);
  __syncthreads();
  float acc = b1[t];
  for (int k = 0; k < 128; ++k) acc = fmaf(hm[k], w1[k * 128 + t], acc);
  red[t] = fmaxf(acc, 0.f) * w2[t];
  for (int off = 64; off > 0; off >>= 1) {
    __syncthreads();
    if (t < off) red[t] += red[t + off];
  }
  __syncthreads();
  if (t == 0) out[0] = red[0] + b2[0];
}

__global__ __launch_bounds__(64) void mask_kernel(const float* __restrict__ lp,
                                                  float* __restrict__ out) {
  int i = threadIdx.x;
  if (i < L_H) out[i] = (lp[i] > 0.5f) ? 1.0f : 0.0f;
}

// ---------------- driver ----------------

extern "C" void kernel_launch(void* const* d_in, const int* in_sizes, int n_in,
                              void* d_out, int out_size, void* d_ws, size_t ws_size,
                              hipStream_t stream) {
  const float* x      = (const float*)d_in[0];
  const int*   ei     = (const int*)d_in[1];
  const float* head_x = (const float*)d_in[2];
  const int*   hei    = (const int*)d_in[3];
  const float* enc_w1 = (const float*)d_in[4];
  const float* enc_b1 = (const float*)d_in[5];
  const float* enc_w2 = (const float*)d_in[6];
  const float* enc_b2 = (const float*)d_in[7];
  const float* gnn_w1 = (const float*)d_in[8];
  const float* gnn_b1 = (const float*)d_in[9];
  const float* gnn_w2 = (const float*)d_in[10];
  const float* gnn_b2 = (const float*)d_in[11];
  const float* lp_w1  = (const float*)d_in[12];
  const float* lp_b1  = (const float*)d_in[13];
  const float* lp_w2  = (const float*)d_in[14];
  const float* lp_b2  = (const float*)d_in[15];
  const float* hp_w1  = (const float*)d_in[16];
  const float* hp_b1  = (const float*)d_in[17];
  const float* hp_w2  = (const float*)d_in[18];
  const float* hp_b2  = (const float*)d_in[19];
  const float* v_w1   = (const float*)d_in[20];
  const float* v_b1   = (const float*)d_in[21];
  const float* v_w2   = (const float*)d_in[22];
  const float* v_b2   = (const float*)d_in[23];
  float* out = (float*)d_out;

  // ---- workspace layout ----
  const size_t ELE = (size_t)R_T * 128;
  char* base = (char*)d_ws;
  float* SAf = (float*)base;                    // G layer rows (fp32)
  unsigned short* Hb = (unsigned short*)(SAf + (size_t)NLP * 128);  // head bf16
  int* rank = (int*)base;                       // overlays SLOT_A (pre-enc only)
  char* baseB = base + ELE * 4;
  unsigned short* SBh = (unsigned short*)baseB;
  unsigned short* SBl = SBh + ELE;
  unsigned short* WTh = (unsigned short*)(baseB + ELE * 4);
  unsigned short* WTl = WTh + 114688;
  float* dinv_g = (float*)(WTl + 114688);       // [R_T]
  float* hsum   = dinv_g + R_T;                 // [128]
  int* ip       = (int*)(hsum + 128);
  int* indeg_g  = ip;  ip += R_T;
  int* rowptr_g = ip;  ip += R_T + 1;
  unsigned* eg  = (unsigned*)ip;  ip += E_T + 16;
  int* bsum     = ip;  ip += 112;

  const int WT_ENC1 = 0, WT_ENC2 = 32768, WT_G1 = 49152, WT_G2 = 65536,
            WT_LP = 81920, WT_HP = 98304;

  const int OUT_LP = 0, OUT_HP = N_L, OUT_MASK = N_L + N_HT, OUT_SV = N_L + N_HT + L_H;

  // ---- CSR + dinv + weight split ----
  hipMemsetAsync(indeg_g, 0, (size_t)R_T * sizeof(int), stream);
  hipMemsetAsync(hsum, 0, 128 * sizeof(float), stream);

  conv_weights<<<448, 256, 0, stream>>>(enc_w1, enc_w2, gnn_w1, gnn_w2, lp_w1, hp_w1,
                                        WTh, WTl);

  count_deg_all<<<(E_T + 255) / 256, 256, 0, stream>>>(ei, hei, indeg_g, rank);
  dinv_kernel<<<(R_T + 255) / 256, 256, 0, stream>>>(indeg_g, dinv_g, R_T);

  scan_block<<<(R_T + 1023) / 1024, 1024, 0, stream>>>(indeg_g, R_T, rowptr_g, bsum);
  scan_top128<<<1, 64, 0, stream>>>(bsum, (R_T + 1023) / 1024);
  scan_fix<<<(R_T + 256) / 256, 256, 0, stream>>>(rowptr_g, bsum, R_T,
                                                  (R_T + 1023) / 1024);
  fill_csr_all<<<(E_T + 255) / 256, 256, 0, stream>>>(ei, hei, dinv_g, rowptr_g,
                                                      rank, eg);

  // ---- fused encoder + g1-mm: x -> h1 -> h2 -> G1 (layer fp32 / head bf16) ----
  // (overwrites the rank overlay -- rank fully consumed by fill_csr_all)
  enc_fused<<<R_T / 128, 256, 0, stream>>>(
      x, head_x,
      WTh + WT_ENC1, WTl + WT_ENC1,
      WTh + WT_ENC2, WTl + WT_ENC2,
      WTh + WT_G1,   WTl + WT_G1,
      enc_b1, enc_b2, SAf, Hb);

  // ---- GCN layer 1 aggregate ----
  agg_packed<<<R_T / 8, 256, 0, stream>>>(SAf, Hb, dinv_g, rowptr_g, eg, gnn_b1,
                                          SBh, SBl);

  // ---- GCN layer 2 ----
  mm_g<<<R_T / 128, 256, 0, stream>>>(SBh, SBl, WTh + WT_G2, WTl + WT_G2, SAf, Hb);
  agg_packed<<<R_T / 8, 256, 0, stream>>>(SAf, Hb, dinv_g, rowptr_g, eg, gnn_b2,
                                          SBh, SBl);

  // ---- policy heads (merged lp+hp, fused sigmoid) ----
  mm_policy<<<R_T / 128, 256, 0, stream>>>(
      SBh, SBl,
      WTh + WT_LP, WTl + WT_LP, WTh + WT_HP, WTl + WT_HP,
      lp_b1, hp_b1, lp_w2, hp_w2, lp_b2, hp_b2,
      out + OUT_LP, out + OUT_HP);

  // ---- value ----
  colsum_split<<<(N_L + 127) / 128, 128, 0, stream>>>(SBh, SBl, hsum, N_L);
  value_kernel<<<1, 128, 0, stream>>>(hsum, v_w1, v_b1, v_w2, v_b2, out + OUT_SV);

  // ---- mask ----
  mask_kernel<<<1, 64, 0, stream>>>(out + OUT_LP, out + OUT_MASK);
}

// Round 11
// 398.981 us; speedup vs baseline: 1.8713x; 1.0530x over previous
//
#include <hip/hip_runtime.h>
#include <hip/hip_fp16.h>
#include <math.h>

// PruningAgent r10:
//  - HYBRID MFMA precision at block granularity: layer blocks (row0<NLP,
//    feed the >0.5 mask) keep split-bf16 x3-MFMA (fp32-exact); head blocks
//    (62% of rows, smooth sigmoid, 2e-2 tol) use single-bf16 x1-MFMA with
//    hi-only staging/LDS/SB-writes. template<bool SPLIT> device bodies,
//    block-uniform branch, single dispatch.
//  - agg: head nodes skip the lo-split store.
//  - r9 CSR (rank-based atomic-free fill) + r8 2-node/wave agg unchanged.

typedef unsigned short ushort_t;
using short8 = __attribute__((ext_vector_type(8))) short;
using f32x4  = __attribute__((ext_vector_type(4))) float;

constexpr int N_L  = 40000;
constexpr int E_L  = 640000;
constexpr int H_   = 128;
constexpr int L_H  = 8;
constexpr int N_H1 = 8192;
constexpr int E_H1 = 131072;
constexpr int N_HT = 65536;    // 8*8192
constexpr int E_HT = 1048576;  // 8*131072
constexpr int E_T  = E_L + E_HT;
constexpr int NLP  = 40064;    // layer rows padded to 128 (313*128)
constexpr int R_T  = 105600;   // NLP + N_HT (combined row space)
constexpr int HBASE = 40064;   // head rows start here

// ---------------- numeric helpers ----------------

__device__ __forceinline__ unsigned short bf16_rne(float f) {
  unsigned u = __float_as_uint(f);
  unsigned r = u + 0x7FFFu + ((u >> 16) & 1u);
  return (unsigned short)(r >> 16);
}
__device__ __forceinline__ float bfhi_f(unsigned short h) {
  return __uint_as_float((unsigned)h << 16);
}
__device__ __forceinline__ void split2(float f, unsigned short& h, unsigned short& l) {
  h = bf16_rne(f);
  l = bf16_rne(f - bfhi_f(h));
}

__device__ __forceinline__ void gload16(const void* g, void* l) {
  __builtin_amdgcn_global_load_lds((__attribute__((address_space(1))) void*)(g),
                                   (__attribute__((address_space(3))) void*)(l),
                                   16, 0, 0);
}

// ---------------- degree / CSR build (combined graph) ----------------

__global__ __launch_bounds__(256) void count_deg_all(const int* __restrict__ ei,
                                                     const int* __restrict__ hei,
                                                     int* __restrict__ indeg,
                                                     int* __restrict__ rank) {
  int i = blockIdx.x * 256 + threadIdx.x;
  if (i < E_L) {
    rank[i] = atomicAdd(&indeg[ei[E_L + i]], 1);
  } else if (i < E_T) {
    int t = i - E_L;
    int l = t >> 17, e = t & (E_H1 - 1);
    rank[i] = atomicAdd(&indeg[HBASE + l * N_H1 + hei[l * 2 * E_H1 + E_H1 + e]], 1);
  }
}

__global__ __launch_bounds__(256) void dinv_kernel(const int* __restrict__ indeg,
                                                   float* __restrict__ dinv, int n) {
  int i = blockIdx.x * 256 + threadIdx.x;
  if (i < n) dinv[i] = 1.0f / sqrtf((float)(indeg[i] + 1));
}

__global__ __launch_bounds__(1024) void scan_block(const int* __restrict__ in, int n,
                                                   int* __restrict__ out,
                                                   int* __restrict__ bsum) {
  __shared__ int s[1024];
  int t = threadIdx.x;
  int i = blockIdx.x * 1024 + t;
  int v = (i < n) ? in[i] : 0;
  s[t] = v;
  __syncthreads();
  for (int off = 1; off < 1024; off <<= 1) {
    int x = (t >= off) ? s[t - off] : 0;
    __syncthreads();
    s[t] += x;
    __syncthreads();
  }
  if (i < n) out[i] = s[t] - v;
  if (t == 1023) bsum[blockIdx.x] = s[t];
}

__global__ __launch_bounds__(64) void scan_top128(int* __restrict__ bsum, int nb) {
  int lane = threadIdx.x;
  int a = (lane < nb) ? bsum[lane] : 0;
  int b = (lane + 64 < nb) ? bsum[lane + 64] : 0;
  int ia = a;
  for (int off = 1; off < 64; off <<= 1) {
    int x = __shfl_up(ia, off);
    if (lane >= off) ia += x;
  }
  int ta = __shfl(ia, 63);
  int ib = b;
  for (int off = 1; off < 64; off <<= 1) {
    int x = __shfl_up(ib, off);
    if (lane >= off) ib += x;
  }
  int tb = __shfl(ib, 63);
  if (lane < nb) bsum[lane] = ia - a;
  if (lane + 64 < nb) bsum[lane + 64] = ta + ib - b;
  if (lane == 0) bsum[nb] = ta + tb;
}

__global__ __launch_bounds__(256) void scan_fix(int* __restrict__ rowptr,
                                                const int* __restrict__ bsum,
                                                int n, int nb) {
  int i = blockIdx.x * 256 + threadIdx.x;
  if (i < n) {
    rowptr[i] += bsum[i >> 10];
  } else if (i == n) {
    rowptr[n] = bsum[nb];
  }
}

__device__ __forceinline__ unsigned pack_edge(int src, float cw) {
  unsigned short hb = __half_as_ushort(__float2half(cw));
  return (unsigned)src | ((unsigned)hb << 17);
}

__global__ __launch_bounds__(256) void fill_csr_all(const int* __restrict__ ei,
                                                    const int* __restrict__ hei,
                                                    const float* __restrict__ dinvg,
                                                    const int* __restrict__ rowptr,
                                                    const int* __restrict__ rank,
                                                    unsigned* __restrict__ eg) {
  int i = blockIdx.x * 256 + threadIdx.x;
  if (i < E_L) {
    int dst = ei[E_L + i];
    int src = ei[i];
    int p = rowptr[dst] + rank[i];
    eg[p] = pack_edge(src, dinvg[src] * dinvg[dst]);
  } else if (i < E_T) {
    int t = i - E_L;
    int l = t >> 17, e = t & (E_H1 - 1);
    int base = l * 2 * E_H1;
    int dst = HBASE + l * N_H1 + hei[base + E_H1 + e];
    int src = HBASE + l * N_H1 + hei[base + e];
    int p = rowptr[dst] + rank[i];
    eg[p] = pack_edge(src, dinvg[src] * dinvg[dst]);
  }
}

// ---------------- weight pre-split (transposed) ----------------

__global__ __launch_bounds__(256) void conv_weights(
    const float* __restrict__ w0, const float* __restrict__ w1,
    const float* __restrict__ w2, const float* __restrict__ w3,
    const float* __restrict__ w4, const float* __restrict__ w5,
    unsigned short* __restrict__ th, unsigned short* __restrict__ tl) {
  int t = blockIdx.x * 256 + threadIdx.x;
  const float* src; int K, dstoff, idx;
  if (t < 32768) { src = w0; K = 256; dstoff = 0; idx = t; }
  else {
    int s = (t - 32768) >> 14;
    idx = (t - 32768) & 16383;
    K = 128;
    dstoff = 32768 + s * 16384;
    src = s == 0 ? w1 : s == 1 ? w2 : s == 2 ? w3 : s == 3 ? w4 : w5;
  }
  int k = idx >> 7, c = idx & 127;
  unsigned short h_, l_;
  split2(src[idx], h_, l_);
  th[dstoff + c * K + k] = h_;
  tl[dstoff + c * K + k] = l_;
}

// ---------------- shared mm helpers (KC=64 chunk), SPLIT-templated -------

template <bool SPLIT>
__device__ __forceinline__ void stage_w_t(const unsigned short* Wth,
                                          const unsigned short* Wtl, int K, int kc,
                                          char* Ws_h, char* Ws_l,
                                          int wv, int rsub, int xr) {
#pragma unroll
  for (int j = 0; j < 4; ++j) {
    int q = wv * 4 + j;
    int c = q * 8 + rsub;
    size_t gb = ((size_t)c * K + kc) * 2 + (size_t)xr * 16;
    gload16((const char*)Wth + gb, Ws_h + q * 1024);
    if constexpr (SPLIT) gload16((const char*)Wtl + gb, Ws_l + q * 1024);
  }
}

template <bool SPLIT>
__device__ __forceinline__ void mfma_chunk_t(const char* As_h, const char* As_l,
                                             const char* Ws_h, const char* Ws_l,
                                             int wv, int g, int li,
                                             f32x4 acc[2][8]) {
  short8 fa_h[2][2], fa_l[2][2];
#pragma unroll
  for (int m = 0; m < 2; ++m)
#pragma unroll
    for (int ks = 0; ks < 2; ++ks) {
      int row = wv * 32 + m * 16 + li;
      int off = row * 128 + ks * 64 + g * 16;
      off ^= (row & 7) << 4;
      fa_h[m][ks] = *(const short8*)(As_h + off);
      if constexpr (SPLIT) fa_l[m][ks] = *(const short8*)(As_l + off);
    }
#pragma unroll
  for (int nh = 0; nh < 2; ++nh) {
    short8 fb_h[4][2], fb_l[4][2];
#pragma unroll
    for (int n = 0; n < 4; ++n)
#pragma unroll
      for (int ks = 0; ks < 2; ++ks) {
        int c = nh * 64 + n * 16 + li;
        int off = c * 128 + ks * 64 + g * 16;
        off ^= (c & 7) << 4;
        fb_h[n][ks] = *(const short8*)(Ws_h + off);
        if constexpr (SPLIT) fb_l[n][ks] = *(const short8*)(Ws_l + off);
      }
#pragma unroll
    for (int m = 0; m < 2; ++m)
#pragma unroll
      for (int n = 0; n < 4; ++n)
#pragma unroll
        for (int ks = 0; ks < 2; ++ks) {
          f32x4 a_ = acc[m][nh * 4 + n];
          a_ = __builtin_amdgcn_mfma_f32_16x16x32_bf16(fa_h[m][ks], fb_h[n][ks], a_, 0, 0, 0);
          if constexpr (SPLIT) {
            a_ = __builtin_amdgcn_mfma_f32_16x16x32_bf16(fa_h[m][ks], fb_l[n][ks], a_, 0, 0, 0);
            a_ = __builtin_amdgcn_mfma_f32_16x16x32_bf16(fa_l[m][ks], fb_h[n][ks], a_, 0, 0, 0);
          }
          acc[m][nh * 4 + n] = a_;
        }
  }
}

// write h slice (cols [kc,kc+64)) from acc (+bias, relu, split) into As in
// the A-fragment layout: byte = row*128 + (((k>>3)^(row&7))<<4) + (k&7)*2
template <bool SPLIT>
__device__ __forceinline__ void write_h_slice_t(const f32x4 acc[2][8],
                                                const float* bj, int kc,
                                                char* As_h, char* As_l,
                                                int wv, int g, int li) {
#pragma unroll
  for (int m = 0; m < 2; ++m)
#pragma unroll
    for (int jj = 0; jj < 4; ++jj) {
      int j = (kc >> 4) + jj;
#pragma unroll
      for (int r = 0; r < 4; ++r) {
        float o = fmaxf(acc[m][j][r] + bj[j], 0.f);
        int row = wv * 32 + m * 16 + g * 4 + r;
        int cl = jj * 16 + li;
        int byte = row * 128 + ((((cl >> 3) ^ (row & 7)) << 4) | ((cl & 7) * 2));
        if constexpr (SPLIT) {
          unsigned short h_, l_;
          split2(o, h_, l_);
          *(unsigned short*)(As_h + byte) = h_;
          *(unsigned short*)(As_l + byte) = l_;
        } else {
          *(unsigned short*)(As_h + byte) = bf16_rne(o);
        }
      }
    }
}

// G epilogue: layer rows -> fp32 G; head rows -> bf16 Hb
__device__ __forceinline__ void write_g_out(const f32x4 acc[2][8],
                                            float* __restrict__ G,
                                            unsigned short* __restrict__ Hb,
                                            int row0, int wv, int g, int li) {
  if (row0 < NLP) {
#pragma unroll
    for (int m = 0; m < 2; ++m)
#pragma unroll
      for (int j = 0; j < 8; ++j) {
        int c = j * 16 + li;
#pragma unroll
        for (int r = 0; r < 4; ++r) {
          int rowg = row0 + wv * 32 + m * 16 + g * 4 + r;
          G[(size_t)rowg * 128 + c] = acc[m][j][r];
        }
      }
  } else {
#pragma unroll
    for (int m = 0; m < 2; ++m)
#pragma unroll
      for (int j = 0; j < 8; ++j) {
        int c = j * 16 + li;
#pragma unroll
        for (int r = 0; r < 4; ++r) {
          int rowg = row0 - HBASE + wv * 32 + m * 16 + g * 4 + r;
          Hb[(size_t)rowg * 128 + c] = bf16_rne(acc[m][j][r]);
        }
      }
  }
}

// ---------------- fused encoder + g1 matmul ----------------

template <bool SPLIT>
__device__ __forceinline__ void enc_body(
    const float* __restrict__ xs, int lclamp,
    const unsigned short* __restrict__ W1h, const unsigned short* __restrict__ W1l,
    const unsigned short* __restrict__ W2h, const unsigned short* __restrict__ W2l,
    const unsigned short* __restrict__ Wgh, const unsigned short* __restrict__ Wgl,
    const float* __restrict__ b1, const float* __restrict__ b2,
    float* __restrict__ G, unsigned short* __restrict__ Hb,
    char* As_h, char* As_l, char* Ws_h, char* Ws_l,
    int tid, int wv, int g, int li, int row0, int lrow0, int rsub, int xr) {
  float bj1[8], bj2[8];
#pragma unroll
  for (int j = 0; j < 8; ++j) {
    bj1[j] = b1[j * 16 + li];
    bj2[j] = b2[j * 16 + li];
  }

  // ---- phase 1: h1 = x @ We1 ----
  f32x4 acc1[2][8];
#pragma unroll
  for (int m = 0; m < 2; ++m)
#pragma unroll
    for (int j = 0; j < 8; ++j) acc1[m][j] = f32x4{0.f, 0.f, 0.f, 0.f};

#pragma unroll
  for (int kc = 0; kc < 256; kc += 64) {
    __syncthreads();
    stage_w_t<SPLIT>(W1h, W1l, 256, kc, Ws_h, Ws_l, wv, rsub, xr);
    {
      int r = tid >> 1, hf = tid & 1;
      int lrow = min(lrow0 + r, lclamp);
      const float* src = xs + (size_t)lrow * 256 + kc + hf * 32;
#pragma unroll
      for (int i = 0; i < 4; ++i) {
        float4 a = ((const float4*)src)[2 * i];
        float4 b = ((const float4*)src)[2 * i + 1];
        float f[8] = {a.x, a.y, a.z, a.w, b.x, b.y, b.z, b.w};
        short8 vh, vl;
#pragma unroll
        for (int e = 0; e < 8; ++e) {
          if constexpr (SPLIT) {
            unsigned short h_, l_;
            split2(f[e], h_, l_);
            vh[e] = (short)h_;
            vl[e] = (short)l_;
          } else {
            vh[e] = (short)bf16_rne(f[e]);
          }
        }
        int xu = hf * 4 + i;
        int u = r * 8 + (xu ^ (r & 7));
        *(short8*)(As_h + u * 16) = vh;
        if constexpr (SPLIT) *(short8*)(As_l + u * 16) = vl;
      }
    }
    __syncthreads();
    mfma_chunk_t<SPLIT>(As_h, As_l, Ws_h, Ws_l, wv, g, li, acc1);
  }

  // ---- phase 2: h2 = relu(h1+b1) @ We2 ----
  f32x4 acc2[2][8];
#pragma unroll
  for (int m = 0; m < 2; ++m)
#pragma unroll
    for (int j = 0; j < 8; ++j) acc2[m][j] = f32x4{0.f, 0.f, 0.f, 0.f};

#pragma unroll
  for (int kc = 0; kc < 128; kc += 64) {
    __syncthreads();
    stage_w_t<SPLIT>(W2h, W2l, 128, kc, Ws_h, Ws_l, wv, rsub, xr);
    write_h_slice_t<SPLIT>(acc1, bj1, kc, As_h, As_l, wv, g, li);
    __syncthreads();
    mfma_chunk_t<SPLIT>(As_h, As_l, Ws_h, Ws_l, wv, g, li, acc2);
  }

  // ---- phase 3: G1 = relu(h2+b2) @ Wg1 ----
  f32x4 acc3[2][8];
#pragma unroll
  for (int m = 0; m < 2; ++m)
#pragma unroll
    for (int j = 0; j < 8; ++j) acc3[m][j] = f32x4{0.f, 0.f, 0.f, 0.f};

#pragma unroll
  for (int kc = 0; kc < 128; kc += 64) {
    __syncthreads();
    stage_w_t<SPLIT>(Wgh, Wgl, 128, kc, Ws_h, Ws_l, wv, rsub, xr);
    write_h_slice_t<SPLIT>(acc2, bj2, kc, As_h, As_l, wv, g, li);
    __syncthreads();
    mfma_chunk_t<SPLIT>(As_h, As_l, Ws_h, Ws_l, wv, g, li, acc3);
  }

  write_g_out(acc3, G, Hb, row0, wv, g, li);
}

__global__ __launch_bounds__(256, 2) void enc_fused(
    const float* __restrict__ x, const float* __restrict__ head_x,
    const unsigned short* __restrict__ W1h, const unsigned short* __restrict__ W1l,
    const unsigned short* __restrict__ W2h, const unsigned short* __restrict__ W2l,
    const unsigned short* __restrict__ Wgh, const unsigned short* __restrict__ Wgl,
    const float* __restrict__ b1, const float* __restrict__ b2,
    float* __restrict__ G, unsigned short* __restrict__ Hb) {
  __shared__ __align__(16) char lds[65536];
  char* As_h = lds;
  char* As_l = lds + 16384;
  char* Ws_h = lds + 32768;
  char* Ws_l = lds + 49152;

  const int tid = threadIdx.x;
  const int lane = tid & 63;
  const int wv = tid >> 6;
  const int g = lane >> 4;
  const int li = lane & 15;
  const int row0 = blockIdx.x * 128;
  const int rsub = lane >> 3;
  const int xr = (lane & 7) ^ ((lane >> 3) & 7);

  if (row0 < NLP) {
    enc_body<true>(x, N_L - 1, W1h, W1l, W2h, W2l, Wgh, Wgl, b1, b2, G, Hb,
                   As_h, As_l, Ws_h, Ws_l, tid, wv, g, li, row0, row0, rsub, xr);
  } else {
    enc_body<false>(head_x, N_HT - 1, W1h, W1l, W2h, W2l, Wgh, Wgl, b1, b2, G, Hb,
                    As_h, As_l, Ws_h, Ws_l, tid, wv, g, li, row0, row0 - NLP,
                    rsub, xr);
  }
}

// ---------------- MFMA matmul (g2: split/single in, hybrid out) ------------

template <bool SPLIT>
__device__ __forceinline__ void mm_g_body(
    const unsigned short* __restrict__ Ah, const unsigned short* __restrict__ Al,
    const unsigned short* __restrict__ Wth, const unsigned short* __restrict__ Wtl,
    char* As_h, char* As_l, char* Ws_h, char* Ws_l,
    int wv, int g, int li, int row0, int rsub, int xr, f32x4 acc[2][8]) {
  constexpr int K = 128;
#pragma unroll
  for (int kc = 0; kc < K; kc += 64) {
    __syncthreads();
    stage_w_t<SPLIT>(Wth, Wtl, K, kc, Ws_h, Ws_l, wv, rsub, xr);
#pragma unroll
    for (int j = 0; j < 4; ++j) {
      int q = wv * 4 + j;
      int r = q * 8 + rsub;
      size_t gb = ((size_t)(row0 + r) * K + kc) * 2 + (size_t)xr * 16;
      gload16((const char*)Ah + gb, As_h + q * 1024);
      if constexpr (SPLIT) gload16((const char*)Al + gb, As_l + q * 1024);
    }
    __syncthreads();
    mfma_chunk_t<SPLIT>(As_h, As_l, Ws_h, Ws_l, wv, g, li, acc);
  }
}

__global__ __launch_bounds__(256) void mm_g(
    const unsigned short* __restrict__ Ah, const unsigned short* __restrict__ Al,
    const unsigned short* __restrict__ Wth, const unsigned short* __restrict__ Wtl,
    float* __restrict__ Cf, unsigned short* __restrict__ Hb) {
  __shared__ __align__(16) char lds[65536];
  char* As_h = lds;
  char* As_l = lds + 16384;
  char* Ws_h = lds + 32768;
  char* Ws_l = lds + 49152;

  const int tid = threadIdx.x;
  const int lane = tid & 63;
  const int wv = tid >> 6;
  const int g = lane >> 4;
  const int li = lane & 15;
  const int row0 = blockIdx.x * 128;
  const int rsub = lane >> 3;
  const int xr = (lane & 7) ^ ((lane >> 3) & 7);

  f32x4 acc[2][8];
#pragma unroll
  for (int m = 0; m < 2; ++m)
#pragma unroll
    for (int j = 0; j < 8; ++j) acc[m][j] = f32x4{0.f, 0.f, 0.f, 0.f};

  if (row0 < NLP)
    mm_g_body<true>(Ah, Al, Wth, Wtl, As_h, As_l, Ws_h, Ws_l,
                    wv, g, li, row0, rsub, xr, acc);
  else
    mm_g_body<false>(Ah, Al, Wth, Wtl, As_h, As_l, Ws_h, Ws_l,
                     wv, g, li, row0, rsub, xr, acc);

  write_g_out(acc, Cf, Hb, row0, wv, g, li);
}

// ---------------- fused policy matmul (lp rows<NLP, hp rows>=NLP) --------

__global__ __launch_bounds__(256) void mm_policy(
    const unsigned short* __restrict__ Ah, const unsigned short* __restrict__ Al,
    const unsigned short* __restrict__ Wth_l, const unsigned short* __restrict__ Wtl_l,
    const unsigned short* __restrict__ Wth_h, const unsigned short* __restrict__ Wtl_h,
    const float* __restrict__ b1l, const float* __restrict__ b1h,
    const float* __restrict__ w2l, const float* __restrict__ w2h,
    const float* __restrict__ b2l, const float* __restrict__ b2h,
    float* __restrict__ out_l, float* __restrict__ out_h) {
  __shared__ __align__(16) char lds[65536];
  char* As_h = lds;
  char* As_l = lds + 16384;
  char* Ws_h = lds + 32768;
  char* Ws_l = lds + 49152;

  const int tid = threadIdx.x;
  const int lane = tid & 63;
  const int wv = tid >> 6;
  const int g = lane >> 4;
  const int li = lane & 15;
  const int row0 = blockIdx.x * 128;
  const bool isl = row0 < NLP;
  const int rsub = lane >> 3;
  const int xr = (lane & 7) ^ ((lane >> 3) & 7);

  const float* bias = isl ? b1l : b1h;
  const float* pw2  = isl ? w2l : w2h;
  const float* pb2  = isl ? b2l : b2h;

  f32x4 acc[2][8];
#pragma unroll
  for (int m = 0; m < 2; ++m)
#pragma unroll
    for (int j = 0; j < 8; ++j) acc[m][j] = f32x4{0.f, 0.f, 0.f, 0.f};

  if (isl)
    mm_g_body<true>(Ah, Al, Wth_l, Wtl_l, As_h, As_l, Ws_h, Ws_l,
                    wv, g, li, row0, rsub, xr, acc);
  else
    mm_g_body<false>(Ah, Al, Wth_h, Wtl_h, As_h, As_l, Ws_h, Ws_l,
                     wv, g, li, row0, rsub, xr, acc);

  // fused head: p = sigmoid( sum_c relu(acc+b1)[c] * w2[c] + b2 )
  float w2c[8], bj[8];
#pragma unroll
  for (int j = 0; j < 8; ++j) {
    w2c[j] = pw2[j * 16 + li];
    bj[j]  = bias[j * 16 + li];
  }
#pragma unroll
  for (int m = 0; m < 2; ++m)
#pragma unroll
    for (int r = 0; r < 4; ++r) {
      float p = 0.f;
#pragma unroll
      for (int j = 0; j < 8; ++j) {
        float o = fmaxf(acc[m][j][r] + bj[j], 0.f);
        p = fmaf(o, w2c[j], p);
      }
      p += __shfl_xor(p, 1);
      p += __shfl_xor(p, 2);
      p += __shfl_xor(p, 4);
      p += __shfl_xor(p, 8);
      if (li == 0) {
        int rowg = row0 + wv * 32 + m * 16 + g * 4 + r;
        if (isl) {
          if (rowg < N_L) out_l[rowg] = 1.0f / (1.0f + expf(-(p + pb2[0])));
        } else {
          out_h[rowg - HBASE] = 1.0f / (1.0f + expf(-(p + pb2[0])));
        }
      }
    }
}

// ---------------- GCN aggregation (2 nodes/wave, hybrid precision) ---------

__global__ __launch_bounds__(256) void agg_packed(const float* __restrict__ Hin,
                                                  const unsigned short* __restrict__ Hb,
                                                  const float* __restrict__ dinvg,
                                                  const int* __restrict__ rowptr,
                                                  const unsigned* __restrict__ eg,
                                                  const float* __restrict__ bias,
                                                  unsigned short* __restrict__ Oh,
                                                  unsigned short* __restrict__ Ol) {
  int b = blockIdx.x;                 // 13200 blocks: 5008 layer + 8192 head
  {
    int x = b & 7, j = b >> 3;        // j in [0,1650)
    b = (j < 626) ? (x * 626 + j) : (5008 + x * 1024 + (j - 626));
  }
  const int lane = threadIdx.x & 63;
  const int wv = threadIdx.x >> 6;
  const int half = lane >> 5;
  const int hl = lane & 31;
  const int v = b * 8 + wv * 2 + half;

  const float4* H4 = (const float4*)Hin;
  const ushort4* Hb4 = (const ushort4*)Hb;

  float dv = dinvg[v];
  int e0 = rowptr[v], e1 = rowptr[v + 1];

  float4 acc;
  if (v < NLP) {
    float4 h = H4[(size_t)v * 32 + hl];
    acc.x = h.x * dv * dv;
    acc.y = h.y * dv * dv;
    acc.z = h.z * dv * dv;
    acc.w = h.w * dv * dv;
  } else {
    ushort4 t = Hb4[(size_t)(v - HBASE) * 32 + hl];
    acc.x = bfhi_f(t.x) * dv * dv;
    acc.y = bfhi_f(t.y) * dv * dv;
    acc.z = bfhi_f(t.z) * dv * dv;
    acc.w = bfhi_f(t.w) * dv * dv;
  }

  int nb = (e1 - e0 + 15) >> 4;
  int nbo = __shfl_xor(nb, 32);
  int nbmax = max(nb, nbo);

  if (v < NLP) {
    for (int t = 0; t < nbmax; ++t) {
      int e = e0 + t * 16;
      unsigned pr = 0;
      if (hl < 16 && e + hl < e1) pr = eg[e + hl];
      float4 xs[16];
      float cs[16];
#pragma unroll
      for (int i = 0; i < 16; ++i) {
        unsigned pe = (unsigned)__shfl((int)pr, (half << 5) | i);
        int u = pe & 0x1FFFF;
        cs[i] = (e + i < e1)
                    ? __half2float(__ushort_as_half((unsigned short)(pe >> 17)))
                    : 0.f;
        xs[i] = H4[(size_t)u * 32 + hl];
      }
#pragma unroll
      for (int i = 0; i < 16; ++i) {
        acc.x = fmaf(xs[i].x, cs[i], acc.x);
        acc.y = fmaf(xs[i].y, cs[i], acc.y);
        acc.z = fmaf(xs[i].z, cs[i], acc.z);
        acc.w = fmaf(xs[i].w, cs[i], acc.w);
      }
    }
  } else {
    for (int t = 0; t < nbmax; ++t) {
      int e = e0 + t * 16;
      unsigned pr = 0;
      if (hl < 16 && e + hl < e1) pr = eg[e + hl];
      ushort4 xs[16];
      float cs[16];
#pragma unroll
      for (int i = 0; i < 16; ++i) {
        unsigned pe = (unsigned)__shfl((int)pr, (half << 5) | i);
        int u = pe & 0x1FFFF;
        cs[i] = (e + i < e1)
                    ? __half2float(__ushort_as_half((unsigned short)(pe >> 17)))
                    : 0.f;
        xs[i] = Hb4[(size_t)(u - HBASE) * 32 + hl];
      }
#pragma unroll
      for (int i = 0; i < 16; ++i) {
        acc.x = fmaf(bfhi_f(xs[i].x), cs[i], acc.x);
        acc.y = fmaf(bfhi_f(xs[i].y), cs[i], acc.y);
        acc.z = fmaf(bfhi_f(xs[i].z), cs[i], acc.z);
        acc.w = fmaf(bfhi_f(xs[i].w), cs[i], acc.w);
      }
    }
  }

  float4 bb = ((const float4*)bias)[hl];
  acc.x = fmaxf(acc.x + bb.x, 0.f);
  acc.y = fmaxf(acc.y + bb.y, 0.f);
  acc.z = fmaxf(acc.z + bb.z, 0.f);
  acc.w = fmaxf(acc.w + bb.w, 0.f);

  if (v < NLP) {
    ushort4 th, tl;
    split2(acc.x, th.x, tl.x);
    split2(acc.y, th.y, tl.y);
    split2(acc.z, th.z, tl.z);
    split2(acc.w, th.w, tl.w);
    ((ushort4*)Oh)[(size_t)v * 32 + hl] = th;
    ((ushort4*)Ol)[(size_t)v * 32 + hl] = tl;
  } else {
    ushort4 th;
    th.x = bf16_rne(acc.x);
    th.y = bf16_rne(acc.y);
    th.z = bf16_rne(acc.z);
    th.w = bf16_rne(acc.w);
    ((ushort4*)Oh)[(size_t)v * 32 + hl] = th;
  }
}

// ---------------- value head ----------------

__global__ __launch_bounds__(128) void colsum_split(const unsigned short* __restrict__ Hh,
                                                    const unsigned short* __restrict__ Hl,
                                                    float* __restrict__ hsum, int n) {
  int f = threadIdx.x;
  int r0 = blockIdx.x * 128;
  int r1 = min(r0 + 128, n);
  float acc = 0.f;
  for (int r = r0; r < r1; ++r) {
    size_t idx = (size_t)r * 128 + f;
    acc += bfhi_f(Hh[idx]) + bfhi_f(Hl[idx]);
  }
  atomicAdd(&hsum[f], acc);
}

__global__ __launch_bounds__(128) void value_kernel(const float* __restrict__ hsum,
                                                    const float* __restrict__ w1,
                                                    const float* __restrict__ b1,
                                                    const float* __restrict__ w2,
                                                    const float* __restrict__ b2,
                                                    float* __restrict__ out) {
  __shared__ float hm[128];
  __shared__ float red[128];
  int t = threadIdx.x;
  hm[t] = hsum[t] * (1.0f / (float)N_L);
  __syncthreads();
  float acc = b1[t];
  for (int k = 0; k < 128; ++k) acc = fmaf(hm[k], w1[k * 128 + t], acc);
  red[t] = fmaxf(acc, 0.f) * w2[t];
  for (int off = 64; off > 0; off >>= 1) {
    __syncthreads();
    if (t < off) red[t] += red[t + off];
  }
  __syncthreads();
  if (t == 0) out[0] = red[0] + b2[0];
}

__global__ __launch_bounds__(64) void mask_kernel(const float* __restrict__ lp,
                                                  float* __restrict__ out) {
  int i = threadIdx.x;
  if (i < L_H) out[i] = (lp[i] > 0.5f) ? 1.0f : 0.0f;
}

// ---------------- driver ----------------

extern "C" void kernel_launch(void* const* d_in, const int* in_sizes, int n_in,
                              void* d_out, int out_size, void* d_ws, size_t ws_size,
                              hipStream_t stream) {
  const float* x      = (const float*)d_in[0];
  const int*   ei     = (const int*)d_in[1];
  const float* head_x = (const float*)d_in[2];
  const int*   hei    = (const int*)d_in[3];
  const float* enc_w1 = (const float*)d_in[4];
  const float* enc_b1 = (const float*)d_in[5];
  const float* enc_w2 = (const float*)d_in[6];
  const float* enc_b2 = (const float*)d_in[7];
  const float* gnn_w1 = (const float*)d_in[8];
  const float* gnn_b1 = (const float*)d_in[9];
  const float* gnn_w2 = (const float*)d_in[10];
  const float* gnn_b2 = (const float*)d_in[11];
  const float* lp_w1  = (const float*)d_in[12];
  const float* lp_b1  = (const float*)d_in[13];
  const float* lp_w2  = (const float*)d_in[14];
  const float* lp_b2  = (const float*)d_in[15];
  const float* hp_w1  = (const float*)d_in[16];
  const float* hp_b1  = (const float*)d_in[17];
  const float* hp_w2  = (const float*)d_in[18];
  const float* hp_b2  = (const float*)d_in[19];
  const float* v_w1   = (const float*)d_in[20];
  const float* v_b1   = (const float*)d_in[21];
  const float* v_w2   = (const float*)d_in[22];
  const float* v_b2   = (const float*)d_in[23];
  float* out = (float*)d_out;

  // ---- workspace layout ----
  const size_t ELE = (size_t)R_T * 128;
  char* base = (char*)d_ws;
  float* SAf = (float*)base;                    // G layer rows (fp32)
  unsigned short* Hb = (unsigned short*)(SAf + (size_t)NLP * 128);  // head bf16
  int* rank = (int*)base;                       // overlays SLOT_A (pre-enc only)
  char* baseB = base + ELE * 4;
  unsigned short* SBh = (unsigned short*)baseB;
  unsigned short* SBl = SBh + ELE;
  unsigned short* WTh = (unsigned short*)(baseB + ELE * 4);
  unsigned short* WTl = WTh + 114688;
  float* dinv_g = (float*)(WTl + 114688);       // [R_T]
  float* hsum   = dinv_g + R_T;                 // [128]
  int* ip       = (int*)(hsum + 128);
  int* indeg_g  = ip;  ip += R_T;
  int* rowptr_g = ip;  ip += R_T + 1;
  unsigned* eg  = (unsigned*)ip;  ip += E_T + 16;
  int* bsum     = ip;  ip += 112;

  const int WT_ENC1 = 0, WT_ENC2 = 32768, WT_G1 = 49152, WT_G2 = 65536,
            WT_LP = 81920, WT_HP = 98304;

  const int OUT_LP = 0, OUT_HP = N_L, OUT_MASK = N_L + N_HT, OUT_SV = N_L + N_HT + L_H;

  // ---- CSR + dinv + weight split ----
  hipMemsetAsync(indeg_g, 0, (size_t)R_T * sizeof(int), stream);
  hipMemsetAsync(hsum, 0, 128 * sizeof(float), stream);

  conv_weights<<<448, 256, 0, stream>>>(enc_w1, enc_w2, gnn_w1, gnn_w2, lp_w1, hp_w1,
                                        WTh, WTl);

  count_deg_all<<<(E_T + 255) / 256, 256, 0, stream>>>(ei, hei, indeg_g, rank);
  dinv_kernel<<<(R_T + 255) / 256, 256, 0, stream>>>(indeg_g, dinv_g, R_T);

  scan_block<<<(R_T + 1023) / 1024, 1024, 0, stream>>>(indeg_g, R_T, rowptr_g, bsum);
  scan_top128<<<1, 64, 0, stream>>>(bsum, (R_T + 1023) / 1024);
  scan_fix<<<(R_T + 256) / 256, 256, 0, stream>>>(rowptr_g, bsum, R_T,
                                                  (R_T + 1023) / 1024);
  fill_csr_all<<<(E_T + 255) / 256, 256, 0, stream>>>(ei, hei, dinv_g, rowptr_g,
                                                      rank, eg);

  // ---- fused encoder + g1-mm: x -> h1 -> h2 -> G1 (layer fp32 / head bf16) ----
  enc_fused<<<R_T / 128, 256, 0, stream>>>(
      x, head_x,
      WTh + WT_ENC1, WTl + WT_ENC1,
      WTh + WT_ENC2, WTl + WT_ENC2,
      WTh + WT_G1,   WTl + WT_G1,
      enc_b1, enc_b2, SAf, Hb);

  // ---- GCN layer 1 aggregate ----
  agg_packed<<<R_T / 8, 256, 0, stream>>>(SAf, Hb, dinv_g, rowptr_g, eg, gnn_b1,
                                          SBh, SBl);

  // ---- GCN layer 2 ----
  mm_g<<<R_T / 128, 256, 0, stream>>>(SBh, SBl, WTh + WT_G2, WTl + WT_G2, SAf, Hb);
  agg_packed<<<R_T / 8, 256, 0, stream>>>(SAf, Hb, dinv_g, rowptr_g, eg, gnn_b2,
                                          SBh, SBl);

  // ---- policy heads (merged lp+hp, fused sigmoid) ----
  mm_policy<<<R_T / 128, 256, 0, stream>>>(
      SBh, SBl,
      WTh + WT_LP, WTl + WT_LP, WTh + WT_HP, WTl + WT_HP,
      lp_b1, hp_b1, lp_w2, hp_w2, lp_b2, hp_b2,
      out + OUT_LP, out + OUT_HP);

  // ---- value ----
  colsum_split<<<(N_L + 127) / 128, 128, 0, stream>>>(SBh, SBl, hsum, N_L);
  value_kernel<<<1, 128, 0, stream>>>(hsum, v_w1, v_b1, v_w2, v_b2, out + OUT_SV);

  // ---- mask ----
  mask_kernel<<<1, 64, 0, stream>>>(out + OUT_LP, out + OUT_MASK);
}